// Round 8
// baseline (442.703 us; speedup 1.0000x reference)
//
#include <hip/hip_runtime.h>
#include <hip/hip_bf16.h>
#include <math.h>

// Problem constants (match reference)
#define BATCH 4
#define SEQ   2048
#define DMODEL 768
#define NHEAD 12
#define HS    64
#define HID   3072   // 4*DMODEL
#define NROWS (BATCH*SEQ)   // 8192
#define QKVN  (3*DMODEL)    // 2304
#define EPS   1e-6f

typedef __attribute__((ext_vector_type(8))) short bf16x8;
typedef __attribute__((ext_vector_type(4))) float f32x4;

__device__ inline ushort f2b(float f) {
    union { float f; unsigned u; } x; x.f = f;
    unsigned u = x.u;
    unsigned r = (u + 0x7FFFu + ((u >> 16) & 1u)) >> 16;
    return (ushort)r;
}

// async global->LDS, 16B per lane (m97)
#define GLDS16(g, l) __builtin_amdgcn_global_load_lds( \
    (const __attribute__((address_space(1))) void*)(g), \
    (__attribute__((address_space(3))) void*)(l), 16, 0, 0)

// ---------------- Weight convert+transpose: fp32 [K][N] -> bf16 [N][K] ----------------
__global__ __launch_bounds__(256) void convert_w4(const float* __restrict__ p0,
                                                  const float* __restrict__ p1,
                                                  const float* __restrict__ p2,
                                                  const float* __restrict__ p3,
                                                  ushort* __restrict__ out) {
    const float* srcs[4] = { p0, p1, p2, p3 };
    const float* in = srcs[blockIdx.z];
    ushort* dst = out + (size_t)blockIdx.z * DMODEL * DMODEL;
    __shared__ float tile[32][33];
    const int bx = blockIdx.x * 32;  // N
    const int by = blockIdx.y * 32;  // K
    const int tx = threadIdx.x & 31, ty = threadIdx.x >> 5;
    #pragma unroll
    for (int i = 0; i < 32; i += 8)
        tile[ty + i][tx] = in[(size_t)(by + ty + i) * DMODEL + bx + tx];
    __syncthreads();
    #pragma unroll
    for (int i = 0; i < 32; i += 8)
        dst[(size_t)(bx + ty + i) * DMODEL + by + tx] = f2b(tile[tx][ty + i]);
}

__global__ __launch_bounds__(256) void convert_w(const float* __restrict__ in,
                                                 ushort* __restrict__ out,
                                                 int K, int N) {
    __shared__ float tile[32][33];
    const int bx = blockIdx.x * 32;  // N
    const int by = blockIdx.y * 32;  // K
    const int tx = threadIdx.x & 31, ty = threadIdx.x >> 5;
    #pragma unroll
    for (int i = 0; i < 32; i += 8)
        tile[ty + i][tx] = in[(size_t)(by + ty + i) * N + bx + tx];
    __syncthreads();
    #pragma unroll
    for (int i = 0; i < 32; i += 8)
        out[(size_t)(bx + ty + i) * K + by + tx] = f2b(tile[tx][ty + i]);
}

// ---------------- V transpose: v[b][s][h*64+d] (stride QKVN) -> vt[(bh*64+d)][s] ----------------
__global__ __launch_bounds__(256) void transpose_v(const ushort* __restrict__ v,
                                                   ushort* __restrict__ vt) {
    const int st = blockIdx.x;   // key tile (64 rows)
    const int bh = blockIdx.y;
    const int b = bh / NHEAD, h = bh % NHEAD;
    const ushort* src = v + ((size_t)b * SEQ) * QKVN + h * HS;
    ushort* dst = vt + ((size_t)bh * HS) * SEQ;
    __shared__ ushort t[64][65];
    const int col = threadIdx.x & 63;
    const int r0  = (threadIdx.x >> 6) * 16;
    #pragma unroll
    for (int i = 0; i < 16; ++i)
        t[col][r0 + i] = src[(size_t)(st * 64 + r0 + i) * QKVN + col];
    __syncthreads();
    #pragma unroll
    for (int i = 0; i < 16; ++i)
        dst[(size_t)(r0 + i) * SEQ + st * 64 + col] = t[r0 + i][col];
}

// ---------------- LayerNorm (ddof=1), fp32 in -> bf16 out ----------------
__global__ __launch_bounds__(256) void ln_kernel(const float* __restrict__ x,
                                                 const float* __restrict__ gamma,
                                                 const float* __restrict__ beta,
                                                 ushort* __restrict__ out) {
    const int row = blockIdx.x;
    const float* xr = x + (size_t)row * DMODEL;
    float s = 0.f, s2 = 0.f;
    for (int i = threadIdx.x; i < DMODEL; i += 256) {
        float v = xr[i];
        s += v; s2 += v * v;
    }
    for (int off = 32; off > 0; off >>= 1) {
        s  += __shfl_down(s,  off, 64);
        s2 += __shfl_down(s2, off, 64);
    }
    __shared__ float shs[4], shs2[4];
    int wid = threadIdx.x >> 6, lane = threadIdx.x & 63;
    if (lane == 0) { shs[wid] = s; shs2[wid] = s2; }
    __syncthreads();
    __shared__ float smean, srstd;
    if (threadIdx.x == 0) {
        float S  = shs[0] + shs[1] + shs[2] + shs[3];
        float S2 = shs2[0] + shs2[1] + shs2[2] + shs2[3];
        float mean = S / DMODEL;
        float var  = (S2 - DMODEL * mean * mean) / (DMODEL - 1);
        smean = mean;
        srstd = rsqrtf(var + EPS);
    }
    __syncthreads();
    float mean = smean, rstd = srstd;
    ushort* orow = out + (size_t)row * DMODEL;
    for (int i = threadIdx.x; i < DMODEL; i += 256) {
        orow[i] = f2b(gamma[i] * (xr[i] - mean) * rstd + beta[i]);
    }
}

// ---------------- gemm_mfma: 64x128 tile, BK=32, tri-buffer + counted vmcnt (N=768) ----------------
// r15: port the r6-proven schedule (tri-buffer, counted vmcnt, raw barrier)
// to the N=768 GEMMs. MLP2 previously paid 96 full vmcnt(0) drains. BK=32
// row-pair layout (zero-conflict, verified r5/r6). LDS 36KB -> LDS-cap 4
// blocks/CU (grid supplies 3). Wait-BEFORE-barrier ordering: each wave
// drains its OWN tile-t loads to vmcnt(3), then barrier -> collectively all
// tile-t data in LDS (multi-wave safety, r6 argument).
#define GN 128
#define GK 32
#define GM 64
__global__ __launch_bounds__(256, 4) void gemm_mfma(const ushort* __restrict__ A,
                                                    const ushort* __restrict__ Bt,
                                                    const float* __restrict__ bias,
                                                    const float* __restrict__ res,
                                                    float* __restrict__ C,
                                                    ushort* __restrict__ Cb,
                                                    int M, int N, int K, int do_relu,
                                                    int scale_q) {
    __shared__ ushort As[3][GM * GK];   // 3 x 4 KB
    __shared__ ushort Bs[3][GN * GK];   // 3 x 8 KB -> 36 KB total
    const int tid  = threadIdx.x;
    const int lane = tid & 63, wave = tid >> 6;
    const int l16  = lane & 15, quad = lane >> 4;
    const int wr = wave >> 1, wc = wave & 1;

    // XCD-aware swizzle
    const int nwg = gridDim.x * gridDim.y;
    int id = blockIdx.y * gridDim.x + blockIdx.x;
    if ((nwg & 7) == 0) {
        const int chunk = nwg >> 3;
        id = (id & 7) * chunk + (id >> 3);
    }
    const int bx = id % gridDim.x;
    const int by = id / gridDim.x;
    const int row0 = by * GM, col0 = bx * GN;

    f32x4 acc[2][4];
    #pragma unroll
    for (int i = 0; i < 2; ++i)
        #pragma unroll
        for (int j = 0; j < 4; ++j) acc[i][j] = (f32x4){0.f, 0.f, 0.f, 0.f};

    // row-pair layout: LDS chunk c = lr*8+pos <- global (m=2*lr+(p>>2), j=p&3), p=pos^(lr&7)
    const ushort* Asrc;      // A: 256 chunks, 1/thread
    const ushort* Bsrc[2];   // B: 512 chunks, 2/thread
    {
        int c = tid, lr = c >> 3, pp = (c & 7) ^ (lr & 7);
        int m = lr * 2 + (pp >> 2), j = pp & 3;
        Asrc = A + (size_t)(row0 + m) * K + j * 8;
    }
    #pragma unroll
    for (int i = 0; i < 2; ++i) {
        int c = tid + i * 256, lr = c >> 3, pp = (c & 7) ^ (lr & 7);
        int m = lr * 2 + (pp >> 2), j = pp & 3;
        Bsrc[i] = Bt + (size_t)(col0 + m) * K + j * 8;
    }

    const int nk = K / GK;   // 24 (proj) or 96 (MLP2)

#define STAGE_MF(kt, b) do { \
    const int _k = (kt) * GK; \
    GLDS16(Asrc + _k,    &As[b][tid * 8]); \
    GLDS16(Bsrc[0] + _k, &Bs[b][tid * 8]); \
    GLDS16(Bsrc[1] + _k, &Bs[b][(tid + 256) * 8]); \
} while (0)

    STAGE_MF(0, 0);
    STAGE_MF(1, 1);

    int pc = 0, pn = 1, ps = 2;
    for (int t = 0; t < nk; ++t) {
        if (t + 1 < nk) asm volatile("s_waitcnt vmcnt(3)" ::: "memory");
        else            asm volatile("s_waitcnt vmcnt(0)" ::: "memory");
        __builtin_amdgcn_s_barrier();
        if (t + 2 < nk) STAGE_MF(t + 2, ps);

        bf16x8 af[2], bfr[4];
        #pragma unroll
        for (int i = 0; i < 2; ++i) {
            int m = wr * 32 + i * 16 + l16;
            int ch = (m >> 1) * 8 + ((((m & 1) << 2) | quad) ^ ((m >> 1) & 7));
            af[i] = *(const bf16x8*)&As[pc][ch * 8];
        }
        #pragma unroll
        for (int j = 0; j < 4; ++j) {
            int n = wc * 64 + j * 16 + l16;
            int ch = (n >> 1) * 8 + ((((n & 1) << 2) | quad) ^ ((n >> 1) & 7));
            bfr[j] = *(const bf16x8*)&Bs[pc][ch * 8];
        }
        #pragma unroll
        for (int i = 0; i < 2; ++i)
            #pragma unroll
            for (int j = 0; j < 4; ++j)
                acc[i][j] = __builtin_amdgcn_mfma_f32_16x16x32_bf16(af[i], bfr[j], acc[i][j], 0, 0, 0);

        int tmp = pc; pc = pn; pn = ps; ps = tmp;
    }

    // epilogue: C/D layout col=l16, row=quad*4+r
    #pragma unroll
    for (int i = 0; i < 2; ++i) {
        #pragma unroll
        for (int r = 0; r < 4; ++r) {
            int row = row0 + wr * 32 + i * 16 + quad * 4 + r;
            #pragma unroll
            for (int j = 0; j < 4; ++j) {
                int col = col0 + wc * 64 + j * 16 + l16;
                float v = acc[i][j][r];
                if (bias) v += bias[col];
                if (do_relu) v = fmaxf(v, 0.f);
                if (scale_q && col < DMODEL) v *= 0.125f;
                if (res) v += res[(size_t)row * N + col];
                if (Cb) Cb[(size_t)row * N + col] = f2b(v);
                else    C [(size_t)row * N + col] = v;
            }
        }
    }
}

// ---------------- gemm_big: 256x128, 8 waves x 64x64, BK=32, tri-buffer + counted vmcnt ----------------
// r15: r7 hit 54% occupancy but MfmaUtil stuck 21% -> LDS reads are the
// busiest pipe (~60% of BW; 32x64/wave = 21.3 FLOP/LDS-byte). 64x64/wave
// gives 32 FLOP/LDS-byte. All three previous blockers now composed away:
// bank conflicts (row-pair layout, r5), barrier drain (counted vmcnt, r6),
// wave starvation (512t, r7). 72KB LDS -> 2 blocks/CU = 16 waves/CU.
// Per-thread stage = 2 A + 1 B chunk -> vmcnt(3).
// Tripwires: WRITE_SIZE jump = spill at (512,4) 128-reg cap; conflicts
// >1e5 = layout port bug; flat time at 50% occ -> go 8-phase next.
#define HM 256
#define HN 128
#define HK 32
__global__ __launch_bounds__(512, 4) void gemm_big(const ushort* __restrict__ A,
                                                   const ushort* __restrict__ Bt,
                                                   const float* __restrict__ bias,
                                                   const float* __restrict__ res,
                                                   float* __restrict__ C,
                                                   ushort* __restrict__ Cb,
                                                   int M, int N, int K, int do_relu,
                                                   int scale_q) {
    __shared__ ushort As[3][HM * HK];   // 3 x 16 KB
    __shared__ ushort Bs[3][HN * HK];   // 3 x 8 KB  -> 72 KB total
    const int tid  = threadIdx.x;
    const int lane = tid & 63, wave = tid >> 6;   // 0..7
    const int l16  = lane & 15, quad = lane >> 4;
    const int wr = wave & 3, wc = wave >> 2;      // 4x2 wave grid, 64x64/wave

    const int nwg = gridDim.x * gridDim.y;
    int id = blockIdx.y * gridDim.x + blockIdx.x;
    if ((nwg & 7) == 0) {
        const int chunk = nwg >> 3;
        id = (id & 7) * chunk + (id >> 3);
    }
    const int bx = id % gridDim.x;
    const int by = id / gridDim.x;
    const int row0 = by * HM, col0 = bx * HN;

    f32x4 acc[4][4];
    #pragma unroll
    for (int i = 0; i < 4; ++i)
        #pragma unroll
        for (int j = 0; j < 4; ++j) acc[i][j] = (f32x4){0.f, 0.f, 0.f, 0.f};

    // row-pair layout (zero-conflict, verified r5/r6)
    // A: 256x32 = 1024 chunks -> 2/thread; B: 128x32 = 512 chunks -> 1/thread
    const ushort* Asrc[2];
    const ushort* Bsrc;
    #pragma unroll
    for (int i = 0; i < 2; ++i) {
        int c = tid + i * 512, lr = c >> 3, pp = (c & 7) ^ (lr & 7);
        int m = lr * 2 + (pp >> 2), j = pp & 3;
        Asrc[i] = A + (size_t)(row0 + m) * K + j * 8;
    }
    {
        int c = tid, lr = c >> 3, pp = (c & 7) ^ (lr & 7);
        int m = lr * 2 + (pp >> 2), j = pp & 3;
        Bsrc = Bt + (size_t)(col0 + m) * K + j * 8;
    }

    const int nk = K / HK;   // 24

#define STAGE_BIG(kt, b) do { \
    const int _k = (kt) * HK; \
    GLDS16(Asrc[0] + _k, &As[b][tid * 8]); \
    GLDS16(Asrc[1] + _k, &As[b][(tid + 512) * 8]); \
    GLDS16(Bsrc + _k,    &Bs[b][tid * 8]); \
} while (0)

    STAGE_BIG(0, 0);
    STAGE_BIG(1, 1);

    int pc = 0, pn = 1, ps = 2;
    for (int t = 0; t < nk; ++t) {
        if (t + 1 < nk) asm volatile("s_waitcnt vmcnt(3)" ::: "memory");
        else            asm volatile("s_waitcnt vmcnt(0)" ::: "memory");
        __builtin_amdgcn_s_barrier();
        if (t + 2 < nk) STAGE_BIG(t + 2, ps);

        bf16x8 af[4], bfr[4];
        #pragma unroll
        for (int i = 0; i < 4; ++i) {
            int m = wr * 64 + i * 16 + l16;
            int ch = (m >> 1) * 8 + ((((m & 1) << 2) | quad) ^ ((m >> 1) & 7));
            af[i] = *(const bf16x8*)&As[pc][ch * 8];
        }
        #pragma unroll
        for (int j = 0; j < 4; ++j) {
            int n = wc * 64 + j * 16 + l16;
            int ch = (n >> 1) * 8 + ((((n & 1) << 2) | quad) ^ ((n >> 1) & 7));
            bfr[j] = *(const bf16x8*)&Bs[pc][ch * 8];
        }
        #pragma unroll
        for (int i = 0; i < 4; ++i)
            #pragma unroll
            for (int j = 0; j < 4; ++j)
                acc[i][j] = __builtin_amdgcn_mfma_f32_16x16x32_bf16(af[i], bfr[j], acc[i][j], 0, 0, 0);

        int tmp = pc; pc = pn; pn = ps; ps = tmp;
    }

    // epilogue: C/D layout col=l16, row=quad*4+r
    #pragma unroll
    for (int i = 0; i < 4; ++i) {
        #pragma unroll
        for (int r = 0; r < 4; ++r) {
            int row = row0 + wr * 64 + i * 16 + quad * 4 + r;
            #pragma unroll
            for (int j = 0; j < 4; ++j) {
                int col = col0 + wc * 64 + j * 16 + l16;
                float v = acc[i][j][r];
                if (bias) v += bias[col];
                if (do_relu) v = fmaxf(v, 0.f);
                if (scale_q && col < DMODEL) v *= 0.125f;
                if (res) v += res[(size_t)row * N + col];
                if (Cb) Cb[(size_t)row * N + col] = f2b(v);
                else    C [(size_t)row * N + col] = v;
            }
        }
    }
}

// ---------------- Flash attention: paired q-tiles, GLDS staging, dbuf ----------------
#define TQ 64
#define TK 64
#define PPAD 72
#define NQT (SEQ / TQ)   // 32

__global__ __launch_bounds__(256, 3) void fattn_kernel(const ushort* __restrict__ q,
                                                       const ushort* __restrict__ k,
                                                       const ushort* __restrict__ vt,
                                                       ushort* __restrict__ o,
                                                       int ldqkv) {
    const int pair = blockIdx.x;             // 0..15
    const int qts[2] = { pair, NQT - 1 - pair };
    const int bh = blockIdx.y;
    const int b = bh / NHEAD, h = bh % NHEAD;
    const int tid  = threadIdx.x;
    const int wave = tid >> 6;
    const int lane = tid & 63;
    const int l16  = lane & 15;
    const int quad = lane >> 4;

    __shared__ ushort Ks[2][TK * 64];    // 8 KB per buffer, packed [key][8 chunks]
    __shared__ ushort Vs[2][HS * 64];    // 8 KB per buffer, packed [d][8 chunks]
    __shared__ ushort Ps[4][16][PPAD];   // per-wave P[q][key] (wave-private)

    const size_t base  = ((size_t)b * SEQ) * ldqkv + (size_t)h * HS;
    const size_t baseO = ((size_t)b * SEQ) * DMODEL + (size_t)h * HS;
    const ushort* vth = vt + ((size_t)bh * HS) * SEQ;

    const int r0 = tid >> 3, j0 = (tid & 7) ^ (r0 & 7);
    const int r1 = (tid + 256) >> 3, j1 = (tid & 7) ^ (r1 & 7);
    const ushort* Ksrc0 = k + base + (size_t)r0 * ldqkv + j0 * 8;
    const ushort* Ksrc1 = k + base + (size_t)r1 * ldqkv + j1 * 8;
    const ushort* Vsrc0 = vth + (size_t)r0 * SEQ + j0 * 8;
    const ushort* Vsrc1 = vth + (size_t)r1 * SEQ + j1 * 8;

    bf16x8 qf[2][2];
    #pragma unroll
    for (int t = 0; t < 2; ++t) {
        int qrow = qts[t] * TQ + wave * 16 + l16;
        const ushort* qp = q + base + (size_t)qrow * ldqkv + quad * 8;
        qf[t][0] = *(const bf16x8*)(qp);
        qf[t][1] = *(const bf16x8*)(qp + 32);
    }

    f32x4 Oacc[2][4];
    float lrow[2][4];
    #pragma unroll
    for (int t = 0; t < 2; ++t) {
        #pragma unroll
        for (int f = 0; f < 4; ++f) Oacc[t][f] = (f32x4){0.f, 0.f, 0.f, 0.f};
        #pragma unroll
        for (int r = 0; r < 4; ++r) lrow[t][r] = 0.f;
    }

    const int ktiles = qts[1] + 1;
    GLDS16(Ksrc0, &Ks[0][tid * 8]);
    GLDS16(Ksrc1, &Ks[0][(tid + 256) * 8]);
    GLDS16(Vsrc0, &Vs[0][tid * 8]);
    GLDS16(Vsrc1, &Vs[0][(tid + 256) * 8]);

    for (int kt = 0; kt < ktiles; ++kt) {
        const int p = kt & 1;
        __syncthreads();   // drains buf[p] (in flight since last compute phase)
        if (kt + 1 < ktiles) {
            const size_t ko = (size_t)(kt + 1) * TK;
            GLDS16(Ksrc0 + ko * ldqkv, &Ks[p ^ 1][tid * 8]);
            GLDS16(Ksrc1 + ko * ldqkv, &Ks[p ^ 1][(tid + 256) * 8]);
            GLDS16(Vsrc0 + ko,         &Vs[p ^ 1][tid * 8]);
            GLDS16(Vsrc1 + ko,         &Vs[p ^ 1][(tid + 256) * 8]);
        }

        bf16x8 kb[4][2], vb[4][2];
        #pragma unroll
        for (int f = 0; f < 4; ++f) {
            int row = f * 16 + l16;
            kb[f][0] = *(const bf16x8*)&Ks[p][(row * 8 + (quad ^ (row & 7))) * 8];
            kb[f][1] = *(const bf16x8*)&Ks[p][(row * 8 + ((4 | quad) ^ (row & 7))) * 8];
            vb[f][0] = *(const bf16x8*)&Vs[p][(row * 8 + (quad ^ (row & 7))) * 8];
            vb[f][1] = *(const bf16x8*)&Vs[p][(row * 8 + ((4 | quad) ^ (row & 7))) * 8];
        }

        #pragma unroll
        for (int t = 0; t < 2; ++t) {
            const int qt = qts[t];
            if (kt > qt) continue;   // wave-uniform; only t=0 can skip

            f32x4 S[4];
            #pragma unroll
            for (int f = 0; f < 4; ++f) {
                f32x4 a = (f32x4){0.f, 0.f, 0.f, 0.f};
                a = __builtin_amdgcn_mfma_f32_16x16x32_bf16(qf[t][0], kb[f][0], a, 0, 0, 0);
                a = __builtin_amdgcn_mfma_f32_16x16x32_bf16(qf[t][1], kb[f][1], a, 0, 0, 0);
                S[f] = a;
            }

            const int qrow_base = qt * TQ + wave * 16 + quad * 4;
            if (kt == qt) {
                #pragma unroll
                for (int f = 0; f < 4; ++f) {
                    int key = kt * TK + f * 16 + l16;
                    #pragma unroll
                    for (int r = 0; r < 4; ++r)
                        if (key > qrow_base + r) S[f][r] = -INFINITY;
                }
            }

            #pragma unroll
            for (int f = 0; f < 4; ++f) {
                #pragma unroll
                for (int r = 0; r < 4; ++r) {
                    float pv = __expf(S[f][r]);
                    S[f][r] = pv;
                    lrow[t][r] += pv;
                }
            }

            #pragma unroll
            for (int f = 0; f < 4; ++f)
                #pragma unroll
                for (int r = 0; r < 4; ++r)
                    Ps[wave][quad * 4 + r][f * 16 + l16] = f2b(S[f][r]);

            bf16x8 pa0 = *(const bf16x8*)&Ps[wave][l16][quad * 8];
            bf16x8 pa1 = *(const bf16x8*)&Ps[wave][l16][32 + quad * 8];
            #pragma unroll
            for (int f = 0; f < 4; ++f) {
                Oacc[t][f] = __builtin_amdgcn_mfma_f32_16x16x32_bf16(pa0, vb[f][0], Oacc[t][f], 0, 0, 0);
                Oacc[t][f] = __builtin_amdgcn_mfma_f32_16x16x32_bf16(pa1, vb[f][1], Oacc[t][f], 0, 0, 0);
            }
        }
    }

    #pragma unroll
    for (int t = 0; t < 2; ++t) {
        const int qrow = qts[t] * TQ + wave * 16 + quad * 4;
        #pragma unroll
        for (int r = 0; r < 4; ++r) {
            float l = lrow[t][r];
            #pragma unroll
            for (int m = 1; m < 16; m <<= 1) l += __shfl_xor(l, m, 64);
            float invl = 1.f / l;
            #pragma unroll
            for (int f = 0; f < 4; ++f)
                o[baseO + (size_t)(qrow + r) * DMODEL + f * 16 + l16] = f2b(Oacc[t][f][r] * invl);
        }
    }
}

// ---------------- Host launcher ----------------
extern "C" void kernel_launch(void* const* d_in, const int* in_sizes, int n_in,
                              void* d_out, int out_size, void* d_ws, size_t ws_size,
                              hipStream_t stream) {
    const float* x      = (const float*)d_in[0];
    const float* wq     = (const float*)d_in[1];
    const float* wk     = (const float*)d_in[2];
    const float* wv     = (const float*)d_in[3];
    const float* wo     = (const float*)d_in[4];
    const float* w1     = (const float*)d_in[5];
    const float* b1     = (const float*)d_in[6];
    const float* w2     = (const float*)d_in[7];
    const float* b2     = (const float*)d_in[8];
    const float* gamma1 = (const float*)d_in[9];
    const float* beta1  = (const float*)d_in[10];
    const float* gamma2 = (const float*)d_in[11];
    const float* beta2  = (const float*)d_in[12];
    float* out = (float*)d_out;

    char* ws = (char*)d_ws;
    ushort* buf_xn   = (ushort*)ws;                              // 8192*768
    ushort* buf_attn = buf_xn;
    ushort* buf_qkv  = (ushort*)(ws + 12582912);                 // 8192*2304
    ushort* buf_h    = buf_qkv;                                  // 8192*3072
    ushort* w_qkv    = (ushort*)(ws + 12582912 + 50331648);      // 2304*768
    ushort* w_ot     = w_qkv + (size_t)QKVN * DMODEL;
    ushort* w_1t     = w_ot + (size_t)DMODEL * DMODEL;
    ushort* w_2t     = w_1t + (size_t)HID * DMODEL;
    // V^T lives in d_out (free until step 4; stream-serial)
    ushort* buf_vt   = (ushort*)d_out;

    convert_w4<<<dim3(DMODEL/32, DMODEL/32, 4), 256, 0, stream>>>(wq, wk, wv, wo, w_qkv);
    convert_w<<<dim3(HID/32,    DMODEL/32), 256, 0, stream>>>(w1, w_1t, DMODEL, HID);
    convert_w<<<dim3(DMODEL/32, HID/32),    256, 0, stream>>>(w2, w_2t, HID, DMODEL);

    // 1) xn1 = LN(x)
    ln_kernel<<<NROWS, 256, 0, stream>>>(x, gamma1, beta1, buf_xn);
    // 2) qkv = xn1 @ [wq|wk|wv], Q cols pre-scaled by 0.125 (gemm_big 256x128, 512t)
    gemm_big<<<dim3(QKVN/HN, NROWS/HM), 512, 0, stream>>>(buf_xn, w_qkv, nullptr, nullptr,
                                                          nullptr, buf_qkv, NROWS, QKVN, DMODEL, 0, 1);
    // 2b) V -> V^T per head (into d_out scratch)
    transpose_v<<<dim3(SEQ/64, BATCH*NHEAD), 256, 0, stream>>>(buf_qkv + 2*DMODEL, buf_vt);
    // 3) flash attention (paired q-tiles, GLDS dbuf staging, fixed-max softmax)
    fattn_kernel<<<dim3(NQT/2, BATCH*NHEAD), 256, 0, stream>>>(buf_qkv, buf_qkv + DMODEL,
                                                               buf_vt, buf_attn, QKVN);
    // 4) x1 = x + attn @ wo (N=768 -> gemm_mfma, tri-buffer counted vmcnt)
    gemm_mfma<<<dim3(DMODEL/GN, NROWS/GM), 256, 0, stream>>>(buf_attn, w_ot, nullptr, x,
                                                             out, nullptr, NROWS, DMODEL, DMODEL, 0, 0);
    // 5) xn2 = LN(x1)
    ln_kernel<<<NROWS, 256, 0, stream>>>(out, gamma2, beta2, buf_xn);
    // 6) h = relu(xn2 @ w1 + b1) (gemm_big 256x128, 512t)
    gemm_big<<<dim3(HID/HN, NROWS/HM), 512, 0, stream>>>(buf_xn, w_1t, b1, nullptr,
                                                         nullptr, buf_h, NROWS, HID, DMODEL, 1, 0);
    // 7) out = x1 + h @ w2 + b2 (N=768 -> gemm_mfma)
    gemm_mfma<<<dim3(DMODEL/GN, NROWS/GM), 256, 0, stream>>>(buf_h, w_2t, b2, out,
                                                             out, nullptr, NROWS, DMODEL, HID, 0, 0);
}

// Round 9
// 415.181 us; speedup vs baseline: 1.0663x; 1.0663x over previous
//
#include <hip/hip_runtime.h>
#include <hip/hip_bf16.h>
#include <math.h>

// Problem constants (match reference)
#define BATCH 4
#define SEQ   2048
#define DMODEL 768
#define NHEAD 12
#define HS    64
#define HID   3072   // 4*DMODEL
#define NROWS (BATCH*SEQ)   // 8192
#define QKVN  (3*DMODEL)    // 2304
#define EPS   1e-6f

typedef __attribute__((ext_vector_type(8))) short bf16x8;
typedef __attribute__((ext_vector_type(4))) float f32x4;

__device__ inline ushort f2b(float f) {
    union { float f; unsigned u; } x; x.f = f;
    unsigned u = x.u;
    unsigned r = (u + 0x7FFFu + ((u >> 16) & 1u)) >> 16;
    return (ushort)r;
}

// async global->LDS, 16B per lane (m97)
#define GLDS16(g, l) __builtin_amdgcn_global_load_lds( \
    (const __attribute__((address_space(1))) void*)(g), \
    (__attribute__((address_space(3))) void*)(l), 16, 0, 0)

// ---------------- Weight convert+transpose: fp32 [K][N] -> bf16 [N][K] ----------------
__global__ __launch_bounds__(256) void convert_w4(const float* __restrict__ p0,
                                                  const float* __restrict__ p1,
                                                  const float* __restrict__ p2,
                                                  const float* __restrict__ p3,
                                                  ushort* __restrict__ out) {
    const float* srcs[4] = { p0, p1, p2, p3 };
    const float* in = srcs[blockIdx.z];
    ushort* dst = out + (size_t)blockIdx.z * DMODEL * DMODEL;
    __shared__ float tile[32][33];
    const int bx = blockIdx.x * 32;  // N
    const int by = blockIdx.y * 32;  // K
    const int tx = threadIdx.x & 31, ty = threadIdx.x >> 5;
    #pragma unroll
    for (int i = 0; i < 32; i += 8)
        tile[ty + i][tx] = in[(size_t)(by + ty + i) * DMODEL + bx + tx];
    __syncthreads();
    #pragma unroll
    for (int i = 0; i < 32; i += 8)
        dst[(size_t)(bx + ty + i) * DMODEL + by + tx] = f2b(tile[tx][ty + i]);
}

__global__ __launch_bounds__(256) void convert_w(const float* __restrict__ in,
                                                 ushort* __restrict__ out,
                                                 int K, int N) {
    __shared__ float tile[32][33];
    const int bx = blockIdx.x * 32;  // N
    const int by = blockIdx.y * 32;  // K
    const int tx = threadIdx.x & 31, ty = threadIdx.x >> 5;
    #pragma unroll
    for (int i = 0; i < 32; i += 8)
        tile[ty + i][tx] = in[(size_t)(by + ty + i) * N + bx + tx];
    __syncthreads();
    #pragma unroll
    for (int i = 0; i < 32; i += 8)
        out[(size_t)(bx + ty + i) * K + by + tx] = f2b(tile[tx][ty + i]);
}

// ---------------- V transpose: v[b][s][h*64+d] (stride QKVN) -> vt[(bh*64+d)][s] ----------------
__global__ __launch_bounds__(256) void transpose_v(const ushort* __restrict__ v,
                                                   ushort* __restrict__ vt) {
    const int st = blockIdx.x;   // key tile (64 rows)
    const int bh = blockIdx.y;
    const int b = bh / NHEAD, h = bh % NHEAD;
    const ushort* src = v + ((size_t)b * SEQ) * QKVN + h * HS;
    ushort* dst = vt + ((size_t)bh * HS) * SEQ;
    __shared__ ushort t[64][65];
    const int col = threadIdx.x & 63;
    const int r0  = (threadIdx.x >> 6) * 16;
    #pragma unroll
    for (int i = 0; i < 16; ++i)
        t[col][r0 + i] = src[(size_t)(st * 64 + r0 + i) * QKVN + col];
    __syncthreads();
    #pragma unroll
    for (int i = 0; i < 16; ++i)
        dst[(size_t)(r0 + i) * SEQ + st * 64 + col] = t[r0 + i][col];
}

// ---------------- LayerNorm (ddof=1), fp32 in -> bf16 out ----------------
__global__ __launch_bounds__(256) void ln_kernel(const float* __restrict__ x,
                                                 const float* __restrict__ gamma,
                                                 const float* __restrict__ beta,
                                                 ushort* __restrict__ out) {
    const int row = blockIdx.x;
    const float* xr = x + (size_t)row * DMODEL;
    float s = 0.f, s2 = 0.f;
    for (int i = threadIdx.x; i < DMODEL; i += 256) {
        float v = xr[i];
        s += v; s2 += v * v;
    }
    for (int off = 32; off > 0; off >>= 1) {
        s  += __shfl_down(s,  off, 64);
        s2 += __shfl_down(s2, off, 64);
    }
    __shared__ float shs[4], shs2[4];
    int wid = threadIdx.x >> 6, lane = threadIdx.x & 63;
    if (lane == 0) { shs[wid] = s; shs2[wid] = s2; }
    __syncthreads();
    __shared__ float smean, srstd;
    if (threadIdx.x == 0) {
        float S  = shs[0] + shs[1] + shs[2] + shs[3];
        float S2 = shs2[0] + shs2[1] + shs2[2] + shs2[3];
        float mean = S / DMODEL;
        float var  = (S2 - DMODEL * mean * mean) / (DMODEL - 1);
        smean = mean;
        srstd = rsqrtf(var + EPS);
    }
    __syncthreads();
    float mean = smean, rstd = srstd;
    ushort* orow = out + (size_t)row * DMODEL;
    for (int i = threadIdx.x; i < DMODEL; i += 256) {
        orow[i] = f2b(gamma[i] * (xr[i] - mean) * rstd + beta[i]);
    }
}

// ---------------- gemm_mfma: 64x128 tile, BK=64, per-wave 32x64 (N=768) ----------------
// r16: REVERTED to the r2/r7-proven config. r8's BK=32 tri-buffer DOUBLED
// the sync frequency (MLP2: 48->96 barriers) while halving per-step MFMA
// work (16->8) -> MLP2 65-ish -> 91.5us. BK=32 pays only at 128+-row tiles
// with 8 waves; at 64x128/4-wave it is pure sync overhead. This config
// measured MLP2 < 73us (r7 bench).
#define GN 128
#define GK 64
#define GM 64
__global__ __launch_bounds__(256, 3) void gemm_mfma(const ushort* __restrict__ A,
                                                    const ushort* __restrict__ Bt,
                                                    const float* __restrict__ bias,
                                                    const float* __restrict__ res,
                                                    float* __restrict__ C,
                                                    ushort* __restrict__ Cb,
                                                    int M, int N, int K, int do_relu,
                                                    int scale_q) {
    __shared__ ushort As[2][GM * GK];
    __shared__ ushort Bs[2][GN * GK];
    const int tid  = threadIdx.x;
    const int lane = tid & 63, wave = tid >> 6;
    const int l16  = lane & 15, quad = lane >> 4;
    const int wr = wave >> 1, wc = wave & 1;

    // XCD-aware swizzle: give each XCD a contiguous row-major chunk
    const int nwg = gridDim.x * gridDim.y;
    int id = blockIdx.y * gridDim.x + blockIdx.x;
    if ((nwg & 7) == 0) {
        const int chunk = nwg >> 3;
        id = (id & 7) * chunk + (id >> 3);
    }
    const int bx = id % gridDim.x;
    const int by = id / gridDim.x;
    const int row0 = by * GM, col0 = bx * GN;

    f32x4 acc[2][4];
    #pragma unroll
    for (int i = 0; i < 2; ++i)
        #pragma unroll
        for (int j = 0; j < 4; ++j) acc[i][j] = (f32x4){0.f, 0.f, 0.f, 0.f};

    // staging: LDS chunk c=(m<<3)|j  <-  global chunk j^(m&7) of row m
    const ushort* Asrc[2];
    const ushort* Bsrc[4];
    #pragma unroll
    for (int i = 0; i < 2; ++i) {
        int c = tid + i * 256, m = c >> 3, j = c & 7;
        Asrc[i] = A + (size_t)(row0 + m) * K + (j ^ (m & 7)) * 8;
    }
    #pragma unroll
    for (int i = 0; i < 4; ++i) {
        int c = tid + i * 256, m = c >> 3, j = c & 7;
        Bsrc[i] = Bt + (size_t)(col0 + m) * K + (j ^ (m & 7)) * 8;
    }

    const int nk = K / GK;
    // prologue: stage K-tile 0 into buf 0
    #pragma unroll
    for (int i = 0; i < 2; ++i) GLDS16(Asrc[i], &As[0][(tid + i * 256) * 8]);
    #pragma unroll
    for (int i = 0; i < 4; ++i)  GLDS16(Bsrc[i], &Bs[0][(tid + i * 256) * 8]);

    for (int kt = 0; kt < nk; ++kt) {
        const int p = kt & 1;
        __syncthreads();   // drains buf[p] loads; all waves done reading buf[p^1]
        if (kt + 1 < nk) {
            const int k1 = (kt + 1) * GK;
            #pragma unroll
            for (int i = 0; i < 2; ++i) GLDS16(Asrc[i] + k1, &As[p ^ 1][(tid + i * 256) * 8]);
            #pragma unroll
            for (int i = 0; i < 4; ++i)  GLDS16(Bsrc[i] + k1, &Bs[p ^ 1][(tid + i * 256) * 8]);
        }

        #pragma unroll
        for (int s = 0; s < 2; ++s) {
            bf16x8 af[2], bfr[4];
            #pragma unroll
            for (int i = 0; i < 2; ++i) {
                int m = wr * 32 + i * 16 + l16;
                af[i] = *(const bf16x8*)&As[p][(m * 8 + (((s << 2) | quad) ^ (m & 7))) * 8];
            }
            #pragma unroll
            for (int j = 0; j < 4; ++j) {
                int n = wc * 64 + j * 16 + l16;
                bfr[j] = *(const bf16x8*)&Bs[p][(n * 8 + (((s << 2) | quad) ^ (n & 7))) * 8];
            }
            #pragma unroll
            for (int i = 0; i < 2; ++i)
                #pragma unroll
                for (int j = 0; j < 4; ++j)
                    acc[i][j] = __builtin_amdgcn_mfma_f32_16x16x32_bf16(af[i], bfr[j], acc[i][j], 0, 0, 0);
        }
    }

    // epilogue: C/D layout col=l16, row=quad*4+r
    #pragma unroll
    for (int i = 0; i < 2; ++i) {
        #pragma unroll
        for (int r = 0; r < 4; ++r) {
            int row = row0 + wr * 32 + i * 16 + quad * 4 + r;
            #pragma unroll
            for (int j = 0; j < 4; ++j) {
                int col = col0 + wc * 64 + j * 16 + l16;
                float v = acc[i][j][r];
                if (bias) v += bias[col];
                if (do_relu) v = fmaxf(v, 0.f);
                if (scale_q && col < DMODEL) v *= 0.125f;  // fold 1/sqrt(hs) into Q
                if (res) v += res[(size_t)row * N + col];
                if (Cb) Cb[(size_t)row * N + col] = f2b(v);
                else    C [(size_t)row * N + col] = v;
            }
        }
    }
}

// ---------------- gemm_big: 256x128, 8 waves x 64x64, BK=32, tri-buffer + counted vmcnt ----------------
// r16: KEPT from r8 (its time was masked by the gemm_mfma regression; this
// round isolates it). Pre-registered read: MLP1 >= 73us -> revert to r7's
// 128x128/512t next round; < 68us -> keep and iterate.
// Rationale (r15): 64x64/wave = 32 FLOP/LDS-byte (vs 21.3 at 32x64);
// conflicts fixed by row-pair layout (r5), drain fixed by counted vmcnt
// (r6), wave starvation fixed by 512t (r7). 72KB LDS -> 2 blocks/CU.
#define HM 256
#define HN 128
#define HK 32
__global__ __launch_bounds__(512, 4) void gemm_big(const ushort* __restrict__ A,
                                                   const ushort* __restrict__ Bt,
                                                   const float* __restrict__ bias,
                                                   const float* __restrict__ res,
                                                   float* __restrict__ C,
                                                   ushort* __restrict__ Cb,
                                                   int M, int N, int K, int do_relu,
                                                   int scale_q) {
    __shared__ ushort As[3][HM * HK];   // 3 x 16 KB
    __shared__ ushort Bs[3][HN * HK];   // 3 x 8 KB  -> 72 KB total
    const int tid  = threadIdx.x;
    const int lane = tid & 63, wave = tid >> 6;   // 0..7
    const int l16  = lane & 15, quad = lane >> 4;
    const int wr = wave & 3, wc = wave >> 2;      // 4x2 wave grid, 64x64/wave

    const int nwg = gridDim.x * gridDim.y;
    int id = blockIdx.y * gridDim.x + blockIdx.x;
    if ((nwg & 7) == 0) {
        const int chunk = nwg >> 3;
        id = (id & 7) * chunk + (id >> 3);
    }
    const int bx = id % gridDim.x;
    const int by = id / gridDim.x;
    const int row0 = by * HM, col0 = bx * HN;

    f32x4 acc[4][4];
    #pragma unroll
    for (int i = 0; i < 4; ++i)
        #pragma unroll
        for (int j = 0; j < 4; ++j) acc[i][j] = (f32x4){0.f, 0.f, 0.f, 0.f};

    // row-pair layout (zero-conflict, verified r5/r6)
    // A: 256x32 = 1024 chunks -> 2/thread; B: 128x32 = 512 chunks -> 1/thread
    const ushort* Asrc[2];
    const ushort* Bsrc;
    #pragma unroll
    for (int i = 0; i < 2; ++i) {
        int c = tid + i * 512, lr = c >> 3, pp = (c & 7) ^ (lr & 7);
        int m = lr * 2 + (pp >> 2), j = pp & 3;
        Asrc[i] = A + (size_t)(row0 + m) * K + j * 8;
    }
    {
        int c = tid, lr = c >> 3, pp = (c & 7) ^ (lr & 7);
        int m = lr * 2 + (pp >> 2), j = pp & 3;
        Bsrc = Bt + (size_t)(col0 + m) * K + j * 8;
    }

    const int nk = K / HK;   // 24

#define STAGE_BIG(kt, b) do { \
    const int _k = (kt) * HK; \
    GLDS16(Asrc[0] + _k, &As[b][tid * 8]); \
    GLDS16(Asrc[1] + _k, &As[b][(tid + 512) * 8]); \
    GLDS16(Bsrc + _k,    &Bs[b][tid * 8]); \
} while (0)

    STAGE_BIG(0, 0);
    STAGE_BIG(1, 1);

    int pc = 0, pn = 1, ps = 2;
    for (int t = 0; t < nk; ++t) {
        if (t + 1 < nk) asm volatile("s_waitcnt vmcnt(3)" ::: "memory");
        else            asm volatile("s_waitcnt vmcnt(0)" ::: "memory");
        __builtin_amdgcn_s_barrier();
        if (t + 2 < nk) STAGE_BIG(t + 2, ps);

        bf16x8 af[4], bfr[4];
        #pragma unroll
        for (int i = 0; i < 4; ++i) {
            int m = wr * 64 + i * 16 + l16;
            int ch = (m >> 1) * 8 + ((((m & 1) << 2) | quad) ^ ((m >> 1) & 7));
            af[i] = *(const bf16x8*)&As[pc][ch * 8];
        }
        #pragma unroll
        for (int j = 0; j < 4; ++j) {
            int n = wc * 64 + j * 16 + l16;
            int ch = (n >> 1) * 8 + ((((n & 1) << 2) | quad) ^ ((n >> 1) & 7));
            bfr[j] = *(const bf16x8*)&Bs[pc][ch * 8];
        }
        #pragma unroll
        for (int i = 0; i < 4; ++i)
            #pragma unroll
            for (int j = 0; j < 4; ++j)
                acc[i][j] = __builtin_amdgcn_mfma_f32_16x16x32_bf16(af[i], bfr[j], acc[i][j], 0, 0, 0);

        int tmp = pc; pc = pn; pn = ps; ps = tmp;
    }

    // epilogue: C/D layout col=l16, row=quad*4+r
    #pragma unroll
    for (int i = 0; i < 4; ++i) {
        #pragma unroll
        for (int r = 0; r < 4; ++r) {
            int row = row0 + wr * 64 + i * 16 + quad * 4 + r;
            #pragma unroll
            for (int j = 0; j < 4; ++j) {
                int col = col0 + wc * 64 + j * 16 + l16;
                float v = acc[i][j][r];
                if (bias) v += bias[col];
                if (do_relu) v = fmaxf(v, 0.f);
                if (scale_q && col < DMODEL) v *= 0.125f;
                if (res) v += res[(size_t)row * N + col];
                if (Cb) Cb[(size_t)row * N + col] = f2b(v);
                else    C [(size_t)row * N + col] = v;
            }
        }
    }
}

// ---------------- Flash attention: paired q-tiles, GLDS staging, dbuf ----------------
#define TQ 64
#define TK 64
#define PPAD 72
#define NQT (SEQ / TQ)   // 32

__global__ __launch_bounds__(256, 3) void fattn_kernel(const ushort* __restrict__ q,
                                                       const ushort* __restrict__ k,
                                                       const ushort* __restrict__ vt,
                                                       ushort* __restrict__ o,
                                                       int ldqkv) {
    const int pair = blockIdx.x;             // 0..15
    const int qts[2] = { pair, NQT - 1 - pair };
    const int bh = blockIdx.y;
    const int b = bh / NHEAD, h = bh % NHEAD;
    const int tid  = threadIdx.x;
    const int wave = tid >> 6;
    const int lane = tid & 63;
    const int l16  = lane & 15;
    const int quad = lane >> 4;

    __shared__ ushort Ks[2][TK * 64];    // 8 KB per buffer, packed [key][8 chunks]
    __shared__ ushort Vs[2][HS * 64];    // 8 KB per buffer, packed [d][8 chunks]
    __shared__ ushort Ps[4][16][PPAD];   // per-wave P[q][key] (wave-private)

    const size_t base  = ((size_t)b * SEQ) * ldqkv + (size_t)h * HS;
    const size_t baseO = ((size_t)b * SEQ) * DMODEL + (size_t)h * HS;
    const ushort* vth = vt + ((size_t)bh * HS) * SEQ;

    const int r0 = tid >> 3, j0 = (tid & 7) ^ (r0 & 7);
    const int r1 = (tid + 256) >> 3, j1 = (tid & 7) ^ (r1 & 7);
    const ushort* Ksrc0 = k + base + (size_t)r0 * ldqkv + j0 * 8;
    const ushort* Ksrc1 = k + base + (size_t)r1 * ldqkv + j1 * 8;
    const ushort* Vsrc0 = vth + (size_t)r0 * SEQ + j0 * 8;
    const ushort* Vsrc1 = vth + (size_t)r1 * SEQ + j1 * 8;

    bf16x8 qf[2][2];
    #pragma unroll
    for (int t = 0; t < 2; ++t) {
        int qrow = qts[t] * TQ + wave * 16 + l16;
        const ushort* qp = q + base + (size_t)qrow * ldqkv + quad * 8;
        qf[t][0] = *(const bf16x8*)(qp);
        qf[t][1] = *(const bf16x8*)(qp + 32);
    }

    f32x4 Oacc[2][4];
    float lrow[2][4];
    #pragma unroll
    for (int t = 0; t < 2; ++t) {
        #pragma unroll
        for (int f = 0; f < 4; ++f) Oacc[t][f] = (f32x4){0.f, 0.f, 0.f, 0.f};
        #pragma unroll
        for (int r = 0; r < 4; ++r) lrow[t][r] = 0.f;
    }

    const int ktiles = qts[1] + 1;
    GLDS16(Ksrc0, &Ks[0][tid * 8]);
    GLDS16(Ksrc1, &Ks[0][(tid + 256) * 8]);
    GLDS16(Vsrc0, &Vs[0][tid * 8]);
    GLDS16(Vsrc1, &Vs[0][(tid + 256) * 8]);

    for (int kt = 0; kt < ktiles; ++kt) {
        const int p = kt & 1;
        __syncthreads();   // drains buf[p] (in flight since last compute phase)
        if (kt + 1 < ktiles) {
            const size_t ko = (size_t)(kt + 1) * TK;
            GLDS16(Ksrc0 + ko * ldqkv, &Ks[p ^ 1][tid * 8]);
            GLDS16(Ksrc1 + ko * ldqkv, &Ks[p ^ 1][(tid + 256) * 8]);
            GLDS16(Vsrc0 + ko,         &Vs[p ^ 1][tid * 8]);
            GLDS16(Vsrc1 + ko,         &Vs[p ^ 1][(tid + 256) * 8]);
        }

        bf16x8 kb[4][2], vb[4][2];
        #pragma unroll
        for (int f = 0; f < 4; ++f) {
            int row = f * 16 + l16;
            kb[f][0] = *(const bf16x8*)&Ks[p][(row * 8 + (quad ^ (row & 7))) * 8];
            kb[f][1] = *(const bf16x8*)&Ks[p][(row * 8 + ((4 | quad) ^ (row & 7))) * 8];
            vb[f][0] = *(const bf16x8*)&Vs[p][(row * 8 + (quad ^ (row & 7))) * 8];
            vb[f][1] = *(const bf16x8*)&Vs[p][(row * 8 + ((4 | quad) ^ (row & 7))) * 8];
        }

        #pragma unroll
        for (int t = 0; t < 2; ++t) {
            const int qt = qts[t];
            if (kt > qt) continue;   // wave-uniform; only t=0 can skip

            f32x4 S[4];
            #pragma unroll
            for (int f = 0; f < 4; ++f) {
                f32x4 a = (f32x4){0.f, 0.f, 0.f, 0.f};
                a = __builtin_amdgcn_mfma_f32_16x16x32_bf16(qf[t][0], kb[f][0], a, 0, 0, 0);
                a = __builtin_amdgcn_mfma_f32_16x16x32_bf16(qf[t][1], kb[f][1], a, 0, 0, 0);
                S[f] = a;
            }

            const int qrow_base = qt * TQ + wave * 16 + quad * 4;
            if (kt == qt) {
                #pragma unroll
                for (int f = 0; f < 4; ++f) {
                    int key = kt * TK + f * 16 + l16;
                    #pragma unroll
                    for (int r = 0; r < 4; ++r)
                        if (key > qrow_base + r) S[f][r] = -INFINITY;
                }
            }

            #pragma unroll
            for (int f = 0; f < 4; ++f) {
                #pragma unroll
                for (int r = 0; r < 4; ++r) {
                    float pv = __expf(S[f][r]);
                    S[f][r] = pv;
                    lrow[t][r] += pv;
                }
            }

            #pragma unroll
            for (int f = 0; f < 4; ++f)
                #pragma unroll
                for (int r = 0; r < 4; ++r)
                    Ps[wave][quad * 4 + r][f * 16 + l16] = f2b(S[f][r]);

            bf16x8 pa0 = *(const bf16x8*)&Ps[wave][l16][quad * 8];
            bf16x8 pa1 = *(const bf16x8*)&Ps[wave][l16][32 + quad * 8];
            #pragma unroll
            for (int f = 0; f < 4; ++f) {
                Oacc[t][f] = __builtin_amdgcn_mfma_f32_16x16x32_bf16(pa0, vb[f][0], Oacc[t][f], 0, 0, 0);
                Oacc[t][f] = __builtin_amdgcn_mfma_f32_16x16x32_bf16(pa1, vb[f][1], Oacc[t][f], 0, 0, 0);
            }
        }
    }

    #pragma unroll
    for (int t = 0; t < 2; ++t) {
        const int qrow = qts[t] * TQ + wave * 16 + quad * 4;
        #pragma unroll
        for (int r = 0; r < 4; ++r) {
            float l = lrow[t][r];
            #pragma unroll
            for (int m = 1; m < 16; m <<= 1) l += __shfl_xor(l, m, 64);
            float invl = 1.f / l;
            #pragma unroll
            for (int f = 0; f < 4; ++f)
                o[baseO + (size_t)(qrow + r) * DMODEL + f * 16 + l16] = f2b(Oacc[t][f][r] * invl);
        }
    }
}

// ---------------- Host launcher ----------------
extern "C" void kernel_launch(void* const* d_in, const int* in_sizes, int n_in,
                              void* d_out, int out_size, void* d_ws, size_t ws_size,
                              hipStream_t stream) {
    const float* x      = (const float*)d_in[0];
    const float* wq     = (const float*)d_in[1];
    const float* wk     = (const float*)d_in[2];
    const float* wv     = (const float*)d_in[3];
    const float* wo     = (const float*)d_in[4];
    const float* w1     = (const float*)d_in[5];
    const float* b1     = (const float*)d_in[6];
    const float* w2     = (const float*)d_in[7];
    const float* b2     = (const float*)d_in[8];
    const float* gamma1 = (const float*)d_in[9];
    const float* beta1  = (const float*)d_in[10];
    const float* gamma2 = (const float*)d_in[11];
    const float* beta2  = (const float*)d_in[12];
    float* out = (float*)d_out;

    char* ws = (char*)d_ws;
    ushort* buf_xn   = (ushort*)ws;                              // 8192*768
    ushort* buf_attn = buf_xn;
    ushort* buf_qkv  = (ushort*)(ws + 12582912);                 // 8192*2304
    ushort* buf_h    = buf_qkv;                                  // 8192*3072
    ushort* w_qkv    = (ushort*)(ws + 12582912 + 50331648);      // 2304*768
    ushort* w_ot     = w_qkv + (size_t)QKVN * DMODEL;
    ushort* w_1t     = w_ot + (size_t)DMODEL * DMODEL;
    ushort* w_2t     = w_1t + (size_t)HID * DMODEL;
    // V^T lives in d_out (free until step 4; stream-serial)
    ushort* buf_vt   = (ushort*)d_out;

    convert_w4<<<dim3(DMODEL/32, DMODEL/32, 4), 256, 0, stream>>>(wq, wk, wv, wo, w_qkv);
    convert_w<<<dim3(HID/32,    DMODEL/32), 256, 0, stream>>>(w1, w_1t, DMODEL, HID);
    convert_w<<<dim3(DMODEL/32, HID/32),    256, 0, stream>>>(w2, w_2t, HID, DMODEL);

    // 1) xn1 = LN(x)
    ln_kernel<<<NROWS, 256, 0, stream>>>(x, gamma1, beta1, buf_xn);
    // 2) qkv = xn1 @ [wq|wk|wv], Q cols pre-scaled by 0.125 (gemm_big 256x128, 512t)
    gemm_big<<<dim3(QKVN/HN, NROWS/HM), 512, 0, stream>>>(buf_xn, w_qkv, nullptr, nullptr,
                                                          nullptr, buf_qkv, NROWS, QKVN, DMODEL, 0, 1);
    // 2b) V -> V^T per head (into d_out scratch)
    transpose_v<<<dim3(SEQ/64, BATCH*NHEAD), 256, 0, stream>>>(buf_qkv + 2*DMODEL, buf_vt);
    // 3) flash attention (paired q-tiles, GLDS dbuf staging, fixed-max softmax)
    fattn_kernel<<<dim3(NQT/2, BATCH*NHEAD), 256, 0, stream>>>(buf_qkv, buf_qkv + DMODEL,
                                                               buf_vt, buf_attn, QKVN);
    // 4) x1 = x + attn @ wo (N=768 -> gemm_mfma BK=64 dbuf, proven config)
    gemm_mfma<<<dim3(DMODEL/GN, NROWS/GM), 256, 0, stream>>>(buf_attn, w_ot, nullptr, x,
                                                             out, nullptr, NROWS, DMODEL, DMODEL, 0, 0);
    // 5) xn2 = LN(x1)
    ln_kernel<<<NROWS, 256, 0, stream>>>(out, gamma2, beta2, buf_xn);
    // 6) h = relu(xn2 @ w1 + b1) (gemm_big 256x128, 512t)
    gemm_big<<<dim3(HID/HN, NROWS/HM), 512, 0, stream>>>(buf_xn, w_1t, b1, nullptr,
                                                         nullptr, buf_h, NROWS, HID, DMODEL, 1, 0);
    // 7) out = x1 + h @ w2 + b2 (N=768 -> gemm_mfma BK=64 dbuf, proven config)
    gemm_mfma<<<dim3(DMODEL/GN, NROWS/GM), 256, 0, stream>>>(buf_h, w_2t, b2, out,
                                                             out, nullptr, NROWS, DMODEL, HID, 0, 0);
}

// Round 10
// 398.629 us; speedup vs baseline: 1.1106x; 1.0415x over previous
//
#include <hip/hip_runtime.h>
#include <hip/hip_bf16.h>
#include <math.h>

// Problem constants (match reference)
#define BATCH 4
#define SEQ   2048
#define DMODEL 768
#define NHEAD 12
#define HS    64
#define HID   3072   // 4*DMODEL
#define NROWS (BATCH*SEQ)   // 8192
#define QKVN  (3*DMODEL)    // 2304
#define EPS   1e-6f

typedef __attribute__((ext_vector_type(8))) short bf16x8;
typedef __attribute__((ext_vector_type(4))) float f32x4;

__device__ inline ushort f2b(float f) {
    union { float f; unsigned u; } x; x.f = f;
    unsigned u = x.u;
    unsigned r = (u + 0x7FFFu + ((u >> 16) & 1u)) >> 16;
    return (ushort)r;
}

// async global->LDS, 16B per lane (m97)
#define GLDS16(g, l) __builtin_amdgcn_global_load_lds( \
    (const __attribute__((address_space(1))) void*)(g), \
    (__attribute__((address_space(3))) void*)(l), 16, 0, 0)

// ---------------- Weight convert+transpose: fp32 [K][N] -> bf16 [N][K] ----------------
__global__ __launch_bounds__(256) void convert_w4(const float* __restrict__ p0,
                                                  const float* __restrict__ p1,
                                                  const float* __restrict__ p2,
                                                  const float* __restrict__ p3,
                                                  ushort* __restrict__ out) {
    const float* srcs[4] = { p0, p1, p2, p3 };
    const float* in = srcs[blockIdx.z];
    ushort* dst = out + (size_t)blockIdx.z * DMODEL * DMODEL;
    __shared__ float tile[32][33];
    const int bx = blockIdx.x * 32;  // N
    const int by = blockIdx.y * 32;  // K
    const int tx = threadIdx.x & 31, ty = threadIdx.x >> 5;
    #pragma unroll
    for (int i = 0; i < 32; i += 8)
        tile[ty + i][tx] = in[(size_t)(by + ty + i) * DMODEL + bx + tx];
    __syncthreads();
    #pragma unroll
    for (int i = 0; i < 32; i += 8)
        dst[(size_t)(bx + ty + i) * DMODEL + by + tx] = f2b(tile[tx][ty + i]);
}

__global__ __launch_bounds__(256) void convert_w(const float* __restrict__ in,
                                                 ushort* __restrict__ out,
                                                 int K, int N) {
    __shared__ float tile[32][33];
    const int bx = blockIdx.x * 32;  // N
    const int by = blockIdx.y * 32;  // K
    const int tx = threadIdx.x & 31, ty = threadIdx.x >> 5;
    #pragma unroll
    for (int i = 0; i < 32; i += 8)
        tile[ty + i][tx] = in[(size_t)(by + ty + i) * N + bx + tx];
    __syncthreads();
    #pragma unroll
    for (int i = 0; i < 32; i += 8)
        out[(size_t)(bx + ty + i) * K + by + tx] = f2b(tile[tx][ty + i]);
}

// ---------------- V transpose: v[b][s][h*64+d] (stride QKVN) -> vt[(bh*64+d)][s] ----------------
__global__ __launch_bounds__(256) void transpose_v(const ushort* __restrict__ v,
                                                   ushort* __restrict__ vt) {
    const int st = blockIdx.x;   // key tile (64 rows)
    const int bh = blockIdx.y;
    const int b = bh / NHEAD, h = bh % NHEAD;
    const ushort* src = v + ((size_t)b * SEQ) * QKVN + h * HS;
    ushort* dst = vt + ((size_t)bh * HS) * SEQ;
    __shared__ ushort t[64][65];
    const int col = threadIdx.x & 63;
    const int r0  = (threadIdx.x >> 6) * 16;
    #pragma unroll
    for (int i = 0; i < 16; ++i)
        t[col][r0 + i] = src[(size_t)(st * 64 + r0 + i) * QKVN + col];
    __syncthreads();
    #pragma unroll
    for (int i = 0; i < 16; ++i)
        dst[(size_t)(r0 + i) * SEQ + st * 64 + col] = t[r0 + i][col];
}

// ---------------- LayerNorm (ddof=1), fp32 in -> bf16 out ----------------
__global__ __launch_bounds__(256) void ln_kernel(const float* __restrict__ x,
                                                 const float* __restrict__ gamma,
                                                 const float* __restrict__ beta,
                                                 ushort* __restrict__ out) {
    const int row = blockIdx.x;
    const float* xr = x + (size_t)row * DMODEL;
    float s = 0.f, s2 = 0.f;
    for (int i = threadIdx.x; i < DMODEL; i += 256) {
        float v = xr[i];
        s += v; s2 += v * v;
    }
    for (int off = 32; off > 0; off >>= 1) {
        s  += __shfl_down(s,  off, 64);
        s2 += __shfl_down(s2, off, 64);
    }
    __shared__ float shs[4], shs2[4];
    int wid = threadIdx.x >> 6, lane = threadIdx.x & 63;
    if (lane == 0) { shs[wid] = s; shs2[wid] = s2; }
    __syncthreads();
    __shared__ float smean, srstd;
    if (threadIdx.x == 0) {
        float S  = shs[0] + shs[1] + shs[2] + shs[3];
        float S2 = shs2[0] + shs2[1] + shs2[2] + shs2[3];
        float mean = S / DMODEL;
        float var  = (S2 - DMODEL * mean * mean) / (DMODEL - 1);
        smean = mean;
        srstd = rsqrtf(var + EPS);
    }
    __syncthreads();
    float mean = smean, rstd = srstd;
    ushort* orow = out + (size_t)row * DMODEL;
    for (int i = threadIdx.x; i < DMODEL; i += 256) {
        orow[i] = f2b(gamma[i] * (xr[i] - mean) * rstd + beta[i]);
    }
}

// ---------------- gemm_mfma: 64x128 tile, BK=64, per-wave 32x64 (N=768) ----------------
// r2/r7-proven config (MLP2 < 73us). BK=32 tri-buffer regressed here (r8):
// doubles sync frequency at only 8 MFMAs/step. Do not touch.
#define GN 128
#define GK 64
#define GM 64
__global__ __launch_bounds__(256, 3) void gemm_mfma(const ushort* __restrict__ A,
                                                    const ushort* __restrict__ Bt,
                                                    const float* __restrict__ bias,
                                                    const float* __restrict__ res,
                                                    float* __restrict__ C,
                                                    ushort* __restrict__ Cb,
                                                    int M, int N, int K, int do_relu,
                                                    int scale_q) {
    __shared__ ushort As[2][GM * GK];
    __shared__ ushort Bs[2][GN * GK];
    const int tid  = threadIdx.x;
    const int lane = tid & 63, wave = tid >> 6;
    const int l16  = lane & 15, quad = lane >> 4;
    const int wr = wave >> 1, wc = wave & 1;

    // XCD-aware swizzle: give each XCD a contiguous row-major chunk
    const int nwg = gridDim.x * gridDim.y;
    int id = blockIdx.y * gridDim.x + blockIdx.x;
    if ((nwg & 7) == 0) {
        const int chunk = nwg >> 3;
        id = (id & 7) * chunk + (id >> 3);
    }
    const int bx = id % gridDim.x;
    const int by = id / gridDim.x;
    const int row0 = by * GM, col0 = bx * GN;

    f32x4 acc[2][4];
    #pragma unroll
    for (int i = 0; i < 2; ++i)
        #pragma unroll
        for (int j = 0; j < 4; ++j) acc[i][j] = (f32x4){0.f, 0.f, 0.f, 0.f};

    // staging: LDS chunk c=(m<<3)|j  <-  global chunk j^(m&7) of row m
    const ushort* Asrc[2];
    const ushort* Bsrc[4];
    #pragma unroll
    for (int i = 0; i < 2; ++i) {
        int c = tid + i * 256, m = c >> 3, j = c & 7;
        Asrc[i] = A + (size_t)(row0 + m) * K + (j ^ (m & 7)) * 8;
    }
    #pragma unroll
    for (int i = 0; i < 4; ++i) {
        int c = tid + i * 256, m = c >> 3, j = c & 7;
        Bsrc[i] = Bt + (size_t)(col0 + m) * K + (j ^ (m & 7)) * 8;
    }

    const int nk = K / GK;
    // prologue: stage K-tile 0 into buf 0
    #pragma unroll
    for (int i = 0; i < 2; ++i) GLDS16(Asrc[i], &As[0][(tid + i * 256) * 8]);
    #pragma unroll
    for (int i = 0; i < 4; ++i)  GLDS16(Bsrc[i], &Bs[0][(tid + i * 256) * 8]);

    for (int kt = 0; kt < nk; ++kt) {
        const int p = kt & 1;
        __syncthreads();   // drains buf[p] loads; all waves done reading buf[p^1]
        if (kt + 1 < nk) {
            const int k1 = (kt + 1) * GK;
            #pragma unroll
            for (int i = 0; i < 2; ++i) GLDS16(Asrc[i] + k1, &As[p ^ 1][(tid + i * 256) * 8]);
            #pragma unroll
            for (int i = 0; i < 4; ++i)  GLDS16(Bsrc[i] + k1, &Bs[p ^ 1][(tid + i * 256) * 8]);
        }

        #pragma unroll
        for (int s = 0; s < 2; ++s) {
            bf16x8 af[2], bfr[4];
            #pragma unroll
            for (int i = 0; i < 2; ++i) {
                int m = wr * 32 + i * 16 + l16;
                af[i] = *(const bf16x8*)&As[p][(m * 8 + (((s << 2) | quad) ^ (m & 7))) * 8];
            }
            #pragma unroll
            for (int j = 0; j < 4; ++j) {
                int n = wc * 64 + j * 16 + l16;
                bfr[j] = *(const bf16x8*)&Bs[p][(n * 8 + (((s << 2) | quad) ^ (n & 7))) * 8];
            }
            #pragma unroll
            for (int i = 0; i < 2; ++i)
                #pragma unroll
                for (int j = 0; j < 4; ++j)
                    acc[i][j] = __builtin_amdgcn_mfma_f32_16x16x32_bf16(af[i], bfr[j], acc[i][j], 0, 0, 0);
        }
    }

    // epilogue: C/D layout col=l16, row=quad*4+r
    #pragma unroll
    for (int i = 0; i < 2; ++i) {
        #pragma unroll
        for (int r = 0; r < 4; ++r) {
            int row = row0 + wr * 32 + i * 16 + quad * 4 + r;
            #pragma unroll
            for (int j = 0; j < 4; ++j) {
                int col = col0 + wc * 64 + j * 16 + l16;
                float v = acc[i][j][r];
                if (bias) v += bias[col];
                if (do_relu) v = fmaxf(v, 0.f);
                if (scale_q && col < DMODEL) v *= 0.125f;  // fold 1/sqrt(hs) into Q
                if (res) v += res[(size_t)row * N + col];
                if (Cb) Cb[(size_t)row * N + col] = f2b(v);
                else    C [(size_t)row * N + col] = v;
            }
        }
    }
}

// ---------------- gemm_big: 128x128, BK=32, 512 threads, tri-buffer + counted vmcnt ----------------
// r17: REVERT to r7's proven config (best MLP1 = 73us, occ 54%). r9's
// 256x128 isolated at 82us (72KB LDS -> 2 blocks/CU; occupancy loss beats
// LDS-traffic gain). Tile table for MLP1 is now complete; 128x128/512t is
// the local optimum of this structure.
// NEW (single addition): T5 s_setprio(1) around the MFMA cluster. m190's
// null was single-block lockstep; here 3 blocks/CU + counted-vmcnt stagger
// gives cross-block role diversity for the CU scheduler to arbitrate.
// Attribution: r7 measured MLP1 73.0 +/- 0.3; any delta beyond that is
// setprio's.
#define HM 128
#define HN 128
#define HK 32
__global__ __launch_bounds__(512, 6) void gemm_big(const ushort* __restrict__ A,
                                                   const ushort* __restrict__ Bt,
                                                   const float* __restrict__ bias,
                                                   const float* __restrict__ res,
                                                   float* __restrict__ C,
                                                   ushort* __restrict__ Cb,
                                                   int M, int N, int K, int do_relu,
                                                   int scale_q) {
    __shared__ ushort As[3][HM * HK];   // 3 x 8 KB
    __shared__ ushort Bs[3][HN * HK];   // 3 x 8 KB  -> 48 KB total
    const int tid  = threadIdx.x;
    const int lane = tid & 63, wave = tid >> 6;   // 0..7
    const int l16  = lane & 15, quad = lane >> 4;
    const int wr = wave & 3, wc = wave >> 2;      // 4x2 wave grid, 32x64/wave

    const int nwg = gridDim.x * gridDim.y;
    int id = blockIdx.y * gridDim.x + blockIdx.x;
    if ((nwg & 7) == 0) {
        const int chunk = nwg >> 3;
        id = (id & 7) * chunk + (id >> 3);
    }
    const int bx = id % gridDim.x;
    const int by = id / gridDim.x;
    const int row0 = by * HM, col0 = bx * HN;

    f32x4 acc[2][4];
    #pragma unroll
    for (int i = 0; i < 2; ++i)
        #pragma unroll
        for (int j = 0; j < 4; ++j) acc[i][j] = (f32x4){0.f, 0.f, 0.f, 0.f};

    // row-pair layout: LDS chunk c = lr*8+pos holds global (m = 2*lr + (p>>2), j = p&3)
    // where p = pos ^ (lr&7)   [zero-conflict, verified r5/r6/r7]
    const ushort* Asrc;
    const ushort* Bsrc;
    {
        int c = tid;
        int lr = c >> 3, pp = (c & 7) ^ (lr & 7);
        int m = lr * 2 + (pp >> 2), j = pp & 3;
        Asrc = A  + (size_t)(row0 + m) * K + j * 8;
        Bsrc = Bt + (size_t)(col0 + m) * K + j * 8;
    }

    const int nk = K / HK;   // K=768 -> 24

    // 2 vmcnt-instructions per tile-stage (A,B)
#define STAGE_BIG(kt, b) do { \
    const int _k = (kt) * HK; \
    GLDS16(Asrc + _k, &As[b][tid * 8]); \
    GLDS16(Bsrc + _k, &Bs[b][tid * 8]); \
} while (0)

    STAGE_BIG(0, 0);
    STAGE_BIG(1, 1);

    int pc = 0, pn = 1, ps = 2;   // compute / next / stage-target buffers
    for (int t = 0; t < nk; ++t) {
        // wait tile t only: tile t+1's 2 loads stay in flight
        if (t + 1 < nk) asm volatile("s_waitcnt vmcnt(2)" ::: "memory");
        else            asm volatile("s_waitcnt vmcnt(0)" ::: "memory");
        __builtin_amdgcn_s_barrier();
        if (t + 2 < nk) STAGE_BIG(t + 2, ps);

        bf16x8 af[2], bfr[4];
        #pragma unroll
        for (int i = 0; i < 2; ++i) {
            int m = wr * 32 + i * 16 + l16;
            int ch = (m >> 1) * 8 + ((((m & 1) << 2) | quad) ^ ((m >> 1) & 7));
            af[i] = *(const bf16x8*)&As[pc][ch * 8];
        }
        #pragma unroll
        for (int j = 0; j < 4; ++j) {
            int n = wc * 64 + j * 16 + l16;
            int ch = (n >> 1) * 8 + ((((n & 1) << 2) | quad) ^ ((n >> 1) & 7));
            bfr[j] = *(const bf16x8*)&Bs[pc][ch * 8];
        }
        __builtin_amdgcn_s_setprio(1);
        #pragma unroll
        for (int i = 0; i < 2; ++i)
            #pragma unroll
            for (int j = 0; j < 4; ++j)
                acc[i][j] = __builtin_amdgcn_mfma_f32_16x16x32_bf16(af[i], bfr[j], acc[i][j], 0, 0, 0);
        __builtin_amdgcn_s_setprio(0);

        int tmp = pc; pc = pn; pn = ps; ps = tmp;
    }

    // epilogue: C/D layout col=l16, row=quad*4+r
    #pragma unroll
    for (int i = 0; i < 2; ++i) {
        #pragma unroll
        for (int r = 0; r < 4; ++r) {
            int row = row0 + wr * 32 + i * 16 + quad * 4 + r;
            #pragma unroll
            for (int j = 0; j < 4; ++j) {
                int col = col0 + wc * 64 + j * 16 + l16;
                float v = acc[i][j][r];
                if (bias) v += bias[col];
                if (do_relu) v = fmaxf(v, 0.f);
                if (scale_q && col < DMODEL) v *= 0.125f;  // fold 1/sqrt(hs) into Q
                if (res) v += res[(size_t)row * N + col];
                if (Cb) Cb[(size_t)row * N + col] = f2b(v);
                else    C [(size_t)row * N + col] = v;
            }
        }
    }
}

// ---------------- Flash attention: paired q-tiles, GLDS staging, dbuf ----------------
#define TQ 64
#define TK 64
#define PPAD 72
#define NQT (SEQ / TQ)   // 32

__global__ __launch_bounds__(256, 3) void fattn_kernel(const ushort* __restrict__ q,
                                                       const ushort* __restrict__ k,
                                                       const ushort* __restrict__ vt,
                                                       ushort* __restrict__ o,
                                                       int ldqkv) {
    const int pair = blockIdx.x;             // 0..15
    const int qts[2] = { pair, NQT - 1 - pair };
    const int bh = blockIdx.y;
    const int b = bh / NHEAD, h = bh % NHEAD;
    const int tid  = threadIdx.x;
    const int wave = tid >> 6;
    const int lane = tid & 63;
    const int l16  = lane & 15;
    const int quad = lane >> 4;

    __shared__ ushort Ks[2][TK * 64];    // 8 KB per buffer, packed [key][8 chunks]
    __shared__ ushort Vs[2][HS * 64];    // 8 KB per buffer, packed [d][8 chunks]
    __shared__ ushort Ps[4][16][PPAD];   // per-wave P[q][key] (wave-private)

    const size_t base  = ((size_t)b * SEQ) * ldqkv + (size_t)h * HS;
    const size_t baseO = ((size_t)b * SEQ) * DMODEL + (size_t)h * HS;
    const ushort* vth = vt + ((size_t)bh * HS) * SEQ;

    const int r0 = tid >> 3, j0 = (tid & 7) ^ (r0 & 7);
    const int r1 = (tid + 256) >> 3, j1 = (tid & 7) ^ (r1 & 7);
    const ushort* Ksrc0 = k + base + (size_t)r0 * ldqkv + j0 * 8;
    const ushort* Ksrc1 = k + base + (size_t)r1 * ldqkv + j1 * 8;
    const ushort* Vsrc0 = vth + (size_t)r0 * SEQ + j0 * 8;
    const ushort* Vsrc1 = vth + (size_t)r1 * SEQ + j1 * 8;

    bf16x8 qf[2][2];
    #pragma unroll
    for (int t = 0; t < 2; ++t) {
        int qrow = qts[t] * TQ + wave * 16 + l16;
        const ushort* qp = q + base + (size_t)qrow * ldqkv + quad * 8;
        qf[t][0] = *(const bf16x8*)(qp);
        qf[t][1] = *(const bf16x8*)(qp + 32);
    }

    f32x4 Oacc[2][4];
    float lrow[2][4];
    #pragma unroll
    for (int t = 0; t < 2; ++t) {
        #pragma unroll
        for (int f = 0; f < 4; ++f) Oacc[t][f] = (f32x4){0.f, 0.f, 0.f, 0.f};
        #pragma unroll
        for (int r = 0; r < 4; ++r) lrow[t][r] = 0.f;
    }

    const int ktiles = qts[1] + 1;
    GLDS16(Ksrc0, &Ks[0][tid * 8]);
    GLDS16(Ksrc1, &Ks[0][(tid + 256) * 8]);
    GLDS16(Vsrc0, &Vs[0][tid * 8]);
    GLDS16(Vsrc1, &Vs[0][(tid + 256) * 8]);

    for (int kt = 0; kt < ktiles; ++kt) {
        const int p = kt & 1;
        __syncthreads();   // drains buf[p] (in flight since last compute phase)
        if (kt + 1 < ktiles) {
            const size_t ko = (size_t)(kt + 1) * TK;
            GLDS16(Ksrc0 + ko * ldqkv, &Ks[p ^ 1][tid * 8]);
            GLDS16(Ksrc1 + ko * ldqkv, &Ks[p ^ 1][(tid + 256) * 8]);
            GLDS16(Vsrc0 + ko,         &Vs[p ^ 1][tid * 8]);
            GLDS16(Vsrc1 + ko,         &Vs[p ^ 1][(tid + 256) * 8]);
        }

        bf16x8 kb[4][2], vb[4][2];
        #pragma unroll
        for (int f = 0; f < 4; ++f) {
            int row = f * 16 + l16;
            kb[f][0] = *(const bf16x8*)&Ks[p][(row * 8 + (quad ^ (row & 7))) * 8];
            kb[f][1] = *(const bf16x8*)&Ks[p][(row * 8 + ((4 | quad) ^ (row & 7))) * 8];
            vb[f][0] = *(const bf16x8*)&Vs[p][(row * 8 + (quad ^ (row & 7))) * 8];
            vb[f][1] = *(const bf16x8*)&Vs[p][(row * 8 + ((4 | quad) ^ (row & 7))) * 8];
        }

        #pragma unroll
        for (int t = 0; t < 2; ++t) {
            const int qt = qts[t];
            if (kt > qt) continue;   // wave-uniform; only t=0 can skip

            f32x4 S[4];
            #pragma unroll
            for (int f = 0; f < 4; ++f) {
                f32x4 a = (f32x4){0.f, 0.f, 0.f, 0.f};
                a = __builtin_amdgcn_mfma_f32_16x16x32_bf16(qf[t][0], kb[f][0], a, 0, 0, 0);
                a = __builtin_amdgcn_mfma_f32_16x16x32_bf16(qf[t][1], kb[f][1], a, 0, 0, 0);
                S[f] = a;
            }

            const int qrow_base = qt * TQ + wave * 16 + quad * 4;
            if (kt == qt) {
                #pragma unroll
                for (int f = 0; f < 4; ++f) {
                    int key = kt * TK + f * 16 + l16;
                    #pragma unroll
                    for (int r = 0; r < 4; ++r)
                        if (key > qrow_base + r) S[f][r] = -INFINITY;
                }
            }

            #pragma unroll
            for (int f = 0; f < 4; ++f) {
                #pragma unroll
                for (int r = 0; r < 4; ++r) {
                    float pv = __expf(S[f][r]);
                    S[f][r] = pv;
                    lrow[t][r] += pv;
                }
            }

            #pragma unroll
            for (int f = 0; f < 4; ++f)
                #pragma unroll
                for (int r = 0; r < 4; ++r)
                    Ps[wave][quad * 4 + r][f * 16 + l16] = f2b(S[f][r]);

            bf16x8 pa0 = *(const bf16x8*)&Ps[wave][l16][quad * 8];
            bf16x8 pa1 = *(const bf16x8*)&Ps[wave][l16][32 + quad * 8];
            #pragma unroll
            for (int f = 0; f < 4; ++f) {
                Oacc[t][f] = __builtin_amdgcn_mfma_f32_16x16x32_bf16(pa0, vb[f][0], Oacc[t][f], 0, 0, 0);
                Oacc[t][f] = __builtin_amdgcn_mfma_f32_16x16x32_bf16(pa1, vb[f][1], Oacc[t][f], 0, 0, 0);
            }
        }
    }

    #pragma unroll
    for (int t = 0; t < 2; ++t) {
        const int qrow = qts[t] * TQ + wave * 16 + quad * 4;
        #pragma unroll
        for (int r = 0; r < 4; ++r) {
            float l = lrow[t][r];
            #pragma unroll
            for (int m = 1; m < 16; m <<= 1) l += __shfl_xor(l, m, 64);
            float invl = 1.f / l;
            #pragma unroll
            for (int f = 0; f < 4; ++f)
                o[baseO + (size_t)(qrow + r) * DMODEL + f * 16 + l16] = f2b(Oacc[t][f][r] * invl);
        }
    }
}

// ---------------- Host launcher ----------------
extern "C" void kernel_launch(void* const* d_in, const int* in_sizes, int n_in,
                              void* d_out, int out_size, void* d_ws, size_t ws_size,
                              hipStream_t stream) {
    const float* x      = (const float*)d_in[0];
    const float* wq     = (const float*)d_in[1];
    const float* wk     = (const float*)d_in[2];
    const float* wv     = (const float*)d_in[3];
    const float* wo     = (const float*)d_in[4];
    const float* w1     = (const float*)d_in[5];
    const float* b1     = (const float*)d_in[6];
    const float* w2     = (const float*)d_in[7];
    const float* b2     = (const float*)d_in[8];
    const float* gamma1 = (const float*)d_in[9];
    const float* beta1  = (const float*)d_in[10];
    const float* gamma2 = (const float*)d_in[11];
    const float* beta2  = (const float*)d_in[12];
    float* out = (float*)d_out;

    char* ws = (char*)d_ws;
    ushort* buf_xn   = (ushort*)ws;                              // 8192*768
    ushort* buf_attn = buf_xn;
    ushort* buf_qkv  = (ushort*)(ws + 12582912);                 // 8192*2304
    ushort* buf_h    = buf_qkv;                                  // 8192*3072
    ushort* w_qkv    = (ushort*)(ws + 12582912 + 50331648);      // 2304*768
    ushort* w_ot     = w_qkv + (size_t)QKVN * DMODEL;
    ushort* w_1t     = w_ot + (size_t)DMODEL * DMODEL;
    ushort* w_2t     = w_1t + (size_t)HID * DMODEL;
    // V^T lives in d_out (free until step 4; stream-serial)
    ushort* buf_vt   = (ushort*)d_out;

    convert_w4<<<dim3(DMODEL/32, DMODEL/32, 4), 256, 0, stream>>>(wq, wk, wv, wo, w_qkv);
    convert_w<<<dim3(HID/32,    DMODEL/32), 256, 0, stream>>>(w1, w_1t, DMODEL, HID);
    convert_w<<<dim3(DMODEL/32, HID/32),    256, 0, stream>>>(w2, w_2t, HID, DMODEL);

    // 1) xn1 = LN(x)
    ln_kernel<<<NROWS, 256, 0, stream>>>(x, gamma1, beta1, buf_xn);
    // 2) qkv = xn1 @ [wq|wk|wv], Q cols pre-scaled by 0.125 (gemm_big 128x128, 512t)
    gemm_big<<<dim3(QKVN/HN, NROWS/HM), 512, 0, stream>>>(buf_xn, w_qkv, nullptr, nullptr,
                                                          nullptr, buf_qkv, NROWS, QKVN, DMODEL, 0, 1);
    // 2b) V -> V^T per head (into d_out scratch)
    transpose_v<<<dim3(SEQ/64, BATCH*NHEAD), 256, 0, stream>>>(buf_qkv + 2*DMODEL, buf_vt);
    // 3) flash attention (paired q-tiles, GLDS dbuf staging, fixed-max softmax)
    fattn_kernel<<<dim3(NQT/2, BATCH*NHEAD), 256, 0, stream>>>(buf_qkv, buf_qkv + DMODEL,
                                                               buf_vt, buf_attn, QKVN);
    // 4) x1 = x + attn @ wo (N=768 -> gemm_mfma BK=64 dbuf, proven config)
    gemm_mfma<<<dim3(DMODEL/GN, NROWS/GM), 256, 0, stream>>>(buf_attn, w_ot, nullptr, x,
                                                             out, nullptr, NROWS, DMODEL, DMODEL, 0, 0);
    // 5) xn2 = LN(x1)
    ln_kernel<<<NROWS, 256, 0, stream>>>(out, gamma2, beta2, buf_xn);
    // 6) h = relu(xn2 @ w1 + b1) (gemm_big 128x128, 512t)
    gemm_big<<<dim3(HID/HN, NROWS/HM), 512, 0, stream>>>(buf_xn, w_1t, b1, nullptr,
                                                         nullptr, buf_h, NROWS, HID, DMODEL, 1, 0);
    // 7) out = x1 + h @ w2 + b2 (N=768 -> gemm_mfma BK=64 dbuf, proven config)
    gemm_mfma<<<dim3(DMODEL/GN, NROWS/GM), 256, 0, stream>>>(buf_h, w_2t, b2, out,
                                                             out, nullptr, NROWS, DMODEL, HID, 0, 0);
}

// Round 11
// 387.242 us; speedup vs baseline: 1.1432x; 1.0294x over previous
//
#include <hip/hip_runtime.h>
#include <hip/hip_bf16.h>
#include <math.h>

// Problem constants (match reference)
#define BATCH 4
#define SEQ   2048
#define DMODEL 768
#define NHEAD 12
#define HS    64
#define HID   3072   // 4*DMODEL
#define NROWS (BATCH*SEQ)   // 8192
#define QKVN  (3*DMODEL)    // 2304
#define EPS   1e-6f

typedef __attribute__((ext_vector_type(8))) short bf16x8;
typedef __attribute__((ext_vector_type(4))) float f32x4;

__device__ inline ushort f2b(float f) {
    union { float f; unsigned u; } x; x.f = f;
    unsigned u = x.u;
    unsigned r = (u + 0x7FFFu + ((u >> 16) & 1u)) >> 16;
    return (ushort)r;
}

// async global->LDS, 16B per lane (m97)
#define GLDS16(g, l) __builtin_amdgcn_global_load_lds( \
    (const __attribute__((address_space(1))) void*)(g), \
    (__attribute__((address_space(3))) void*)(l), 16, 0, 0)

// ---------------- Weight convert+transpose: fp32 [K][N] -> bf16 [N][K] ----------------
__global__ __launch_bounds__(256) void convert_w4(const float* __restrict__ p0,
                                                  const float* __restrict__ p1,
                                                  const float* __restrict__ p2,
                                                  const float* __restrict__ p3,
                                                  ushort* __restrict__ out) {
    const float* srcs[4] = { p0, p1, p2, p3 };
    const float* in = srcs[blockIdx.z];
    ushort* dst = out + (size_t)blockIdx.z * DMODEL * DMODEL;
    __shared__ float tile[32][33];
    const int bx = blockIdx.x * 32;  // N
    const int by = blockIdx.y * 32;  // K
    const int tx = threadIdx.x & 31, ty = threadIdx.x >> 5;
    #pragma unroll
    for (int i = 0; i < 32; i += 8)
        tile[ty + i][tx] = in[(size_t)(by + ty + i) * DMODEL + bx + tx];
    __syncthreads();
    #pragma unroll
    for (int i = 0; i < 32; i += 8)
        dst[(size_t)(bx + ty + i) * DMODEL + by + tx] = f2b(tile[tx][ty + i]);
}

__global__ __launch_bounds__(256) void convert_w(const float* __restrict__ in,
                                                 ushort* __restrict__ out,
                                                 int K, int N) {
    __shared__ float tile[32][33];
    const int bx = blockIdx.x * 32;  // N
    const int by = blockIdx.y * 32;  // K
    const int tx = threadIdx.x & 31, ty = threadIdx.x >> 5;
    #pragma unroll
    for (int i = 0; i < 32; i += 8)
        tile[ty + i][tx] = in[(size_t)(by + ty + i) * N + bx + tx];
    __syncthreads();
    #pragma unroll
    for (int i = 0; i < 32; i += 8)
        out[(size_t)(bx + ty + i) * K + by + tx] = f2b(tile[tx][ty + i]);
}

// ---------------- V transpose: v[b][s][h*64+d] (stride QKVN) -> vt[(bh*64+d)][s] ----------------
__global__ __launch_bounds__(256) void transpose_v(const ushort* __restrict__ v,
                                                   ushort* __restrict__ vt) {
    const int st = blockIdx.x;   // key tile (64 rows)
    const int bh = blockIdx.y;
    const int b = bh / NHEAD, h = bh % NHEAD;
    const ushort* src = v + ((size_t)b * SEQ) * QKVN + h * HS;
    ushort* dst = vt + ((size_t)bh * HS) * SEQ;
    __shared__ ushort t[64][65];
    const int col = threadIdx.x & 63;
    const int r0  = (threadIdx.x >> 6) * 16;
    #pragma unroll
    for (int i = 0; i < 16; ++i)
        t[col][r0 + i] = src[(size_t)(st * 64 + r0 + i) * QKVN + col];
    __syncthreads();
    #pragma unroll
    for (int i = 0; i < 16; ++i)
        dst[(size_t)(r0 + i) * SEQ + st * 64 + col] = t[r0 + i][col];
}

// ---------------- LayerNorm (ddof=1), fp32 in -> bf16 out ----------------
// r18: vectorized per G13 — float4 in (16B/lane), ushort4 out (8B/lane).
// Threads 0..191 each own 4 elements (192*4 = 768); reduction unchanged.
__global__ __launch_bounds__(256) void ln_kernel(const float* __restrict__ x,
                                                 const float* __restrict__ gamma,
                                                 const float* __restrict__ beta,
                                                 ushort* __restrict__ out) {
    const int row = blockIdx.x;
    const int tid = threadIdx.x;
    const float4* xr4 = (const float4*)(x + (size_t)row * DMODEL);
    float4 v = make_float4(0.f, 0.f, 0.f, 0.f);
    float s = 0.f, s2 = 0.f;
    if (tid < 192) {
        v = xr4[tid];
        s  = v.x + v.y + v.z + v.w;
        s2 = v.x * v.x + v.y * v.y + v.z * v.z + v.w * v.w;
    }
    for (int off = 32; off > 0; off >>= 1) {
        s  += __shfl_down(s,  off, 64);
        s2 += __shfl_down(s2, off, 64);
    }
    __shared__ float shs[4], shs2[4];
    int wid = tid >> 6, lane = tid & 63;
    if (lane == 0) { shs[wid] = s; shs2[wid] = s2; }
    __syncthreads();
    __shared__ float smean, srstd;
    if (tid == 0) {
        float S  = shs[0] + shs[1] + shs[2] + shs[3];
        float S2 = shs2[0] + shs2[1] + shs2[2] + shs2[3];
        float mean = S / DMODEL;
        float var  = (S2 - DMODEL * mean * mean) / (DMODEL - 1);
        smean = mean;
        srstd = rsqrtf(var + EPS);
    }
    __syncthreads();
    if (tid < 192) {
        float mean = smean, rstd = srstd;
        const float4 g = ((const float4*)gamma)[tid];
        const float4 b = ((const float4*)beta)[tid];
        ushort4 o;
        o.x = f2b(g.x * (v.x - mean) * rstd + b.x);
        o.y = f2b(g.y * (v.y - mean) * rstd + b.y);
        o.z = f2b(g.z * (v.z - mean) * rstd + b.z);
        o.w = f2b(g.w * (v.w - mean) * rstd + b.w);
        ((ushort4*)(out + (size_t)row * DMODEL))[tid] = o;
    }
}

// ---------------- gemm_mfma: 64x128 tile, BK=64, per-wave 32x64 (N=768) ----------------
// r2/r7-proven config (MLP2 < 73us). BK=32 tri-buffer regressed here (r8):
// doubles sync frequency at only 8 MFMAs/step. Do not touch.
#define GN 128
#define GK 64
#define GM 64
__global__ __launch_bounds__(256, 3) void gemm_mfma(const ushort* __restrict__ A,
                                                    const ushort* __restrict__ Bt,
                                                    const float* __restrict__ bias,
                                                    const float* __restrict__ res,
                                                    float* __restrict__ C,
                                                    ushort* __restrict__ Cb,
                                                    int M, int N, int K, int do_relu,
                                                    int scale_q) {
    __shared__ ushort As[2][GM * GK];
    __shared__ ushort Bs[2][GN * GK];
    const int tid  = threadIdx.x;
    const int lane = tid & 63, wave = tid >> 6;
    const int l16  = lane & 15, quad = lane >> 4;
    const int wr = wave >> 1, wc = wave & 1;

    // XCD-aware swizzle: give each XCD a contiguous row-major chunk
    const int nwg = gridDim.x * gridDim.y;
    int id = blockIdx.y * gridDim.x + blockIdx.x;
    if ((nwg & 7) == 0) {
        const int chunk = nwg >> 3;
        id = (id & 7) * chunk + (id >> 3);
    }
    const int bx = id % gridDim.x;
    const int by = id / gridDim.x;
    const int row0 = by * GM, col0 = bx * GN;

    f32x4 acc[2][4];
    #pragma unroll
    for (int i = 0; i < 2; ++i)
        #pragma unroll
        for (int j = 0; j < 4; ++j) acc[i][j] = (f32x4){0.f, 0.f, 0.f, 0.f};

    // staging: LDS chunk c=(m<<3)|j  <-  global chunk j^(m&7) of row m
    const ushort* Asrc[2];
    const ushort* Bsrc[4];
    #pragma unroll
    for (int i = 0; i < 2; ++i) {
        int c = tid + i * 256, m = c >> 3, j = c & 7;
        Asrc[i] = A + (size_t)(row0 + m) * K + (j ^ (m & 7)) * 8;
    }
    #pragma unroll
    for (int i = 0; i < 4; ++i) {
        int c = tid + i * 256, m = c >> 3, j = c & 7;
        Bsrc[i] = Bt + (size_t)(col0 + m) * K + (j ^ (m & 7)) * 8;
    }

    const int nk = K / GK;
    // prologue: stage K-tile 0 into buf 0
    #pragma unroll
    for (int i = 0; i < 2; ++i) GLDS16(Asrc[i], &As[0][(tid + i * 256) * 8]);
    #pragma unroll
    for (int i = 0; i < 4; ++i)  GLDS16(Bsrc[i], &Bs[0][(tid + i * 256) * 8]);

    for (int kt = 0; kt < nk; ++kt) {
        const int p = kt & 1;
        __syncthreads();   // drains buf[p] loads; all waves done reading buf[p^1]
        if (kt + 1 < nk) {
            const int k1 = (kt + 1) * GK;
            #pragma unroll
            for (int i = 0; i < 2; ++i) GLDS16(Asrc[i] + k1, &As[p ^ 1][(tid + i * 256) * 8]);
            #pragma unroll
            for (int i = 0; i < 4; ++i)  GLDS16(Bsrc[i] + k1, &Bs[p ^ 1][(tid + i * 256) * 8]);
        }

        #pragma unroll
        for (int s = 0; s < 2; ++s) {
            bf16x8 af[2], bfr[4];
            #pragma unroll
            for (int i = 0; i < 2; ++i) {
                int m = wr * 32 + i * 16 + l16;
                af[i] = *(const bf16x8*)&As[p][(m * 8 + (((s << 2) | quad) ^ (m & 7))) * 8];
            }
            #pragma unroll
            for (int j = 0; j < 4; ++j) {
                int n = wc * 64 + j * 16 + l16;
                bfr[j] = *(const bf16x8*)&Bs[p][(n * 8 + (((s << 2) | quad) ^ (n & 7))) * 8];
            }
            #pragma unroll
            for (int i = 0; i < 2; ++i)
                #pragma unroll
                for (int j = 0; j < 4; ++j)
                    acc[i][j] = __builtin_amdgcn_mfma_f32_16x16x32_bf16(af[i], bfr[j], acc[i][j], 0, 0, 0);
        }
    }

    // epilogue: C/D layout col=l16, row=quad*4+r
    #pragma unroll
    for (int i = 0; i < 2; ++i) {
        #pragma unroll
        for (int r = 0; r < 4; ++r) {
            int row = row0 + wr * 32 + i * 16 + quad * 4 + r;
            #pragma unroll
            for (int j = 0; j < 4; ++j) {
                int col = col0 + wc * 64 + j * 16 + l16;
                float v = acc[i][j][r];
                if (bias) v += bias[col];
                if (do_relu) v = fmaxf(v, 0.f);
                if (scale_q && col < DMODEL) v *= 0.125f;  // fold 1/sqrt(hs) into Q
                if (res) v += res[(size_t)row * N + col];
                if (Cb) Cb[(size_t)row * N + col] = f2b(v);
                else    C [(size_t)row * N + col] = v;
            }
        }
    }
}

// ---------------- gemm_big: 128x128, BK=32, 512 threads, tri-buffer + counted vmcnt ----------------
// r18: setprio REMOVED — r10 isolated it at -10us (73 -> 83.5, occ 54->46,
// MfmaUtil 21.4->18.4). Confirms m190: in a barrier-locked GEMM, boosting
// MFMA waves starves the staging waves everyone waits on. This is now
// byte-identical to r7's proven config (MLP1 = 73us, occ 54%).
#define HM 128
#define HN 128
#define HK 32
__global__ __launch_bounds__(512, 6) void gemm_big(const ushort* __restrict__ A,
                                                   const ushort* __restrict__ Bt,
                                                   const float* __restrict__ bias,
                                                   const float* __restrict__ res,
                                                   float* __restrict__ C,
                                                   ushort* __restrict__ Cb,
                                                   int M, int N, int K, int do_relu,
                                                   int scale_q) {
    __shared__ ushort As[3][HM * HK];   // 3 x 8 KB
    __shared__ ushort Bs[3][HN * HK];   // 3 x 8 KB  -> 48 KB total
    const int tid  = threadIdx.x;
    const int lane = tid & 63, wave = tid >> 6;   // 0..7
    const int l16  = lane & 15, quad = lane >> 4;
    const int wr = wave & 3, wc = wave >> 2;      // 4x2 wave grid, 32x64/wave

    const int nwg = gridDim.x * gridDim.y;
    int id = blockIdx.y * gridDim.x + blockIdx.x;
    if ((nwg & 7) == 0) {
        const int chunk = nwg >> 3;
        id = (id & 7) * chunk + (id >> 3);
    }
    const int bx = id % gridDim.x;
    const int by = id / gridDim.x;
    const int row0 = by * HM, col0 = bx * HN;

    f32x4 acc[2][4];
    #pragma unroll
    for (int i = 0; i < 2; ++i)
        #pragma unroll
        for (int j = 0; j < 4; ++j) acc[i][j] = (f32x4){0.f, 0.f, 0.f, 0.f};

    // row-pair layout: LDS chunk c = lr*8+pos holds global (m = 2*lr + (p>>2), j = p&3)
    // where p = pos ^ (lr&7)   [zero-conflict, verified r5/r6/r7]
    const ushort* Asrc;
    const ushort* Bsrc;
    {
        int c = tid;
        int lr = c >> 3, pp = (c & 7) ^ (lr & 7);
        int m = lr * 2 + (pp >> 2), j = pp & 3;
        Asrc = A  + (size_t)(row0 + m) * K + j * 8;
        Bsrc = Bt + (size_t)(col0 + m) * K + j * 8;
    }

    const int nk = K / HK;   // K=768 -> 24

    // 2 vmcnt-instructions per tile-stage (A,B)
#define STAGE_BIG(kt, b) do { \
    const int _k = (kt) * HK; \
    GLDS16(Asrc + _k, &As[b][tid * 8]); \
    GLDS16(Bsrc + _k, &Bs[b][tid * 8]); \
} while (0)

    STAGE_BIG(0, 0);
    STAGE_BIG(1, 1);

    int pc = 0, pn = 1, ps = 2;   // compute / next / stage-target buffers
    for (int t = 0; t < nk; ++t) {
        // wait tile t only: tile t+1's 2 loads stay in flight
        if (t + 1 < nk) asm volatile("s_waitcnt vmcnt(2)" ::: "memory");
        else            asm volatile("s_waitcnt vmcnt(0)" ::: "memory");
        __builtin_amdgcn_s_barrier();
        if (t + 2 < nk) STAGE_BIG(t + 2, ps);

        bf16x8 af[2], bfr[4];
        #pragma unroll
        for (int i = 0; i < 2; ++i) {
            int m = wr * 32 + i * 16 + l16;
            int ch = (m >> 1) * 8 + ((((m & 1) << 2) | quad) ^ ((m >> 1) & 7));
            af[i] = *(const bf16x8*)&As[pc][ch * 8];
        }
        #pragma unroll
        for (int j = 0; j < 4; ++j) {
            int n = wc * 64 + j * 16 + l16;
            int ch = (n >> 1) * 8 + ((((n & 1) << 2) | quad) ^ ((n >> 1) & 7));
            bfr[j] = *(const bf16x8*)&Bs[pc][ch * 8];
        }
        #pragma unroll
        for (int i = 0; i < 2; ++i)
            #pragma unroll
            for (int j = 0; j < 4; ++j)
                acc[i][j] = __builtin_amdgcn_mfma_f32_16x16x32_bf16(af[i], bfr[j], acc[i][j], 0, 0, 0);

        int tmp = pc; pc = pn; pn = ps; ps = tmp;
    }

    // epilogue: C/D layout col=l16, row=quad*4+r
    #pragma unroll
    for (int i = 0; i < 2; ++i) {
        #pragma unroll
        for (int r = 0; r < 4; ++r) {
            int row = row0 + wr * 32 + i * 16 + quad * 4 + r;
            #pragma unroll
            for (int j = 0; j < 4; ++j) {
                int col = col0 + wc * 64 + j * 16 + l16;
                float v = acc[i][j][r];
                if (bias) v += bias[col];
                if (do_relu) v = fmaxf(v, 0.f);
                if (scale_q && col < DMODEL) v *= 0.125f;  // fold 1/sqrt(hs) into Q
                if (res) v += res[(size_t)row * N + col];
                if (Cb) Cb[(size_t)row * N + col] = f2b(v);
                else    C [(size_t)row * N + col] = v;
            }
        }
    }
}

// ---------------- Flash attention: paired q-tiles, GLDS staging, dbuf ----------------
// r18: PPAD 72 -> 76. At 72, P-writes put quads {0,2} and {1,3} on the same
// 8-bank windows (4-way conflict, the 811K SQ_LDS_BANK_CONFLICT). At 76 the
// quad windows start at banks {0,24,16,8} -> full 32-bank spread, 2-way
// (free, m136). Read addresses stay <=2-way.
#define TQ 64
#define TK 64
#define PPAD 76
#define NQT (SEQ / TQ)   // 32

__global__ __launch_bounds__(256, 3) void fattn_kernel(const ushort* __restrict__ q,
                                                       const ushort* __restrict__ k,
                                                       const ushort* __restrict__ vt,
                                                       ushort* __restrict__ o,
                                                       int ldqkv) {
    const int pair = blockIdx.x;             // 0..15
    const int qts[2] = { pair, NQT - 1 - pair };
    const int bh = blockIdx.y;
    const int b = bh / NHEAD, h = bh % NHEAD;
    const int tid  = threadIdx.x;
    const int wave = tid >> 6;
    const int lane = tid & 63;
    const int l16  = lane & 15;
    const int quad = lane >> 4;

    __shared__ ushort Ks[2][TK * 64];    // 8 KB per buffer, packed [key][8 chunks]
    __shared__ ushort Vs[2][HS * 64];    // 8 KB per buffer, packed [d][8 chunks]
    __shared__ ushort Ps[4][16][PPAD];   // per-wave P[q][key] (wave-private)

    const size_t base  = ((size_t)b * SEQ) * ldqkv + (size_t)h * HS;
    const size_t baseO = ((size_t)b * SEQ) * DMODEL + (size_t)h * HS;
    const ushort* vth = vt + ((size_t)bh * HS) * SEQ;

    const int r0 = tid >> 3, j0 = (tid & 7) ^ (r0 & 7);
    const int r1 = (tid + 256) >> 3, j1 = (tid & 7) ^ (r1 & 7);
    const ushort* Ksrc0 = k + base + (size_t)r0 * ldqkv + j0 * 8;
    const ushort* Ksrc1 = k + base + (size_t)r1 * ldqkv + j1 * 8;
    const ushort* Vsrc0 = vth + (size_t)r0 * SEQ + j0 * 8;
    const ushort* Vsrc1 = vth + (size_t)r1 * SEQ + j1 * 8;

    bf16x8 qf[2][2];
    #pragma unroll
    for (int t = 0; t < 2; ++t) {
        int qrow = qts[t] * TQ + wave * 16 + l16;
        const ushort* qp = q + base + (size_t)qrow * ldqkv + quad * 8;
        qf[t][0] = *(const bf16x8*)(qp);
        qf[t][1] = *(const bf16x8*)(qp + 32);
    }

    f32x4 Oacc[2][4];
    float lrow[2][4];
    #pragma unroll
    for (int t = 0; t < 2; ++t) {
        #pragma unroll
        for (int f = 0; f < 4; ++f) Oacc[t][f] = (f32x4){0.f, 0.f, 0.f, 0.f};
        #pragma unroll
        for (int r = 0; r < 4; ++r) lrow[t][r] = 0.f;
    }

    const int ktiles = qts[1] + 1;
    GLDS16(Ksrc0, &Ks[0][tid * 8]);
    GLDS16(Ksrc1, &Ks[0][(tid + 256) * 8]);
    GLDS16(Vsrc0, &Vs[0][tid * 8]);
    GLDS16(Vsrc1, &Vs[0][(tid + 256) * 8]);

    for (int kt = 0; kt < ktiles; ++kt) {
        const int p = kt & 1;
        __syncthreads();   // drains buf[p] (in flight since last compute phase)
        if (kt + 1 < ktiles) {
            const size_t ko = (size_t)(kt + 1) * TK;
            GLDS16(Ksrc0 + ko * ldqkv, &Ks[p ^ 1][tid * 8]);
            GLDS16(Ksrc1 + ko * ldqkv, &Ks[p ^ 1][(tid + 256) * 8]);
            GLDS16(Vsrc0 + ko,         &Vs[p ^ 1][tid * 8]);
            GLDS16(Vsrc1 + ko,         &Vs[p ^ 1][(tid + 256) * 8]);
        }

        bf16x8 kb[4][2], vb[4][2];
        #pragma unroll
        for (int f = 0; f < 4; ++f) {
            int row = f * 16 + l16;
            kb[f][0] = *(const bf16x8*)&Ks[p][(row * 8 + (quad ^ (row & 7))) * 8];
            kb[f][1] = *(const bf16x8*)&Ks[p][(row * 8 + ((4 | quad) ^ (row & 7))) * 8];
            vb[f][0] = *(const bf16x8*)&Vs[p][(row * 8 + (quad ^ (row & 7))) * 8];
            vb[f][1] = *(const bf16x8*)&Vs[p][(row * 8 + ((4 | quad) ^ (row & 7))) * 8];
        }

        #pragma unroll
        for (int t = 0; t < 2; ++t) {
            const int qt = qts[t];
            if (kt > qt) continue;   // wave-uniform; only t=0 can skip

            f32x4 S[4];
            #pragma unroll
            for (int f = 0; f < 4; ++f) {
                f32x4 a = (f32x4){0.f, 0.f, 0.f, 0.f};
                a = __builtin_amdgcn_mfma_f32_16x16x32_bf16(qf[t][0], kb[f][0], a, 0, 0, 0);
                a = __builtin_amdgcn_mfma_f32_16x16x32_bf16(qf[t][1], kb[f][1], a, 0, 0, 0);
                S[f] = a;
            }

            const int qrow_base = qt * TQ + wave * 16 + quad * 4;
            if (kt == qt) {
                #pragma unroll
                for (int f = 0; f < 4; ++f) {
                    int key = kt * TK + f * 16 + l16;
                    #pragma unroll
                    for (int r = 0; r < 4; ++r)
                        if (key > qrow_base + r) S[f][r] = -INFINITY;
                }
            }

            #pragma unroll
            for (int f = 0; f < 4; ++f) {
                #pragma unroll
                for (int r = 0; r < 4; ++r) {
                    float pv = __expf(S[f][r]);
                    S[f][r] = pv;
                    lrow[t][r] += pv;
                }
            }

            #pragma unroll
            for (int f = 0; f < 4; ++f)
                #pragma unroll
                for (int r = 0; r < 4; ++r)
                    Ps[wave][quad * 4 + r][f * 16 + l16] = f2b(S[f][r]);

            bf16x8 pa0 = *(const bf16x8*)&Ps[wave][l16][quad * 8];
            bf16x8 pa1 = *(const bf16x8*)&Ps[wave][l16][32 + quad * 8];
            #pragma unroll
            for (int f = 0; f < 4; ++f) {
                Oacc[t][f] = __builtin_amdgcn_mfma_f32_16x16x32_bf16(pa0, vb[f][0], Oacc[t][f], 0, 0, 0);
                Oacc[t][f] = __builtin_amdgcn_mfma_f32_16x16x32_bf16(pa1, vb[f][1], Oacc[t][f], 0, 0, 0);
            }
        }
    }

    #pragma unroll
    for (int t = 0; t < 2; ++t) {
        const int qrow = qts[t] * TQ + wave * 16 + quad * 4;
        #pragma unroll
        for (int r = 0; r < 4; ++r) {
            float l = lrow[t][r];
            #pragma unroll
            for (int m = 1; m < 16; m <<= 1) l += __shfl_xor(l, m, 64);
            float invl = 1.f / l;
            #pragma unroll
            for (int f = 0; f < 4; ++f)
                o[baseO + (size_t)(qrow + r) * DMODEL + f * 16 + l16] = f2b(Oacc[t][f][r] * invl);
        }
    }
}

// ---------------- Host launcher ----------------
extern "C" void kernel_launch(void* const* d_in, const int* in_sizes, int n_in,
                              void* d_out, int out_size, void* d_ws, size_t ws_size,
                              hipStream_t stream) {
    const float* x      = (const float*)d_in[0];
    const float* wq     = (const float*)d_in[1];
    const float* wk     = (const float*)d_in[2];
    const float* wv     = (const float*)d_in[3];
    const float* wo     = (const float*)d_in[4];
    const float* w1     = (const float*)d_in[5];
    const float* b1     = (const float*)d_in[6];
    const float* w2     = (const float*)d_in[7];
    const float* b2     = (const float*)d_in[8];
    const float* gamma1 = (const float*)d_in[9];
    const float* beta1  = (const float*)d_in[10];
    const float* gamma2 = (const float*)d_in[11];
    const float* beta2  = (const float*)d_in[12];
    float* out = (float*)d_out;

    char* ws = (char*)d_ws;
    ushort* buf_xn   = (ushort*)ws;                              // 8192*768
    ushort* buf_attn = buf_xn;
    ushort* buf_qkv  = (ushort*)(ws + 12582912);                 // 8192*2304
    ushort* buf_h    = buf_qkv;                                  // 8192*3072
    ushort* w_qkv    = (ushort*)(ws + 12582912 + 50331648);      // 2304*768
    ushort* w_ot     = w_qkv + (size_t)QKVN * DMODEL;
    ushort* w_1t     = w_ot + (size_t)DMODEL * DMODEL;
    ushort* w_2t     = w_1t + (size_t)HID * DMODEL;
    // V^T lives in d_out (free until step 4; stream-serial)
    ushort* buf_vt   = (ushort*)d_out;

    convert_w4<<<dim3(DMODEL/32, DMODEL/32, 4), 256, 0, stream>>>(wq, wk, wv, wo, w_qkv);
    convert_w<<<dim3(HID/32,    DMODEL/32), 256, 0, stream>>>(w1, w_1t, DMODEL, HID);
    convert_w<<<dim3(DMODEL/32, HID/32),    256, 0, stream>>>(w2, w_2t, HID, DMODEL);

    // 1) xn1 = LN(x)
    ln_kernel<<<NROWS, 256, 0, stream>>>(x, gamma1, beta1, buf_xn);
    // 2) qkv = xn1 @ [wq|wk|wv], Q cols pre-scaled by 0.125 (gemm_big 128x128, 512t)
    gemm_big<<<dim3(QKVN/HN, NROWS/HM), 512, 0, stream>>>(buf_xn, w_qkv, nullptr, nullptr,
                                                          nullptr, buf_qkv, NROWS, QKVN, DMODEL, 0, 1);
    // 2b) V -> V^T per head (into d_out scratch)
    transpose_v<<<dim3(SEQ/64, BATCH*NHEAD), 256, 0, stream>>>(buf_qkv + 2*DMODEL, buf_vt);
    // 3) flash attention (paired q-tiles, GLDS dbuf staging, fixed-max softmax)
    fattn_kernel<<<dim3(NQT/2, BATCH*NHEAD), 256, 0, stream>>>(buf_qkv, buf_qkv + DMODEL,
                                                               buf_vt, buf_attn, QKVN);
    // 4) x1 = x + attn @ wo (N=768 -> gemm_mfma BK=64 dbuf, proven config)
    gemm_mfma<<<dim3(DMODEL/GN, NROWS/GM), 256, 0, stream>>>(buf_attn, w_ot, nullptr, x,
                                                             out, nullptr, NROWS, DMODEL, DMODEL, 0, 0);
    // 5) xn2 = LN(x1)
    ln_kernel<<<NROWS, 256, 0, stream>>>(out, gamma2, beta2, buf_xn);
    // 6) h = relu(xn2 @ w1 + b1) (gemm_big 128x128, 512t)
    gemm_big<<<dim3(HID/HN, NROWS/HM), 512, 0, stream>>>(buf_xn, w_1t, b1, nullptr,
                                                         nullptr, buf_h, NROWS, HID, DMODEL, 1, 0);
    // 7) out = x1 + h @ w2 + b2 (N=768 -> gemm_mfma BK=64 dbuf, proven config)
    gemm_mfma<<<dim3(DMODEL/GN, NROWS/GM), 256, 0, stream>>>(buf_h, w_2t, b2, out,
                                                             out, nullptr, NROWS, DMODEL, HID, 0, 0);
}

// Round 12
// 385.685 us; speedup vs baseline: 1.1478x; 1.0040x over previous
//
#include <hip/hip_runtime.h>
#include <hip/hip_bf16.h>
#include <math.h>

// Problem constants (match reference)
#define BATCH 4
#define SEQ   2048
#define DMODEL 768
#define NHEAD 12
#define HS    64
#define HID   3072   // 4*DMODEL
#define NROWS (BATCH*SEQ)   // 8192
#define QKVN  (3*DMODEL)    // 2304
#define EPS   1e-6f

typedef __attribute__((ext_vector_type(8))) short bf16x8;
typedef __attribute__((ext_vector_type(4))) float f32x4;

__device__ inline ushort f2b(float f) {
    union { float f; unsigned u; } x; x.f = f;
    unsigned u = x.u;
    unsigned r = (u + 0x7FFFu + ((u >> 16) & 1u)) >> 16;
    return (ushort)r;
}

// async global->LDS, 16B per lane (m97)
#define GLDS16(g, l) __builtin_amdgcn_global_load_lds( \
    (const __attribute__((address_space(1))) void*)(g), \
    (__attribute__((address_space(3))) void*)(l), 16, 0, 0)

// ---------------- Weight convert+transpose: fp32 [K][N] -> bf16 [N][K] ----------------
__global__ __launch_bounds__(256) void convert_w4(const float* __restrict__ p0,
                                                  const float* __restrict__ p1,
                                                  const float* __restrict__ p2,
                                                  const float* __restrict__ p3,
                                                  ushort* __restrict__ out) {
    const float* srcs[4] = { p0, p1, p2, p3 };
    const float* in = srcs[blockIdx.z];
    ushort* dst = out + (size_t)blockIdx.z * DMODEL * DMODEL;
    __shared__ float tile[32][33];
    const int bx = blockIdx.x * 32;  // N
    const int by = blockIdx.y * 32;  // K
    const int tx = threadIdx.x & 31, ty = threadIdx.x >> 5;
    #pragma unroll
    for (int i = 0; i < 32; i += 8)
        tile[ty + i][tx] = in[(size_t)(by + ty + i) * DMODEL + bx + tx];
    __syncthreads();
    #pragma unroll
    for (int i = 0; i < 32; i += 8)
        dst[(size_t)(bx + ty + i) * DMODEL + by + tx] = f2b(tile[tx][ty + i]);
}

__global__ __launch_bounds__(256) void convert_w(const float* __restrict__ in,
                                                 ushort* __restrict__ out,
                                                 int K, int N) {
    __shared__ float tile[32][33];
    const int bx = blockIdx.x * 32;  // N
    const int by = blockIdx.y * 32;  // K
    const int tx = threadIdx.x & 31, ty = threadIdx.x >> 5;
    #pragma unroll
    for (int i = 0; i < 32; i += 8)
        tile[ty + i][tx] = in[(size_t)(by + ty + i) * N + bx + tx];
    __syncthreads();
    #pragma unroll
    for (int i = 0; i < 32; i += 8)
        out[(size_t)(bx + ty + i) * K + by + tx] = f2b(tile[tx][ty + i]);
}

// ---------------- V transpose: v[b][s][h*64+d] (stride QKVN) -> vt[(bh*64+d)][s] ----------------
__global__ __launch_bounds__(256) void transpose_v(const ushort* __restrict__ v,
                                                   ushort* __restrict__ vt) {
    const int st = blockIdx.x;   // key tile (64 rows)
    const int bh = blockIdx.y;
    const int b = bh / NHEAD, h = bh % NHEAD;
    const ushort* src = v + ((size_t)b * SEQ) * QKVN + h * HS;
    ushort* dst = vt + ((size_t)bh * HS) * SEQ;
    __shared__ ushort t[64][65];
    const int col = threadIdx.x & 63;
    const int r0  = (threadIdx.x >> 6) * 16;
    #pragma unroll
    for (int i = 0; i < 16; ++i)
        t[col][r0 + i] = src[(size_t)(st * 64 + r0 + i) * QKVN + col];
    __syncthreads();
    #pragma unroll
    for (int i = 0; i < 16; ++i)
        dst[(size_t)(r0 + i) * SEQ + st * 64 + col] = t[r0 + i][col];
}

// ---------------- LayerNorm (ddof=1), fp32 in -> bf16 out ----------------
// r18: vectorized per G13 — float4 in (16B/lane), ushort4 out (8B/lane).
__global__ __launch_bounds__(256) void ln_kernel(const float* __restrict__ x,
                                                 const float* __restrict__ gamma,
                                                 const float* __restrict__ beta,
                                                 ushort* __restrict__ out) {
    const int row = blockIdx.x;
    const int tid = threadIdx.x;
    const float4* xr4 = (const float4*)(x + (size_t)row * DMODEL);
    float4 v = make_float4(0.f, 0.f, 0.f, 0.f);
    float s = 0.f, s2 = 0.f;
    if (tid < 192) {
        v = xr4[tid];
        s  = v.x + v.y + v.z + v.w;
        s2 = v.x * v.x + v.y * v.y + v.z * v.z + v.w * v.w;
    }
    for (int off = 32; off > 0; off >>= 1) {
        s  += __shfl_down(s,  off, 64);
        s2 += __shfl_down(s2, off, 64);
    }
    __shared__ float shs[4], shs2[4];
    int wid = tid >> 6, lane = tid & 63;
    if (lane == 0) { shs[wid] = s; shs2[wid] = s2; }
    __syncthreads();
    __shared__ float smean, srstd;
    if (tid == 0) {
        float S  = shs[0] + shs[1] + shs[2] + shs[3];
        float S2 = shs2[0] + shs2[1] + shs2[2] + shs2[3];
        float mean = S / DMODEL;
        float var  = (S2 - DMODEL * mean * mean) / (DMODEL - 1);
        smean = mean;
        srstd = rsqrtf(var + EPS);
    }
    __syncthreads();
    if (tid < 192) {
        float mean = smean, rstd = srstd;
        const float4 g = ((const float4*)gamma)[tid];
        const float4 b = ((const float4*)beta)[tid];
        ushort4 o;
        o.x = f2b(g.x * (v.x - mean) * rstd + b.x);
        o.y = f2b(g.y * (v.y - mean) * rstd + b.y);
        o.z = f2b(g.z * (v.z - mean) * rstd + b.z);
        o.w = f2b(g.w * (v.w - mean) * rstd + b.w);
        ((ushort4*)(out + (size_t)row * DMODEL))[tid] = o;
    }
}

// ---------------- gemm_mfma: 64x128 tile, BK=64, per-wave 32x64 (N=768) ----------------
// r2/r7-proven config (MLP2 < 73us). BK=32 tri-buffer regressed here (r8). Do not touch.
#define GN 128
#define GK 64
#define GM 64
__global__ __launch_bounds__(256, 3) void gemm_mfma(const ushort* __restrict__ A,
                                                    const ushort* __restrict__ Bt,
                                                    const float* __restrict__ bias,
                                                    const float* __restrict__ res,
                                                    float* __restrict__ C,
                                                    ushort* __restrict__ Cb,
                                                    int M, int N, int K, int do_relu,
                                                    int scale_q) {
    __shared__ ushort As[2][GM * GK];
    __shared__ ushort Bs[2][GN * GK];
    const int tid  = threadIdx.x;
    const int lane = tid & 63, wave = tid >> 6;
    const int l16  = lane & 15, quad = lane >> 4;
    const int wr = wave >> 1, wc = wave & 1;

    // XCD-aware swizzle: give each XCD a contiguous row-major chunk
    const int nwg = gridDim.x * gridDim.y;
    int id = blockIdx.y * gridDim.x + blockIdx.x;
    if ((nwg & 7) == 0) {
        const int chunk = nwg >> 3;
        id = (id & 7) * chunk + (id >> 3);
    }
    const int bx = id % gridDim.x;
    const int by = id / gridDim.x;
    const int row0 = by * GM, col0 = bx * GN;

    f32x4 acc[2][4];
    #pragma unroll
    for (int i = 0; i < 2; ++i)
        #pragma unroll
        for (int j = 0; j < 4; ++j) acc[i][j] = (f32x4){0.f, 0.f, 0.f, 0.f};

    // staging: LDS chunk c=(m<<3)|j  <-  global chunk j^(m&7) of row m
    const ushort* Asrc[2];
    const ushort* Bsrc[4];
    #pragma unroll
    for (int i = 0; i < 2; ++i) {
        int c = tid + i * 256, m = c >> 3, j = c & 7;
        Asrc[i] = A + (size_t)(row0 + m) * K + (j ^ (m & 7)) * 8;
    }
    #pragma unroll
    for (int i = 0; i < 4; ++i) {
        int c = tid + i * 256, m = c >> 3, j = c & 7;
        Bsrc[i] = Bt + (size_t)(col0 + m) * K + (j ^ (m & 7)) * 8;
    }

    const int nk = K / GK;
    #pragma unroll
    for (int i = 0; i < 2; ++i) GLDS16(Asrc[i], &As[0][(tid + i * 256) * 8]);
    #pragma unroll
    for (int i = 0; i < 4; ++i)  GLDS16(Bsrc[i], &Bs[0][(tid + i * 256) * 8]);

    for (int kt = 0; kt < nk; ++kt) {
        const int p = kt & 1;
        __syncthreads();
        if (kt + 1 < nk) {
            const int k1 = (kt + 1) * GK;
            #pragma unroll
            for (int i = 0; i < 2; ++i) GLDS16(Asrc[i] + k1, &As[p ^ 1][(tid + i * 256) * 8]);
            #pragma unroll
            for (int i = 0; i < 4; ++i)  GLDS16(Bsrc[i] + k1, &Bs[p ^ 1][(tid + i * 256) * 8]);
        }

        #pragma unroll
        for (int s = 0; s < 2; ++s) {
            bf16x8 af[2], bfr[4];
            #pragma unroll
            for (int i = 0; i < 2; ++i) {
                int m = wr * 32 + i * 16 + l16;
                af[i] = *(const bf16x8*)&As[p][(m * 8 + (((s << 2) | quad) ^ (m & 7))) * 8];
            }
            #pragma unroll
            for (int j = 0; j < 4; ++j) {
                int n = wc * 64 + j * 16 + l16;
                bfr[j] = *(const bf16x8*)&Bs[p][(n * 8 + (((s << 2) | quad) ^ (n & 7))) * 8];
            }
            #pragma unroll
            for (int i = 0; i < 2; ++i)
                #pragma unroll
                for (int j = 0; j < 4; ++j)
                    acc[i][j] = __builtin_amdgcn_mfma_f32_16x16x32_bf16(af[i], bfr[j], acc[i][j], 0, 0, 0);
        }
    }

    // epilogue: C/D layout col=l16, row=quad*4+r
    #pragma unroll
    for (int i = 0; i < 2; ++i) {
        #pragma unroll
        for (int r = 0; r < 4; ++r) {
            int row = row0 + wr * 32 + i * 16 + quad * 4 + r;
            #pragma unroll
            for (int j = 0; j < 4; ++j) {
                int col = col0 + wc * 64 + j * 16 + l16;
                float v = acc[i][j][r];
                if (bias) v += bias[col];
                if (do_relu) v = fmaxf(v, 0.f);
                if (scale_q && col < DMODEL) v *= 0.125f;  // fold 1/sqrt(hs) into Q
                if (res) v += res[(size_t)row * N + col];
                if (Cb) Cb[(size_t)row * N + col] = f2b(v);
                else    C [(size_t)row * N + col] = v;
            }
        }
    }
}

// ---------------- gemm_big: 128x128, BK=32, 512 threads, tri-buffer + counted vmcnt ----------------
// r7-proven config (MLP1 = 73us, occ 54%). Structure family is measured-
// cornered: every neighbor (bigger tile, deeper pipe, setprio, BK changes)
// regresses. LDS pipe sits at ~55 B/cy ~ 62% of ds_read_b128 ceiling.
#define HM 128
#define HN 128
#define HK 32
__global__ __launch_bounds__(512, 6) void gemm_big(const ushort* __restrict__ A,
                                                   const ushort* __restrict__ Bt,
                                                   const float* __restrict__ bias,
                                                   const float* __restrict__ res,
                                                   float* __restrict__ C,
                                                   ushort* __restrict__ Cb,
                                                   int M, int N, int K, int do_relu,
                                                   int scale_q) {
    __shared__ ushort As[3][HM * HK];   // 3 x 8 KB
    __shared__ ushort Bs[3][HN * HK];   // 3 x 8 KB  -> 48 KB total
    const int tid  = threadIdx.x;
    const int lane = tid & 63, wave = tid >> 6;   // 0..7
    const int l16  = lane & 15, quad = lane >> 4;
    const int wr = wave & 3, wc = wave >> 2;      // 4x2 wave grid, 32x64/wave

    const int nwg = gridDim.x * gridDim.y;
    int id = blockIdx.y * gridDim.x + blockIdx.x;
    if ((nwg & 7) == 0) {
        const int chunk = nwg >> 3;
        id = (id & 7) * chunk + (id >> 3);
    }
    const int bx = id % gridDim.x;
    const int by = id / gridDim.x;
    const int row0 = by * HM, col0 = bx * HN;

    f32x4 acc[2][4];
    #pragma unroll
    for (int i = 0; i < 2; ++i)
        #pragma unroll
        for (int j = 0; j < 4; ++j) acc[i][j] = (f32x4){0.f, 0.f, 0.f, 0.f};

    // row-pair layout: LDS chunk c = lr*8+pos holds global (m = 2*lr + (p>>2), j = p&3)
    // where p = pos ^ (lr&7)   [zero-conflict, verified r5/r6/r7]
    const ushort* Asrc;
    const ushort* Bsrc;
    {
        int c = tid;
        int lr = c >> 3, pp = (c & 7) ^ (lr & 7);
        int m = lr * 2 + (pp >> 2), j = pp & 3;
        Asrc = A  + (size_t)(row0 + m) * K + j * 8;
        Bsrc = Bt + (size_t)(col0 + m) * K + j * 8;
    }

    const int nk = K / HK;   // K=768 -> 24

#define STAGE_BIG(kt, b) do { \
    const int _k = (kt) * HK; \
    GLDS16(Asrc + _k, &As[b][tid * 8]); \
    GLDS16(Bsrc + _k, &Bs[b][tid * 8]); \
} while (0)

    STAGE_BIG(0, 0);
    STAGE_BIG(1, 1);

    int pc = 0, pn = 1, ps = 2;   // compute / next / stage-target buffers
    for (int t = 0; t < nk; ++t) {
        if (t + 1 < nk) asm volatile("s_waitcnt vmcnt(2)" ::: "memory");
        else            asm volatile("s_waitcnt vmcnt(0)" ::: "memory");
        __builtin_amdgcn_s_barrier();
        if (t + 2 < nk) STAGE_BIG(t + 2, ps);

        bf16x8 af[2], bfr[4];
        #pragma unroll
        for (int i = 0; i < 2; ++i) {
            int m = wr * 32 + i * 16 + l16;
            int ch = (m >> 1) * 8 + ((((m & 1) << 2) | quad) ^ ((m >> 1) & 7));
            af[i] = *(const bf16x8*)&As[pc][ch * 8];
        }
        #pragma unroll
        for (int j = 0; j < 4; ++j) {
            int n = wc * 64 + j * 16 + l16;
            int ch = (n >> 1) * 8 + ((((n & 1) << 2) | quad) ^ ((n >> 1) & 7));
            bfr[j] = *(const bf16x8*)&Bs[pc][ch * 8];
        }
        #pragma unroll
        for (int i = 0; i < 2; ++i)
            #pragma unroll
            for (int j = 0; j < 4; ++j)
                acc[i][j] = __builtin_amdgcn_mfma_f32_16x16x32_bf16(af[i], bfr[j], acc[i][j], 0, 0, 0);

        int tmp = pc; pc = pn; pn = ps; ps = tmp;
    }

    // epilogue: C/D layout col=l16, row=quad*4+r
    #pragma unroll
    for (int i = 0; i < 2; ++i) {
        #pragma unroll
        for (int r = 0; r < 4; ++r) {
            int row = row0 + wr * 32 + i * 16 + quad * 4 + r;
            #pragma unroll
            for (int j = 0; j < 4; ++j) {
                int col = col0 + wc * 64 + j * 16 + l16;
                float v = acc[i][j][r];
                if (bias) v += bias[col];
                if (do_relu) v = fmaxf(v, 0.f);
                if (scale_q && col < DMODEL) v *= 0.125f;  // fold 1/sqrt(hs) into Q
                if (res) v += res[(size_t)row * N + col];
                if (Cb) Cb[(size_t)row * N + col] = f2b(v);
                else    C [(size_t)row * N + col] = v;
            }
        }
    }
}

// ---------------- Flash attention: paired q-tiles, K tri-buffer + counted vmcnt ----------------
// r19: two fixes targeting fattn's stall profile (r2 cold: 781 GB/s, occ 2.9%):
// (1) K tri-buffer + counted vmcnt (r6/r7-proven discipline): per tile wait
//     vmcnt(2) — own tile's V+K retired, next K's 2 loads stay in flight —
//     raw barrier, then issue V(t+1) FIRST then K(t+2) (V-first makes the
//     count exact: queue at top of iter t = [V(t) older, K(t+1) newer]).
//     Removes the per-tile full-drain __syncthreads HBM-latency stall.
//     LDS: Ks 3x8KB + Vs 2x8KB + Ps 9.5KB = 49.5KB -> still 3 blocks/CU.
// (2) XCD swizzle: the 16 pair-blocks sharing one (b,h)'s K/V (512KB)
//     previously round-robined across 8 XCDs -> 8x duplicated L2 fills
//     (FETCH 111MB). Chunked remap gives each XCD 6 whole bh-groups.
#define TQ 64
#define TK 64
#define PPAD 76
#define NQT (SEQ / TQ)   // 32

__global__ __launch_bounds__(256, 3) void fattn_kernel(const ushort* __restrict__ q,
                                                       const ushort* __restrict__ k,
                                                       const ushort* __restrict__ vt,
                                                       ushort* __restrict__ o,
                                                       int ldqkv) {
    // XCD-aware remap: same-bh pair-blocks contiguous -> same XCD L2
    const int nwg = gridDim.x * gridDim.y;   // 16*48 = 768, %8==0
    int id = blockIdx.y * gridDim.x + blockIdx.x;
    {
        const int chunk = nwg >> 3;          // 96
        id = (id & 7) * chunk + (id >> 3);
    }
    const int pair = id % gridDim.x;         // 0..15
    const int bh   = id / gridDim.x;
    const int qts[2] = { pair, NQT - 1 - pair };
    const int b = bh / NHEAD, h = bh % NHEAD;
    const int tid  = threadIdx.x;
    const int wave = tid >> 6;
    const int lane = tid & 63;
    const int l16  = lane & 15;
    const int quad = lane >> 4;

    __shared__ ushort Ks[3][TK * 64];    // 24 KB tri-buffer, packed [key][8 chunks]
    __shared__ ushort Vs[2][HS * 64];    // 16 KB dbuf, packed [d][8 chunks]
    __shared__ ushort Ps[4][16][PPAD];   // per-wave P[q][key] (wave-private)

    const size_t base  = ((size_t)b * SEQ) * ldqkv + (size_t)h * HS;
    const size_t baseO = ((size_t)b * SEQ) * DMODEL + (size_t)h * HS;
    const ushort* vth = vt + ((size_t)bh * HS) * SEQ;

    const int r0 = tid >> 3, j0 = (tid & 7) ^ (r0 & 7);
    const int r1 = (tid + 256) >> 3, j1 = (tid & 7) ^ (r1 & 7);
    const ushort* Ksrc0 = k + base + (size_t)r0 * ldqkv + j0 * 8;
    const ushort* Ksrc1 = k + base + (size_t)r1 * ldqkv + j1 * 8;
    const ushort* Vsrc0 = vth + (size_t)r0 * SEQ + j0 * 8;
    const ushort* Vsrc1 = vth + (size_t)r1 * SEQ + j1 * 8;

    bf16x8 qf[2][2];
    #pragma unroll
    for (int t = 0; t < 2; ++t) {
        int qrow = qts[t] * TQ + wave * 16 + l16;
        const ushort* qp = q + base + (size_t)qrow * ldqkv + quad * 8;
        qf[t][0] = *(const bf16x8*)(qp);
        qf[t][1] = *(const bf16x8*)(qp + 32);
    }

    f32x4 Oacc[2][4];
    float lrow[2][4];
    #pragma unroll
    for (int t = 0; t < 2; ++t) {
        #pragma unroll
        for (int f = 0; f < 4; ++f) Oacc[t][f] = (f32x4){0.f, 0.f, 0.f, 0.f};
        #pragma unroll
        for (int r = 0; r < 4; ++r) lrow[t][r] = 0.f;
    }

    const int ktiles = qts[1] + 1;   // >= 17 always (pair <= 15)
    // prologue: V(0) first, then K(0), K(1)  (issue order defines vmcnt FIFO)
    GLDS16(Vsrc0, &Vs[0][tid * 8]);
    GLDS16(Vsrc1, &Vs[0][(tid + 256) * 8]);
    GLDS16(Ksrc0, &Ks[0][tid * 8]);
    GLDS16(Ksrc1, &Ks[0][(tid + 256) * 8]);
    GLDS16(Ksrc0 + (size_t)TK * ldqkv, &Ks[1][tid * 8]);
    GLDS16(Ksrc1 + (size_t)TK * ldqkv, &Ks[1][(tid + 256) * 8]);

    int kc = 0, kn = 1, ks2 = 2;   // K buffer rotation
    for (int kt = 0; kt < ktiles; ++kt) {
        const int pv = kt & 1;
        // wait: own tile's V+K retired; K(t+1)'s 2 loads stay in flight
        if (kt + 1 < ktiles) asm volatile("s_waitcnt vmcnt(2)" ::: "memory");
        else                 asm volatile("s_waitcnt vmcnt(0)" ::: "memory");
        __builtin_amdgcn_s_barrier();
        // issue V(t+1) FIRST, then K(t+2)
        if (kt + 1 < ktiles) {
            const size_t ko = (size_t)(kt + 1) * TK;
            GLDS16(Vsrc0 + ko, &Vs[pv ^ 1][tid * 8]);
            GLDS16(Vsrc1 + ko, &Vs[pv ^ 1][(tid + 256) * 8]);
        }
        if (kt + 2 < ktiles) {
            const size_t ko = (size_t)(kt + 2) * TK * ldqkv;
            GLDS16(Ksrc0 + ko, &Ks[ks2][tid * 8]);
            GLDS16(Ksrc1 + ko, &Ks[ks2][(tid + 256) * 8]);
        }

        bf16x8 kb[4][2], vb[4][2];
        #pragma unroll
        for (int f = 0; f < 4; ++f) {
            int row = f * 16 + l16;
            kb[f][0] = *(const bf16x8*)&Ks[kc][(row * 8 + (quad ^ (row & 7))) * 8];
            kb[f][1] = *(const bf16x8*)&Ks[kc][(row * 8 + ((4 | quad) ^ (row & 7))) * 8];
            vb[f][0] = *(const bf16x8*)&Vs[pv][(row * 8 + (quad ^ (row & 7))) * 8];
            vb[f][1] = *(const bf16x8*)&Vs[pv][(row * 8 + ((4 | quad) ^ (row & 7))) * 8];
        }

        #pragma unroll
        for (int t = 0; t < 2; ++t) {
            const int qt = qts[t];
            if (kt > qt) continue;   // wave-uniform; only t=0 can skip

            f32x4 S[4];
            #pragma unroll
            for (int f = 0; f < 4; ++f) {
                f32x4 a = (f32x4){0.f, 0.f, 0.f, 0.f};
                a = __builtin_amdgcn_mfma_f32_16x16x32_bf16(qf[t][0], kb[f][0], a, 0, 0, 0);
                a = __builtin_amdgcn_mfma_f32_16x16x32_bf16(qf[t][1], kb[f][1], a, 0, 0, 0);
                S[f] = a;
            }

            const int qrow_base = qt * TQ + wave * 16 + quad * 4;
            if (kt == qt) {
                #pragma unroll
                for (int f = 0; f < 4; ++f) {
                    int key = kt * TK + f * 16 + l16;
                    #pragma unroll
                    for (int r = 0; r < 4; ++r)
                        if (key > qrow_base + r) S[f][r] = -INFINITY;
                }
            }

            #pragma unroll
            for (int f = 0; f < 4; ++f) {
                #pragma unroll
                for (int r = 0; r < 4; ++r) {
                    float pv2 = __expf(S[f][r]);
                    S[f][r] = pv2;
                    lrow[t][r] += pv2;
                }
            }

            #pragma unroll
            for (int f = 0; f < 4; ++f)
                #pragma unroll
                for (int r = 0; r < 4; ++r)
                    Ps[wave][quad * 4 + r][f * 16 + l16] = f2b(S[f][r]);

            bf16x8 pa0 = *(const bf16x8*)&Ps[wave][l16][quad * 8];
            bf16x8 pa1 = *(const bf16x8*)&Ps[wave][l16][32 + quad * 8];
            #pragma unroll
            for (int f = 0; f < 4; ++f) {
                Oacc[t][f] = __builtin_amdgcn_mfma_f32_16x16x32_bf16(pa0, vb[f][0], Oacc[t][f], 0, 0, 0);
                Oacc[t][f] = __builtin_amdgcn_mfma_f32_16x16x32_bf16(pa1, vb[f][1], Oacc[t][f], 0, 0, 0);
            }
        }

        int tmp = kc; kc = kn; kn = ks2; ks2 = tmp;
    }

    #pragma unroll
    for (int t = 0; t < 2; ++t) {
        const int qrow = qts[t] * TQ + wave * 16 + quad * 4;
        #pragma unroll
        for (int r = 0; r < 4; ++r) {
            float l = lrow[t][r];
            #pragma unroll
            for (int m = 1; m < 16; m <<= 1) l += __shfl_xor(l, m, 64);
            float invl = 1.f / l;
            #pragma unroll
            for (int f = 0; f < 4; ++f)
                o[baseO + (size_t)(qrow + r) * DMODEL + f * 16 + l16] = f2b(Oacc[t][f][r] * invl);
        }
    }
}

// ---------------- Host launcher ----------------
extern "C" void kernel_launch(void* const* d_in, const int* in_sizes, int n_in,
                              void* d_out, int out_size, void* d_ws, size_t ws_size,
                              hipStream_t stream) {
    const float* x      = (const float*)d_in[0];
    const float* wq     = (const float*)d_in[1];
    const float* wk     = (const float*)d_in[2];
    const float* wv     = (const float*)d_in[3];
    const float* wo     = (const float*)d_in[4];
    const float* w1     = (const float*)d_in[5];
    const float* b1     = (const float*)d_in[6];
    const float* w2     = (const float*)d_in[7];
    const float* b2     = (const float*)d_in[8];
    const float* gamma1 = (const float*)d_in[9];
    const float* beta1  = (const float*)d_in[10];
    const float* gamma2 = (const float*)d_in[11];
    const float* beta2  = (const float*)d_in[12];
    float* out = (float*)d_out;

    char* ws = (char*)d_ws;
    ushort* buf_xn   = (ushort*)ws;                              // 8192*768
    ushort* buf_attn = buf_xn;
    ushort* buf_qkv  = (ushort*)(ws + 12582912);                 // 8192*2304
    ushort* buf_h    = buf_qkv;                                  // 8192*3072
    ushort* w_qkv    = (ushort*)(ws + 12582912 + 50331648);      // 2304*768
    ushort* w_ot     = w_qkv + (size_t)QKVN * DMODEL;
    ushort* w_1t     = w_ot + (size_t)DMODEL * DMODEL;
    ushort* w_2t     = w_1t + (size_t)HID * DMODEL;
    // V^T lives in d_out (free until step 4; stream-serial)
    ushort* buf_vt   = (ushort*)d_out;

    convert_w4<<<dim3(DMODEL/32, DMODEL/32, 4), 256, 0, stream>>>(wq, wk, wv, wo, w_qkv);
    convert_w<<<dim3(HID/32,    DMODEL/32), 256, 0, stream>>>(w1, w_1t, DMODEL, HID);
    convert_w<<<dim3(DMODEL/32, HID/32),    256, 0, stream>>>(w2, w_2t, HID, DMODEL);

    // 1) xn1 = LN(x)
    ln_kernel<<<NROWS, 256, 0, stream>>>(x, gamma1, beta1, buf_xn);
    // 2) qkv = xn1 @ [wq|wk|wv], Q cols pre-scaled by 0.125 (gemm_big 128x128, 512t)
    gemm_big<<<dim3(QKVN/HN, NROWS/HM), 512, 0, stream>>>(buf_xn, w_qkv, nullptr, nullptr,
                                                          nullptr, buf_qkv, NROWS, QKVN, DMODEL, 0, 1);
    // 2b) V -> V^T per head (into d_out scratch)
    transpose_v<<<dim3(SEQ/64, BATCH*NHEAD), 256, 0, stream>>>(buf_qkv + 2*DMODEL, buf_vt);
    // 3) flash attention (K tri-buffer + counted vmcnt, XCD swizzle)
    fattn_kernel<<<dim3(NQT/2, BATCH*NHEAD), 256, 0, stream>>>(buf_qkv, buf_qkv + DMODEL,
                                                               buf_vt, buf_attn, QKVN);
    // 4) x1 = x + attn @ wo (N=768 -> gemm_mfma BK=64 dbuf, proven config)
    gemm_mfma<<<dim3(DMODEL/GN, NROWS/GM), 256, 0, stream>>>(buf_attn, w_ot, nullptr, x,
                                                             out, nullptr, NROWS, DMODEL, DMODEL, 0, 0);
    // 5) xn2 = LN(x1)
    ln_kernel<<<NROWS, 256, 0, stream>>>(out, gamma2, beta2, buf_xn);
    // 6) h = relu(xn2 @ w1 + b1) (gemm_big 128x128, 512t)
    gemm_big<<<dim3(HID/HN, NROWS/HM), 512, 0, stream>>>(buf_xn, w_1t, b1, nullptr,
                                                         nullptr, buf_h, NROWS, HID, DMODEL, 1, 0);
    // 7) out = x1 + h @ w2 + b2 (N=768 -> gemm_mfma BK=64 dbuf, proven config)
    gemm_mfma<<<dim3(DMODEL/GN, NROWS/GM), 256, 0, stream>>>(buf_h, w_2t, b2, out,
                                                             out, nullptr, NROWS, DMODEL, HID, 0, 0);
}

// Round 13
// 371.537 us; speedup vs baseline: 1.1915x; 1.0381x over previous
//
#include <hip/hip_runtime.h>
#include <hip/hip_bf16.h>
#include <math.h>

// Problem constants (match reference)
#define BATCH 4
#define SEQ   2048
#define DMODEL 768
#define NHEAD 12
#define HS    64
#define HID   3072   // 4*DMODEL
#define NROWS (BATCH*SEQ)   // 8192
#define QKVN  (3*DMODEL)    // 2304
#define EPS   1e-6f

typedef __attribute__((ext_vector_type(8))) short bf16x8;
typedef __attribute__((ext_vector_type(4))) float f32x4;

__device__ inline ushort f2b(float f) {
    union { float f; unsigned u; } x; x.f = f;
    unsigned u = x.u;
    unsigned r = (u + 0x7FFFu + ((u >> 16) & 1u)) >> 16;
    return (ushort)r;
}

// async global->LDS, 16B per lane (m97)
#define GLDS16(g, l) __builtin_amdgcn_global_load_lds( \
    (const __attribute__((address_space(1))) void*)(g), \
    (__attribute__((address_space(3))) void*)(l), 16, 0, 0)

// ---------------- Weight convert+transpose: fp32 [K][N] -> bf16 [N][K] ----------------
__global__ __launch_bounds__(256) void convert_w4(const float* __restrict__ p0,
                                                  const float* __restrict__ p1,
                                                  const float* __restrict__ p2,
                                                  const float* __restrict__ p3,
                                                  ushort* __restrict__ out) {
    const float* srcs[4] = { p0, p1, p2, p3 };
    const float* in = srcs[blockIdx.z];
    ushort* dst = out + (size_t)blockIdx.z * DMODEL * DMODEL;
    __shared__ float tile[32][33];
    const int bx = blockIdx.x * 32;  // N
    const int by = blockIdx.y * 32;  // K
    const int tx = threadIdx.x & 31, ty = threadIdx.x >> 5;
    #pragma unroll
    for (int i = 0; i < 32; i += 8)
        tile[ty + i][tx] = in[(size_t)(by + ty + i) * DMODEL + bx + tx];
    __syncthreads();
    #pragma unroll
    for (int i = 0; i < 32; i += 8)
        dst[(size_t)(bx + ty + i) * DMODEL + by + tx] = f2b(tile[tx][ty + i]);
}

__global__ __launch_bounds__(256) void convert_w(const float* __restrict__ in,
                                                 ushort* __restrict__ out,
                                                 int K, int N) {
    __shared__ float tile[32][33];
    const int bx = blockIdx.x * 32;  // N
    const int by = blockIdx.y * 32;  // K
    const int tx = threadIdx.x & 31, ty = threadIdx.x >> 5;
    #pragma unroll
    for (int i = 0; i < 32; i += 8)
        tile[ty + i][tx] = in[(size_t)(by + ty + i) * N + bx + tx];
    __syncthreads();
    #pragma unroll
    for (int i = 0; i < 32; i += 8)
        out[(size_t)(bx + ty + i) * K + by + tx] = f2b(tile[tx][ty + i]);
}

// ---------------- V transpose: v[b][s][h*64+d] (stride QKVN) -> vt[(bh*64+d)][s] ----------------
__global__ __launch_bounds__(256) void transpose_v(const ushort* __restrict__ v,
                                                   ushort* __restrict__ vt) {
    const int st = blockIdx.x;   // key tile (64 rows)
    const int bh = blockIdx.y;
    const int b = bh / NHEAD, h = bh % NHEAD;
    const ushort* src = v + ((size_t)b * SEQ) * QKVN + h * HS;
    ushort* dst = vt + ((size_t)bh * HS) * SEQ;
    __shared__ ushort t[64][65];
    const int col = threadIdx.x & 63;
    const int r0  = (threadIdx.x >> 6) * 16;
    #pragma unroll
    for (int i = 0; i < 16; ++i)
        t[col][r0 + i] = src[(size_t)(st * 64 + r0 + i) * QKVN + col];
    __syncthreads();
    #pragma unroll
    for (int i = 0; i < 16; ++i)
        dst[(size_t)(r0 + i) * SEQ + st * 64 + col] = t[r0 + i][col];
}

// ---------------- LayerNorm (ddof=1), fp32 in -> bf16 out ----------------
// r18: vectorized per G13 — float4 in (16B/lane), ushort4 out (8B/lane).
__global__ __launch_bounds__(256) void ln_kernel(const float* __restrict__ x,
                                                 const float* __restrict__ gamma,
                                                 const float* __restrict__ beta,
                                                 ushort* __restrict__ out) {
    const int row = blockIdx.x;
    const int tid = threadIdx.x;
    const float4* xr4 = (const float4*)(x + (size_t)row * DMODEL);
    float4 v = make_float4(0.f, 0.f, 0.f, 0.f);
    float s = 0.f, s2 = 0.f;
    if (tid < 192) {
        v = xr4[tid];
        s  = v.x + v.y + v.z + v.w;
        s2 = v.x * v.x + v.y * v.y + v.z * v.z + v.w * v.w;
    }
    for (int off = 32; off > 0; off >>= 1) {
        s  += __shfl_down(s,  off, 64);
        s2 += __shfl_down(s2, off, 64);
    }
    __shared__ float shs[4], shs2[4];
    int wid = tid >> 6, lane = tid & 63;
    if (lane == 0) { shs[wid] = s; shs2[wid] = s2; }
    __syncthreads();
    __shared__ float smean, srstd;
    if (tid == 0) {
        float S  = shs[0] + shs[1] + shs[2] + shs[3];
        float S2 = shs2[0] + shs2[1] + shs2[2] + shs2[3];
        float mean = S / DMODEL;
        float var  = (S2 - DMODEL * mean * mean) / (DMODEL - 1);
        smean = mean;
        srstd = rsqrtf(var + EPS);
    }
    __syncthreads();
    if (tid < 192) {
        float mean = smean, rstd = srstd;
        const float4 g = ((const float4*)gamma)[tid];
        const float4 b = ((const float4*)beta)[tid];
        ushort4 o;
        o.x = f2b(g.x * (v.x - mean) * rstd + b.x);
        o.y = f2b(g.y * (v.y - mean) * rstd + b.y);
        o.z = f2b(g.z * (v.z - mean) * rstd + b.z);
        o.w = f2b(g.w * (v.w - mean) * rstd + b.w);
        ((ushort4*)(out + (size_t)row * DMODEL))[tid] = o;
    }
}

// ---------------- gemm_mfma: 64x128 tile, BK=64, 512 threads / 8 waves (N=768) ----------------
// r20: apply the r7-proven lever (waves/SIMD 3 -> 6 at constant tile) to the
// N=768 GEMMs. Same 64x128 tile, BK=64, 2-buffer __syncthreads schedule, and
// zero-conflict 8-chunk XOR layout as the 256t version (r2-proven); ONLY the
// wave partition changes: 8 waves in a 2x4 grid, per-wave 32x32, acc[2][2].
// LDS 48KB -> 3 blocks/CU -> 24 waves/CU = 6 waves/SIMD. FLOP/LDS-byte drops
// 21.3 -> 16 (+33% LDS reads) — r7 measured occupancy > FLOP/byte in exactly
// this trade (gemm_big 80 -> 73). r8's gemm_mfma failure was a SCHEDULE
// change (BK=32, 2x barriers), not a wave-count change.
// Tripwire: regression = LDS pipe saturated -> revert to 256t (r12 known).
#define GN 128
#define GK 64
#define GM 64
__global__ __launch_bounds__(512, 6) void gemm_mfma(const ushort* __restrict__ A,
                                                    const ushort* __restrict__ Bt,
                                                    const float* __restrict__ bias,
                                                    const float* __restrict__ res,
                                                    float* __restrict__ C,
                                                    ushort* __restrict__ Cb,
                                                    int M, int N, int K, int do_relu,
                                                    int scale_q) {
    __shared__ ushort As[2][GM * GK];   // 2 x 8 KB
    __shared__ ushort Bs[2][GN * GK];   // 2 x 16 KB -> 48 KB total
    const int tid  = threadIdx.x;
    const int lane = tid & 63, wave = tid >> 6;   // 0..7
    const int l16  = lane & 15, quad = lane >> 4;
    const int wr = wave & 1, wc = wave >> 1;      // 2x4 wave grid, 32x32/wave

    // XCD-aware swizzle: give each XCD a contiguous row-major chunk
    const int nwg = gridDim.x * gridDim.y;
    int id = blockIdx.y * gridDim.x + blockIdx.x;
    if ((nwg & 7) == 0) {
        const int chunk = nwg >> 3;
        id = (id & 7) * chunk + (id >> 3);
    }
    const int bx = id % gridDim.x;
    const int by = id / gridDim.x;
    const int row0 = by * GM, col0 = bx * GN;

    f32x4 acc[2][2];
    #pragma unroll
    for (int i = 0; i < 2; ++i)
        #pragma unroll
        for (int j = 0; j < 2; ++j) acc[i][j] = (f32x4){0.f, 0.f, 0.f, 0.f};

    // staging: LDS chunk c=(m<<3)|j  <-  global chunk j^(m&7) of row m
    // A: 512 chunks -> 1/thread; B: 1024 chunks -> 2/thread
    const ushort* Asrc;
    const ushort* Bsrc[2];
    {
        int c = tid, m = c >> 3, j = c & 7;
        Asrc = A + (size_t)(row0 + m) * K + (j ^ (m & 7)) * 8;
    }
    #pragma unroll
    for (int i = 0; i < 2; ++i) {
        int c = tid + i * 512, m = c >> 3, j = c & 7;
        Bsrc[i] = Bt + (size_t)(col0 + m) * K + (j ^ (m & 7)) * 8;
    }

    const int nk = K / GK;
    // prologue: stage K-tile 0 into buf 0
    GLDS16(Asrc, &As[0][tid * 8]);
    #pragma unroll
    for (int i = 0; i < 2; ++i) GLDS16(Bsrc[i], &Bs[0][(tid + i * 512) * 8]);

    for (int kt = 0; kt < nk; ++kt) {
        const int p = kt & 1;
        __syncthreads();   // drains buf[p] loads; all waves done reading buf[p^1]
        if (kt + 1 < nk) {
            const int k1 = (kt + 1) * GK;
            GLDS16(Asrc + k1, &As[p ^ 1][tid * 8]);
            #pragma unroll
            for (int i = 0; i < 2; ++i) GLDS16(Bsrc[i] + k1, &Bs[p ^ 1][(tid + i * 512) * 8]);
        }

        #pragma unroll
        for (int s = 0; s < 2; ++s) {
            bf16x8 af[2], bfr[2];
            #pragma unroll
            for (int i = 0; i < 2; ++i) {
                int m = wr * 32 + i * 16 + l16;
                af[i] = *(const bf16x8*)&As[p][(m * 8 + (((s << 2) | quad) ^ (m & 7))) * 8];
            }
            #pragma unroll
            for (int j = 0; j < 2; ++j) {
                int n = wc * 32 + j * 16 + l16;
                bfr[j] = *(const bf16x8*)&Bs[p][(n * 8 + (((s << 2) | quad) ^ (n & 7))) * 8];
            }
            #pragma unroll
            for (int i = 0; i < 2; ++i)
                #pragma unroll
                for (int j = 0; j < 2; ++j)
                    acc[i][j] = __builtin_amdgcn_mfma_f32_16x16x32_bf16(af[i], bfr[j], acc[i][j], 0, 0, 0);
        }
    }

    // epilogue: C/D layout col=l16, row=quad*4+r
    #pragma unroll
    for (int i = 0; i < 2; ++i) {
        #pragma unroll
        for (int r = 0; r < 4; ++r) {
            int row = row0 + wr * 32 + i * 16 + quad * 4 + r;
            #pragma unroll
            for (int j = 0; j < 2; ++j) {
                int col = col0 + wc * 32 + j * 16 + l16;
                float v = acc[i][j][r];
                if (bias) v += bias[col];
                if (do_relu) v = fmaxf(v, 0.f);
                if (scale_q && col < DMODEL) v *= 0.125f;  // fold 1/sqrt(hs) into Q
                if (res) v += res[(size_t)row * N + col];
                if (Cb) Cb[(size_t)row * N + col] = f2b(v);
                else    C [(size_t)row * N + col] = v;
            }
        }
    }
}

// ---------------- gemm_big: 128x128, BK=32, 512 threads, tri-buffer + counted vmcnt ----------------
// r7-proven config (MLP1 = 71-73us, occ 54%). Structure family measured-
// cornered: every neighbor (bigger tile, deeper pipe, setprio, BK) regresses.
#define HM 128
#define HN 128
#define HK 32
__global__ __launch_bounds__(512, 6) void gemm_big(const ushort* __restrict__ A,
                                                   const ushort* __restrict__ Bt,
                                                   const float* __restrict__ bias,
                                                   const float* __restrict__ res,
                                                   float* __restrict__ C,
                                                   ushort* __restrict__ Cb,
                                                   int M, int N, int K, int do_relu,
                                                   int scale_q) {
    __shared__ ushort As[3][HM * HK];   // 3 x 8 KB
    __shared__ ushort Bs[3][HN * HK];   // 3 x 8 KB  -> 48 KB total
    const int tid  = threadIdx.x;
    const int lane = tid & 63, wave = tid >> 6;   // 0..7
    const int l16  = lane & 15, quad = lane >> 4;
    const int wr = wave & 3, wc = wave >> 2;      // 4x2 wave grid, 32x64/wave

    const int nwg = gridDim.x * gridDim.y;
    int id = blockIdx.y * gridDim.x + blockIdx.x;
    if ((nwg & 7) == 0) {
        const int chunk = nwg >> 3;
        id = (id & 7) * chunk + (id >> 3);
    }
    const int bx = id % gridDim.x;
    const int by = id / gridDim.x;
    const int row0 = by * HM, col0 = bx * HN;

    f32x4 acc[2][4];
    #pragma unroll
    for (int i = 0; i < 2; ++i)
        #pragma unroll
        for (int j = 0; j < 4; ++j) acc[i][j] = (f32x4){0.f, 0.f, 0.f, 0.f};

    // row-pair layout: LDS chunk c = lr*8+pos holds global (m = 2*lr + (p>>2), j = p&3)
    // where p = pos ^ (lr&7)   [zero-conflict, verified r5/r6/r7]
    const ushort* Asrc;
    const ushort* Bsrc;
    {
        int c = tid;
        int lr = c >> 3, pp = (c & 7) ^ (lr & 7);
        int m = lr * 2 + (pp >> 2), j = pp & 3;
        Asrc = A  + (size_t)(row0 + m) * K + j * 8;
        Bsrc = Bt + (size_t)(col0 + m) * K + j * 8;
    }

    const int nk = K / HK;   // K=768 -> 24

#define STAGE_BIG(kt, b) do { \
    const int _k = (kt) * HK; \
    GLDS16(Asrc + _k, &As[b][tid * 8]); \
    GLDS16(Bsrc + _k, &Bs[b][tid * 8]); \
} while (0)

    STAGE_BIG(0, 0);
    STAGE_BIG(1, 1);

    int pc = 0, pn = 1, ps = 2;   // compute / next / stage-target buffers
    for (int t = 0; t < nk; ++t) {
        if (t + 1 < nk) asm volatile("s_waitcnt vmcnt(2)" ::: "memory");
        else            asm volatile("s_waitcnt vmcnt(0)" ::: "memory");
        __builtin_amdgcn_s_barrier();
        if (t + 2 < nk) STAGE_BIG(t + 2, ps);

        bf16x8 af[2], bfr[4];
        #pragma unroll
        for (int i = 0; i < 2; ++i) {
            int m = wr * 32 + i * 16 + l16;
            int ch = (m >> 1) * 8 + ((((m & 1) << 2) | quad) ^ ((m >> 1) & 7));
            af[i] = *(const bf16x8*)&As[pc][ch * 8];
        }
        #pragma unroll
        for (int j = 0; j < 4; ++j) {
            int n = wc * 64 + j * 16 + l16;
            int ch = (n >> 1) * 8 + ((((n & 1) << 2) | quad) ^ ((n >> 1) & 7));
            bfr[j] = *(const bf16x8*)&Bs[pc][ch * 8];
        }
        #pragma unroll
        for (int i = 0; i < 2; ++i)
            #pragma unroll
            for (int j = 0; j < 4; ++j)
                acc[i][j] = __builtin_amdgcn_mfma_f32_16x16x32_bf16(af[i], bfr[j], acc[i][j], 0, 0, 0);

        int tmp = pc; pc = pn; pn = ps; ps = tmp;
    }

    // epilogue: C/D layout col=l16, row=quad*4+r
    #pragma unroll
    for (int i = 0; i < 2; ++i) {
        #pragma unroll
        for (int r = 0; r < 4; ++r) {
            int row = row0 + wr * 32 + i * 16 + quad * 4 + r;
            #pragma unroll
            for (int j = 0; j < 4; ++j) {
                int col = col0 + wc * 64 + j * 16 + l16;
                float v = acc[i][j][r];
                if (bias) v += bias[col];
                if (do_relu) v = fmaxf(v, 0.f);
                if (scale_q && col < DMODEL) v *= 0.125f;  // fold 1/sqrt(hs) into Q
                if (res) v += res[(size_t)row * N + col];
                if (Cb) Cb[(size_t)row * N + col] = f2b(v);
                else    C [(size_t)row * N + col] = v;
            }
        }
    }
}

// ---------------- Flash attention: paired q-tiles, K tri-buffer + counted vmcnt ----------------
// r19 config (verified r12): K tri-buffer + counted vmcnt(2), V dbuf,
// V-first issue order, XCD swizzle for K/V L2 locality. PPAD=76.
#define TQ 64
#define TK 64
#define PPAD 76
#define NQT (SEQ / TQ)   // 32

__global__ __launch_bounds__(256, 3) void fattn_kernel(const ushort* __restrict__ q,
                                                       const ushort* __restrict__ k,
                                                       const ushort* __restrict__ vt,
                                                       ushort* __restrict__ o,
                                                       int ldqkv) {
    // XCD-aware remap: same-bh pair-blocks contiguous -> same XCD L2
    const int nwg = gridDim.x * gridDim.y;   // 16*48 = 768, %8==0
    int id = blockIdx.y * gridDim.x + blockIdx.x;
    {
        const int chunk = nwg >> 3;          // 96
        id = (id & 7) * chunk + (id >> 3);
    }
    const int pair = id % gridDim.x;         // 0..15
    const int bh   = id / gridDim.x;
    const int qts[2] = { pair, NQT - 1 - pair };
    const int b = bh / NHEAD, h = bh % NHEAD;
    const int tid  = threadIdx.x;
    const int wave = tid >> 6;
    const int lane = tid & 63;
    const int l16  = lane & 15;
    const int quad = lane >> 4;

    __shared__ ushort Ks[3][TK * 64];    // 24 KB tri-buffer, packed [key][8 chunks]
    __shared__ ushort Vs[2][HS * 64];    // 16 KB dbuf, packed [d][8 chunks]
    __shared__ ushort Ps[4][16][PPAD];   // per-wave P[q][key] (wave-private)

    const size_t base  = ((size_t)b * SEQ) * ldqkv + (size_t)h * HS;
    const size_t baseO = ((size_t)b * SEQ) * DMODEL + (size_t)h * HS;
    const ushort* vth = vt + ((size_t)bh * HS) * SEQ;

    const int r0 = tid >> 3, j0 = (tid & 7) ^ (r0 & 7);
    const int r1 = (tid + 256) >> 3, j1 = (tid & 7) ^ (r1 & 7);
    const ushort* Ksrc0 = k + base + (size_t)r0 * ldqkv + j0 * 8;
    const ushort* Ksrc1 = k + base + (size_t)r1 * ldqkv + j1 * 8;
    const ushort* Vsrc0 = vth + (size_t)r0 * SEQ + j0 * 8;
    const ushort* Vsrc1 = vth + (size_t)r1 * SEQ + j1 * 8;

    bf16x8 qf[2][2];
    #pragma unroll
    for (int t = 0; t < 2; ++t) {
        int qrow = qts[t] * TQ + wave * 16 + l16;
        const ushort* qp = q + base + (size_t)qrow * ldqkv + quad * 8;
        qf[t][0] = *(const bf16x8*)(qp);
        qf[t][1] = *(const bf16x8*)(qp + 32);
    }

    f32x4 Oacc[2][4];
    float lrow[2][4];
    #pragma unroll
    for (int t = 0; t < 2; ++t) {
        #pragma unroll
        for (int f = 0; f < 4; ++f) Oacc[t][f] = (f32x4){0.f, 0.f, 0.f, 0.f};
        #pragma unroll
        for (int r = 0; r < 4; ++r) lrow[t][r] = 0.f;
    }

    const int ktiles = qts[1] + 1;   // >= 17 always (pair <= 15)
    // prologue: V(0) first, then K(0), K(1)  (issue order defines vmcnt FIFO)
    GLDS16(Vsrc0, &Vs[0][tid * 8]);
    GLDS16(Vsrc1, &Vs[0][(tid + 256) * 8]);
    GLDS16(Ksrc0, &Ks[0][tid * 8]);
    GLDS16(Ksrc1, &Ks[0][(tid + 256) * 8]);
    GLDS16(Ksrc0 + (size_t)TK * ldqkv, &Ks[1][tid * 8]);
    GLDS16(Ksrc1 + (size_t)TK * ldqkv, &Ks[1][(tid + 256) * 8]);

    int kc = 0, kn = 1, ks2 = 2;   // K buffer rotation
    for (int kt = 0; kt < ktiles; ++kt) {
        const int pv = kt & 1;
        if (kt + 1 < ktiles) asm volatile("s_waitcnt vmcnt(2)" ::: "memory");
        else                 asm volatile("s_waitcnt vmcnt(0)" ::: "memory");
        __builtin_amdgcn_s_barrier();
        if (kt + 1 < ktiles) {
            const size_t ko = (size_t)(kt + 1) * TK;
            GLDS16(Vsrc0 + ko, &Vs[pv ^ 1][tid * 8]);
            GLDS16(Vsrc1 + ko, &Vs[pv ^ 1][(tid + 256) * 8]);
        }
        if (kt + 2 < ktiles) {
            const size_t ko = (size_t)(kt + 2) * TK * ldqkv;
            GLDS16(Ksrc0 + ko, &Ks[ks2][tid * 8]);
            GLDS16(Ksrc1 + ko, &Ks[ks2][(tid + 256) * 8]);
        }

        bf16x8 kb[4][2], vb[4][2];
        #pragma unroll
        for (int f = 0; f < 4; ++f) {
            int row = f * 16 + l16;
            kb[f][0] = *(const bf16x8*)&Ks[kc][(row * 8 + (quad ^ (row & 7))) * 8];
            kb[f][1] = *(const bf16x8*)&Ks[kc][(row * 8 + ((4 | quad) ^ (row & 7))) * 8];
            vb[f][0] = *(const bf16x8*)&Vs[pv][(row * 8 + (quad ^ (row & 7))) * 8];
            vb[f][1] = *(const bf16x8*)&Vs[pv][(row * 8 + ((4 | quad) ^ (row & 7))) * 8];
        }

        #pragma unroll
        for (int t = 0; t < 2; ++t) {
            const int qt = qts[t];
            if (kt > qt) continue;   // wave-uniform; only t=0 can skip

            f32x4 S[4];
            #pragma unroll
            for (int f = 0; f < 4; ++f) {
                f32x4 a = (f32x4){0.f, 0.f, 0.f, 0.f};
                a = __builtin_amdgcn_mfma_f32_16x16x32_bf16(qf[t][0], kb[f][0], a, 0, 0, 0);
                a = __builtin_amdgcn_mfma_f32_16x16x32_bf16(qf[t][1], kb[f][1], a, 0, 0, 0);
                S[f] = a;
            }

            const int qrow_base = qt * TQ + wave * 16 + quad * 4;
            if (kt == qt) {
                #pragma unroll
                for (int f = 0; f < 4; ++f) {
                    int key = kt * TK + f * 16 + l16;
                    #pragma unroll
                    for (int r = 0; r < 4; ++r)
                        if (key > qrow_base + r) S[f][r] = -INFINITY;
                }
            }

            #pragma unroll
            for (int f = 0; f < 4; ++f) {
                #pragma unroll
                for (int r = 0; r < 4; ++r) {
                    float pv2 = __expf(S[f][r]);
                    S[f][r] = pv2;
                    lrow[t][r] += pv2;
                }
            }

            #pragma unroll
            for (int f = 0; f < 4; ++f)
                #pragma unroll
                for (int r = 0; r < 4; ++r)
                    Ps[wave][quad * 4 + r][f * 16 + l16] = f2b(S[f][r]);

            bf16x8 pa0 = *(const bf16x8*)&Ps[wave][l16][quad * 8];
            bf16x8 pa1 = *(const bf16x8*)&Ps[wave][l16][32 + quad * 8];
            #pragma unroll
            for (int f = 0; f < 4; ++f) {
                Oacc[t][f] = __builtin_amdgcn_mfma_f32_16x16x32_bf16(pa0, vb[f][0], Oacc[t][f], 0, 0, 0);
                Oacc[t][f] = __builtin_amdgcn_mfma_f32_16x16x32_bf16(pa1, vb[f][1], Oacc[t][f], 0, 0, 0);
            }
        }

        int tmp = kc; kc = kn; kn = ks2; ks2 = tmp;
    }

    #pragma unroll
    for (int t = 0; t < 2; ++t) {
        const int qrow = qts[t] * TQ + wave * 16 + quad * 4;
        #pragma unroll
        for (int r = 0; r < 4; ++r) {
            float l = lrow[t][r];
            #pragma unroll
            for (int m = 1; m < 16; m <<= 1) l += __shfl_xor(l, m, 64);
            float invl = 1.f / l;
            #pragma unroll
            for (int f = 0; f < 4; ++f)
                o[baseO + (size_t)(qrow + r) * DMODEL + f * 16 + l16] = f2b(Oacc[t][f][r] * invl);
        }
    }
}

// ---------------- Host launcher ----------------
extern "C" void kernel_launch(void* const* d_in, const int* in_sizes, int n_in,
                              void* d_out, int out_size, void* d_ws, size_t ws_size,
                              hipStream_t stream) {
    const float* x      = (const float*)d_in[0];
    const float* wq     = (const float*)d_in[1];
    const float* wk     = (const float*)d_in[2];
    const float* wv     = (const float*)d_in[3];
    const float* wo     = (const float*)d_in[4];
    const float* w1     = (const float*)d_in[5];
    const float* b1     = (const float*)d_in[6];
    const float* w2     = (const float*)d_in[7];
    const float* b2     = (const float*)d_in[8];
    const float* gamma1 = (const float*)d_in[9];
    const float* beta1  = (const float*)d_in[10];
    const float* gamma2 = (const float*)d_in[11];
    const float* beta2  = (const float*)d_in[12];
    float* out = (float*)d_out;

    char* ws = (char*)d_ws;
    ushort* buf_xn   = (ushort*)ws;                              // 8192*768
    ushort* buf_attn = buf_xn;
    ushort* buf_qkv  = (ushort*)(ws + 12582912);                 // 8192*2304
    ushort* buf_h    = buf_qkv;                                  // 8192*3072
    ushort* w_qkv    = (ushort*)(ws + 12582912 + 50331648);      // 2304*768
    ushort* w_ot     = w_qkv + (size_t)QKVN * DMODEL;
    ushort* w_1t     = w_ot + (size_t)DMODEL * DMODEL;
    ushort* w_2t     = w_1t + (size_t)HID * DMODEL;
    // V^T lives in d_out (free until step 4; stream-serial)
    ushort* buf_vt   = (ushort*)d_out;

    convert_w4<<<dim3(DMODEL/32, DMODEL/32, 4), 256, 0, stream>>>(wq, wk, wv, wo, w_qkv);
    convert_w<<<dim3(HID/32,    DMODEL/32), 256, 0, stream>>>(w1, w_1t, DMODEL, HID);
    convert_w<<<dim3(DMODEL/32, HID/32),    256, 0, stream>>>(w2, w_2t, HID, DMODEL);

    // 1) xn1 = LN(x)
    ln_kernel<<<NROWS, 256, 0, stream>>>(x, gamma1, beta1, buf_xn);
    // 2) qkv = xn1 @ [wq|wk|wv], Q cols pre-scaled by 0.125 (gemm_big 128x128, 512t)
    gemm_big<<<dim3(QKVN/HN, NROWS/HM), 512, 0, stream>>>(buf_xn, w_qkv, nullptr, nullptr,
                                                          nullptr, buf_qkv, NROWS, QKVN, DMODEL, 0, 1);
    // 2b) V -> V^T per head (into d_out scratch)
    transpose_v<<<dim3(SEQ/64, BATCH*NHEAD), 256, 0, stream>>>(buf_qkv + 2*DMODEL, buf_vt);
    // 3) flash attention (K tri-buffer + counted vmcnt, XCD swizzle)
    fattn_kernel<<<dim3(NQT/2, BATCH*NHEAD), 256, 0, stream>>>(buf_qkv, buf_qkv + DMODEL,
                                                               buf_vt, buf_attn, QKVN);
    // 4) x1 = x + attn @ wo (N=768 -> gemm_mfma 512t)
    gemm_mfma<<<dim3(DMODEL/GN, NROWS/GM), 512, 0, stream>>>(buf_attn, w_ot, nullptr, x,
                                                             out, nullptr, NROWS, DMODEL, DMODEL, 0, 0);
    // 5) xn2 = LN(x1)
    ln_kernel<<<NROWS, 256, 0, stream>>>(out, gamma2, beta2, buf_xn);
    // 6) h = relu(xn2 @ w1 + b1) (gemm_big 128x128, 512t)
    gemm_big<<<dim3(HID/HN, NROWS/HM), 512, 0, stream>>>(buf_xn, w_1t, b1, nullptr,
                                                         nullptr, buf_h, NROWS, HID, DMODEL, 1, 0);
    // 7) out = x1 + h @ w2 + b2 (N=768 -> gemm_mfma 512t)
    gemm_mfma<<<dim3(DMODEL/GN, NROWS/GM), 512, 0, stream>>>(buf_h, w_2t, b2, out,
                                                             out, nullptr, NROWS, DMODEL, HID, 0, 0);
}

// Round 14
// 365.345 us; speedup vs baseline: 1.2117x; 1.0169x over previous
//
#include <hip/hip_runtime.h>
#include <hip/hip_bf16.h>
#include <math.h>

// Problem constants (match reference)
#define BATCH 4
#define SEQ   2048
#define DMODEL 768
#define NHEAD 12
#define HS    64
#define HID   3072   // 4*DMODEL
#define NROWS (BATCH*SEQ)   // 8192
#define QKVN  (3*DMODEL)    // 2304
#define EPS   1e-6f

typedef __attribute__((ext_vector_type(8))) short bf16x8;
typedef __attribute__((ext_vector_type(4))) float f32x4;

__device__ inline ushort f2b(float f) {
    union { float f; unsigned u; } x; x.f = f;
    unsigned u = x.u;
    unsigned r = (u + 0x7FFFu + ((u >> 16) & 1u)) >> 16;
    return (ushort)r;
}

// async global->LDS, 16B per lane (m97)
#define GLDS16(g, l) __builtin_amdgcn_global_load_lds( \
    (const __attribute__((address_space(1))) void*)(g), \
    (__attribute__((address_space(3))) void*)(l), 16, 0, 0)

// ---------------- Merged weight convert+transpose: fp32 [K][N] -> bf16 [N][K] ----------------
// r21: one launch instead of three (saves 2 dispatch overheads at stream head).
// 1D grid of 6912 32x32 tiles: [0,2304) = wq/wk/wv/wo (4 x 24x24 tiles),
// [2304,4608) = w1 (96x24), [4608,6912) = w2 (24x96). Same tile body as before.
__global__ __launch_bounds__(256) void convert_all(const float* __restrict__ wq,
                                                   const float* __restrict__ wk,
                                                   const float* __restrict__ wv,
                                                   const float* __restrict__ wo,
                                                   const float* __restrict__ w1,
                                                   const float* __restrict__ w2,
                                                   ushort* __restrict__ o_qkv,
                                                   ushort* __restrict__ o_1t,
                                                   ushort* __restrict__ o_2t) {
    const float* in;
    ushort* out;
    int K, N, bx, by;
    int id = blockIdx.x;
    if (id < 2304) {
        const float* srcs[4] = { wq, wk, wv, wo };
        int z = id / 576, rem = id % 576;
        in = srcs[z]; out = o_qkv + (size_t)z * DMODEL * DMODEL;
        K = DMODEL; N = DMODEL; bx = (rem % 24) * 32; by = (rem / 24) * 32;
    } else if (id < 4608) {
        int rem = id - 2304;
        in = w1; out = o_1t; K = DMODEL; N = HID;
        bx = (rem % 96) * 32; by = (rem / 96) * 32;
    } else {
        int rem = id - 4608;
        in = w2; out = o_2t; K = HID; N = DMODEL;
        bx = (rem % 24) * 32; by = (rem / 24) * 32;
    }
    __shared__ float tile[32][33];
    const int tx = threadIdx.x & 31, ty = threadIdx.x >> 5;
    #pragma unroll
    for (int i = 0; i < 32; i += 8)
        tile[ty + i][tx] = in[(size_t)(by + ty + i) * N + bx + tx];
    __syncthreads();
    #pragma unroll
    for (int i = 0; i < 32; i += 8)
        out[(size_t)(bx + ty + i) * K + by + tx] = f2b(tile[tx][ty + i]);
}

// ---------------- V transpose: v[b][s][h*64+d] (stride QKVN) -> vt[(bh*64+d)][s] ----------------
__global__ __launch_bounds__(256) void transpose_v(const ushort* __restrict__ v,
                                                   ushort* __restrict__ vt) {
    const int st = blockIdx.x;   // key tile (64 rows)
    const int bh = blockIdx.y;
    const int b = bh / NHEAD, h = bh % NHEAD;
    const ushort* src = v + ((size_t)b * SEQ) * QKVN + h * HS;
    ushort* dst = vt + ((size_t)bh * HS) * SEQ;
    __shared__ ushort t[64][65];
    const int col = threadIdx.x & 63;
    const int r0  = (threadIdx.x >> 6) * 16;
    #pragma unroll
    for (int i = 0; i < 16; ++i)
        t[col][r0 + i] = src[(size_t)(st * 64 + r0 + i) * QKVN + col];
    __syncthreads();
    #pragma unroll
    for (int i = 0; i < 16; ++i)
        dst[(size_t)(r0 + i) * SEQ + st * 64 + col] = t[r0 + i][col];
}

// ---------------- LayerNorm (ddof=1), fp32 in -> bf16 out ----------------
// r21: wave-per-row (4 rows/block, grid NROWS/4). Row = 768 floats = 3x
// float4 per lane of a 64-lane wave; reduction is pure __shfl — no LDS,
// no __syncthreads, no idle threads (was: 1 row/256t block, 2 barriers).
__global__ __launch_bounds__(256) void ln_kernel(const float* __restrict__ x,
                                                 const float* __restrict__ gamma,
                                                 const float* __restrict__ beta,
                                                 ushort* __restrict__ out) {
    const int wid = threadIdx.x >> 6, lane = threadIdx.x & 63;
    const int row = blockIdx.x * 4 + wid;
    const float4* xr4 = (const float4*)(x + (size_t)row * DMODEL);
    float4 v[3];
    float s = 0.f, s2 = 0.f;
    #pragma unroll
    for (int i = 0; i < 3; ++i) {
        v[i] = xr4[lane + i * 64];
        s  += v[i].x + v[i].y + v[i].z + v[i].w;
        s2 += v[i].x * v[i].x + v[i].y * v[i].y + v[i].z * v[i].z + v[i].w * v[i].w;
    }
    #pragma unroll
    for (int off = 32; off > 0; off >>= 1) {
        s  += __shfl_down(s,  off, 64);
        s2 += __shfl_down(s2, off, 64);
    }
    float S  = __shfl(s,  0, 64);
    float S2 = __shfl(s2, 0, 64);
    const float mean = S / DMODEL;
    const float rstd = rsqrtf((S2 - DMODEL * mean * mean) / (DMODEL - 1) + EPS);
    ushort4* orow = (ushort4*)(out + (size_t)row * DMODEL);
    #pragma unroll
    for (int i = 0; i < 3; ++i) {
        const float4 g = ((const float4*)gamma)[lane + i * 64];
        const float4 b = ((const float4*)beta)[lane + i * 64];
        ushort4 o;
        o.x = f2b(g.x * (v[i].x - mean) * rstd + b.x);
        o.y = f2b(g.y * (v[i].y - mean) * rstd + b.y);
        o.z = f2b(g.z * (v[i].z - mean) * rstd + b.z);
        o.w = f2b(g.w * (v[i].w - mean) * rstd + b.w);
        orow[lane + i * 64] = o;
    }
}

// ---------------- gemm_mfma: 64x128 tile, BK=64, 512 threads / 8 waves (N=768) ----------------
// r20-proven (r13 bench): waves/SIMD 3 -> 6 at constant tile. 2x4 wave grid,
// per-wave 32x32, acc[2][2]; zero-conflict 8-chunk XOR layout; LDS 48KB ->
// 3 blocks/CU = 6 waves/SIMD. Frozen.
#define GN 128
#define GK 64
#define GM 64
__global__ __launch_bounds__(512, 6) void gemm_mfma(const ushort* __restrict__ A,
                                                    const ushort* __restrict__ Bt,
                                                    const float* __restrict__ bias,
                                                    const float* __restrict__ res,
                                                    float* __restrict__ C,
                                                    ushort* __restrict__ Cb,
                                                    int M, int N, int K, int do_relu,
                                                    int scale_q) {
    __shared__ ushort As[2][GM * GK];   // 2 x 8 KB
    __shared__ ushort Bs[2][GN * GK];   // 2 x 16 KB -> 48 KB total
    const int tid  = threadIdx.x;
    const int lane = tid & 63, wave = tid >> 6;   // 0..7
    const int l16  = lane & 15, quad = lane >> 4;
    const int wr = wave & 1, wc = wave >> 1;      // 2x4 wave grid, 32x32/wave

    // XCD-aware swizzle: give each XCD a contiguous row-major chunk
    const int nwg = gridDim.x * gridDim.y;
    int id = blockIdx.y * gridDim.x + blockIdx.x;
    if ((nwg & 7) == 0) {
        const int chunk = nwg >> 3;
        id = (id & 7) * chunk + (id >> 3);
    }
    const int bx = id % gridDim.x;
    const int by = id / gridDim.x;
    const int row0 = by * GM, col0 = bx * GN;

    f32x4 acc[2][2];
    #pragma unroll
    for (int i = 0; i < 2; ++i)
        #pragma unroll
        for (int j = 0; j < 2; ++j) acc[i][j] = (f32x4){0.f, 0.f, 0.f, 0.f};

    // staging: LDS chunk c=(m<<3)|j  <-  global chunk j^(m&7) of row m
    // A: 512 chunks -> 1/thread; B: 1024 chunks -> 2/thread
    const ushort* Asrc;
    const ushort* Bsrc[2];
    {
        int c = tid, m = c >> 3, j = c & 7;
        Asrc = A + (size_t)(row0 + m) * K + (j ^ (m & 7)) * 8;
    }
    #pragma unroll
    for (int i = 0; i < 2; ++i) {
        int c = tid + i * 512, m = c >> 3, j = c & 7;
        Bsrc[i] = Bt + (size_t)(col0 + m) * K + (j ^ (m & 7)) * 8;
    }

    const int nk = K / GK;
    // prologue: stage K-tile 0 into buf 0
    GLDS16(Asrc, &As[0][tid * 8]);
    #pragma unroll
    for (int i = 0; i < 2; ++i) GLDS16(Bsrc[i], &Bs[0][(tid + i * 512) * 8]);

    for (int kt = 0; kt < nk; ++kt) {
        const int p = kt & 1;
        __syncthreads();   // drains buf[p] loads; all waves done reading buf[p^1]
        if (kt + 1 < nk) {
            const int k1 = (kt + 1) * GK;
            GLDS16(Asrc + k1, &As[p ^ 1][tid * 8]);
            #pragma unroll
            for (int i = 0; i < 2; ++i) GLDS16(Bsrc[i] + k1, &Bs[p ^ 1][(tid + i * 512) * 8]);
        }

        #pragma unroll
        for (int s = 0; s < 2; ++s) {
            bf16x8 af[2], bfr[2];
            #pragma unroll
            for (int i = 0; i < 2; ++i) {
                int m = wr * 32 + i * 16 + l16;
                af[i] = *(const bf16x8*)&As[p][(m * 8 + (((s << 2) | quad) ^ (m & 7))) * 8];
            }
            #pragma unroll
            for (int j = 0; j < 2; ++j) {
                int n = wc * 32 + j * 16 + l16;
                bfr[j] = *(const bf16x8*)&Bs[p][(n * 8 + (((s << 2) | quad) ^ (n & 7))) * 8];
            }
            #pragma unroll
            for (int i = 0; i < 2; ++i)
                #pragma unroll
                for (int j = 0; j < 2; ++j)
                    acc[i][j] = __builtin_amdgcn_mfma_f32_16x16x32_bf16(af[i], bfr[j], acc[i][j], 0, 0, 0);
        }
    }

    // epilogue: C/D layout col=l16, row=quad*4+r
    #pragma unroll
    for (int i = 0; i < 2; ++i) {
        #pragma unroll
        for (int r = 0; r < 4; ++r) {
            int row = row0 + wr * 32 + i * 16 + quad * 4 + r;
            #pragma unroll
            for (int j = 0; j < 2; ++j) {
                int col = col0 + wc * 32 + j * 16 + l16;
                float v = acc[i][j][r];
                if (bias) v += bias[col];
                if (do_relu) v = fmaxf(v, 0.f);
                if (scale_q && col < DMODEL) v *= 0.125f;  // fold 1/sqrt(hs) into Q
                if (res) v += res[(size_t)row * N + col];
                if (Cb) Cb[(size_t)row * N + col] = f2b(v);
                else    C [(size_t)row * N + col] = v;
            }
        }
    }
}

// ---------------- gemm_big: 128x128, BK=32, 512 threads, tri-buffer + counted vmcnt ----------------
// r7-proven config (MLP1 = 71-75us across rounds, occ 54-58%). Structure
// family measured-cornered. Frozen.
#define HM 128
#define HN 128
#define HK 32
__global__ __launch_bounds__(512, 6) void gemm_big(const ushort* __restrict__ A,
                                                   const ushort* __restrict__ Bt,
                                                   const float* __restrict__ bias,
                                                   const float* __restrict__ res,
                                                   float* __restrict__ C,
                                                   ushort* __restrict__ Cb,
                                                   int M, int N, int K, int do_relu,
                                                   int scale_q) {
    __shared__ ushort As[3][HM * HK];   // 3 x 8 KB
    __shared__ ushort Bs[3][HN * HK];   // 3 x 8 KB  -> 48 KB total
    const int tid  = threadIdx.x;
    const int lane = tid & 63, wave = tid >> 6;   // 0..7
    const int l16  = lane & 15, quad = lane >> 4;
    const int wr = wave & 3, wc = wave >> 2;      // 4x2 wave grid, 32x64/wave

    const int nwg = gridDim.x * gridDim.y;
    int id = blockIdx.y * gridDim.x + blockIdx.x;
    if ((nwg & 7) == 0) {
        const int chunk = nwg >> 3;
        id = (id & 7) * chunk + (id >> 3);
    }
    const int bx = id % gridDim.x;
    const int by = id / gridDim.x;
    const int row0 = by * HM, col0 = bx * HN;

    f32x4 acc[2][4];
    #pragma unroll
    for (int i = 0; i < 2; ++i)
        #pragma unroll
        for (int j = 0; j < 4; ++j) acc[i][j] = (f32x4){0.f, 0.f, 0.f, 0.f};

    // row-pair layout: LDS chunk c = lr*8+pos holds global (m = 2*lr + (p>>2), j = p&3)
    // where p = pos ^ (lr&7)   [zero-conflict, verified r5/r6/r7]
    const ushort* Asrc;
    const ushort* Bsrc;
    {
        int c = tid;
        int lr = c >> 3, pp = (c & 7) ^ (lr & 7);
        int m = lr * 2 + (pp >> 2), j = pp & 3;
        Asrc = A  + (size_t)(row0 + m) * K + j * 8;
        Bsrc = Bt + (size_t)(col0 + m) * K + j * 8;
    }

    const int nk = K / HK;   // K=768 -> 24

#define STAGE_BIG(kt, b) do { \
    const int _k = (kt) * HK; \
    GLDS16(Asrc + _k, &As[b][tid * 8]); \
    GLDS16(Bsrc + _k, &Bs[b][tid * 8]); \
} while (0)

    STAGE_BIG(0, 0);
    STAGE_BIG(1, 1);

    int pc = 0, pn = 1, ps = 2;   // compute / next / stage-target buffers
    for (int t = 0; t < nk; ++t) {
        if (t + 1 < nk) asm volatile("s_waitcnt vmcnt(2)" ::: "memory");
        else            asm volatile("s_waitcnt vmcnt(0)" ::: "memory");
        __builtin_amdgcn_s_barrier();
        if (t + 2 < nk) STAGE_BIG(t + 2, ps);

        bf16x8 af[2], bfr[4];
        #pragma unroll
        for (int i = 0; i < 2; ++i) {
            int m = wr * 32 + i * 16 + l16;
            int ch = (m >> 1) * 8 + ((((m & 1) << 2) | quad) ^ ((m >> 1) & 7));
            af[i] = *(const bf16x8*)&As[pc][ch * 8];
        }
        #pragma unroll
        for (int j = 0; j < 4; ++j) {
            int n = wc * 64 + j * 16 + l16;
            int ch = (n >> 1) * 8 + ((((n & 1) << 2) | quad) ^ ((n >> 1) & 7));
            bfr[j] = *(const bf16x8*)&Bs[pc][ch * 8];
        }
        #pragma unroll
        for (int i = 0; i < 2; ++i)
            #pragma unroll
            for (int j = 0; j < 4; ++j)
                acc[i][j] = __builtin_amdgcn_mfma_f32_16x16x32_bf16(af[i], bfr[j], acc[i][j], 0, 0, 0);

        int tmp = pc; pc = pn; pn = ps; ps = tmp;
    }

    // epilogue: C/D layout col=l16, row=quad*4+r
    #pragma unroll
    for (int i = 0; i < 2; ++i) {
        #pragma unroll
        for (int r = 0; r < 4; ++r) {
            int row = row0 + wr * 32 + i * 16 + quad * 4 + r;
            #pragma unroll
            for (int j = 0; j < 4; ++j) {
                int col = col0 + wc * 64 + j * 16 + l16;
                float v = acc[i][j][r];
                if (bias) v += bias[col];
                if (do_relu) v = fmaxf(v, 0.f);
                if (scale_q && col < DMODEL) v *= 0.125f;  // fold 1/sqrt(hs) into Q
                if (res) v += res[(size_t)row * N + col];
                if (Cb) Cb[(size_t)row * N + col] = f2b(v);
                else    C [(size_t)row * N + col] = v;
            }
        }
    }
}

// ---------------- Flash attention: paired q-tiles, K tri-buffer + counted vmcnt ----------------
// r19 config (verified r12): K tri-buffer + counted vmcnt(2), V dbuf,
// V-first issue order, XCD swizzle for K/V L2 locality. PPAD=76. Frozen.
#define TQ 64
#define TK 64
#define PPAD 76
#define NQT (SEQ / TQ)   // 32

__global__ __launch_bounds__(256, 3) void fattn_kernel(const ushort* __restrict__ q,
                                                       const ushort* __restrict__ k,
                                                       const ushort* __restrict__ vt,
                                                       ushort* __restrict__ o,
                                                       int ldqkv) {
    // XCD-aware remap: same-bh pair-blocks contiguous -> same XCD L2
    const int nwg = gridDim.x * gridDim.y;   // 16*48 = 768, %8==0
    int id = blockIdx.y * gridDim.x + blockIdx.x;
    {
        const int chunk = nwg >> 3;          // 96
        id = (id & 7) * chunk + (id >> 3);
    }
    const int pair = id % gridDim.x;         // 0..15
    const int bh   = id / gridDim.x;
    const int qts[2] = { pair, NQT - 1 - pair };
    const int b = bh / NHEAD, h = bh % NHEAD;
    const int tid  = threadIdx.x;
    const int wave = tid >> 6;
    const int lane = tid & 63;
    const int l16  = lane & 15;
    const int quad = lane >> 4;

    __shared__ ushort Ks[3][TK * 64];    // 24 KB tri-buffer, packed [key][8 chunks]
    __shared__ ushort Vs[2][HS * 64];    // 16 KB dbuf, packed [d][8 chunks]
    __shared__ ushort Ps[4][16][PPAD];   // per-wave P[q][key] (wave-private)

    const size_t base  = ((size_t)b * SEQ) * ldqkv + (size_t)h * HS;
    const size_t baseO = ((size_t)b * SEQ) * DMODEL + (size_t)h * HS;
    const ushort* vth = vt + ((size_t)bh * HS) * SEQ;

    const int r0 = tid >> 3, j0 = (tid & 7) ^ (r0 & 7);
    const int r1 = (tid + 256) >> 3, j1 = (tid & 7) ^ (r1 & 7);
    const ushort* Ksrc0 = k + base + (size_t)r0 * ldqkv + j0 * 8;
    const ushort* Ksrc1 = k + base + (size_t)r1 * ldqkv + j1 * 8;
    const ushort* Vsrc0 = vth + (size_t)r0 * SEQ + j0 * 8;
    const ushort* Vsrc1 = vth + (size_t)r1 * SEQ + j1 * 8;

    bf16x8 qf[2][2];
    #pragma unroll
    for (int t = 0; t < 2; ++t) {
        int qrow = qts[t] * TQ + wave * 16 + l16;
        const ushort* qp = q + base + (size_t)qrow * ldqkv + quad * 8;
        qf[t][0] = *(const bf16x8*)(qp);
        qf[t][1] = *(const bf16x8*)(qp + 32);
    }

    f32x4 Oacc[2][4];
    float lrow[2][4];
    #pragma unroll
    for (int t = 0; t < 2; ++t) {
        #pragma unroll
        for (int f = 0; f < 4; ++f) Oacc[t][f] = (f32x4){0.f, 0.f, 0.f, 0.f};
        #pragma unroll
        for (int r = 0; r < 4; ++r) lrow[t][r] = 0.f;
    }

    const int ktiles = qts[1] + 1;   // >= 17 always (pair <= 15)
    // prologue: V(0) first, then K(0), K(1)  (issue order defines vmcnt FIFO)
    GLDS16(Vsrc0, &Vs[0][tid * 8]);
    GLDS16(Vsrc1, &Vs[0][(tid + 256) * 8]);
    GLDS16(Ksrc0, &Ks[0][tid * 8]);
    GLDS16(Ksrc1, &Ks[0][(tid + 256) * 8]);
    GLDS16(Ksrc0 + (size_t)TK * ldqkv, &Ks[1][tid * 8]);
    GLDS16(Ksrc1 + (size_t)TK * ldqkv, &Ks[1][(tid + 256) * 8]);

    int kc = 0, kn = 1, ks2 = 2;   // K buffer rotation
    for (int kt = 0; kt < ktiles; ++kt) {
        const int pv = kt & 1;
        if (kt + 1 < ktiles) asm volatile("s_waitcnt vmcnt(2)" ::: "memory");
        else                 asm volatile("s_waitcnt vmcnt(0)" ::: "memory");
        __builtin_amdgcn_s_barrier();
        if (kt + 1 < ktiles) {
            const size_t ko = (size_t)(kt + 1) * TK;
            GLDS16(Vsrc0 + ko, &Vs[pv ^ 1][tid * 8]);
            GLDS16(Vsrc1 + ko, &Vs[pv ^ 1][(tid + 256) * 8]);
        }
        if (kt + 2 < ktiles) {
            const size_t ko = (size_t)(kt + 2) * TK * ldqkv;
            GLDS16(Ksrc0 + ko, &Ks[ks2][tid * 8]);
            GLDS16(Ksrc1 + ko, &Ks[ks2][(tid + 256) * 8]);
        }

        bf16x8 kb[4][2], vb[4][2];
        #pragma unroll
        for (int f = 0; f < 4; ++f) {
            int row = f * 16 + l16;
            kb[f][0] = *(const bf16x8*)&Ks[kc][(row * 8 + (quad ^ (row & 7))) * 8];
            kb[f][1] = *(const bf16x8*)&Ks[kc][(row * 8 + ((4 | quad) ^ (row & 7))) * 8];
            vb[f][0] = *(const bf16x8*)&Vs[pv][(row * 8 + (quad ^ (row & 7))) * 8];
            vb[f][1] = *(const bf16x8*)&Vs[pv][(row * 8 + ((4 | quad) ^ (row & 7))) * 8];
        }

        #pragma unroll
        for (int t = 0; t < 2; ++t) {
            const int qt = qts[t];
            if (kt > qt) continue;   // wave-uniform; only t=0 can skip

            f32x4 S[4];
            #pragma unroll
            for (int f = 0; f < 4; ++f) {
                f32x4 a = (f32x4){0.f, 0.f, 0.f, 0.f};
                a = __builtin_amdgcn_mfma_f32_16x16x32_bf16(qf[t][0], kb[f][0], a, 0, 0, 0);
                a = __builtin_amdgcn_mfma_f32_16x16x32_bf16(qf[t][1], kb[f][1], a, 0, 0, 0);
                S[f] = a;
            }

            const int qrow_base = qt * TQ + wave * 16 + quad * 4;
            if (kt == qt) {
                #pragma unroll
                for (int f = 0; f < 4; ++f) {
                    int key = kt * TK + f * 16 + l16;
                    #pragma unroll
                    for (int r = 0; r < 4; ++r)
                        if (key > qrow_base + r) S[f][r] = -INFINITY;
                }
            }

            #pragma unroll
            for (int f = 0; f < 4; ++f) {
                #pragma unroll
                for (int r = 0; r < 4; ++r) {
                    float pv2 = __expf(S[f][r]);
                    S[f][r] = pv2;
                    lrow[t][r] += pv2;
                }
            }

            #pragma unroll
            for (int f = 0; f < 4; ++f)
                #pragma unroll
                for (int r = 0; r < 4; ++r)
                    Ps[wave][quad * 4 + r][f * 16 + l16] = f2b(S[f][r]);

            bf16x8 pa0 = *(const bf16x8*)&Ps[wave][l16][quad * 8];
            bf16x8 pa1 = *(const bf16x8*)&Ps[wave][l16][32 + quad * 8];
            #pragma unroll
            for (int f = 0; f < 4; ++f) {
                Oacc[t][f] = __builtin_amdgcn_mfma_f32_16x16x32_bf16(pa0, vb[f][0], Oacc[t][f], 0, 0, 0);
                Oacc[t][f] = __builtin_amdgcn_mfma_f32_16x16x32_bf16(pa1, vb[f][1], Oacc[t][f], 0, 0, 0);
            }
        }

        int tmp = kc; kc = kn; kn = ks2; ks2 = tmp;
    }

    #pragma unroll
    for (int t = 0; t < 2; ++t) {
        const int qrow = qts[t] * TQ + wave * 16 + quad * 4;
        #pragma unroll
        for (int r = 0; r < 4; ++r) {
            float l = lrow[t][r];
            #pragma unroll
            for (int m = 1; m < 16; m <<= 1) l += __shfl_xor(l, m, 64);
            float invl = 1.f / l;
            #pragma unroll
            for (int f = 0; f < 4; ++f)
                o[baseO + (size_t)(qrow + r) * DMODEL + f * 16 + l16] = f2b(Oacc[t][f][r] * invl);
        }
    }
}

// ---------------- Host launcher ----------------
extern "C" void kernel_launch(void* const* d_in, const int* in_sizes, int n_in,
                              void* d_out, int out_size, void* d_ws, size_t ws_size,
                              hipStream_t stream) {
    const float* x      = (const float*)d_in[0];
    const float* wq     = (const float*)d_in[1];
    const float* wk     = (const float*)d_in[2];
    const float* wv     = (const float*)d_in[3];
    const float* wo     = (const float*)d_in[4];
    const float* w1     = (const float*)d_in[5];
    const float* b1     = (const float*)d_in[6];
    const float* w2     = (const float*)d_in[7];
    const float* b2     = (const float*)d_in[8];
    const float* gamma1 = (const float*)d_in[9];
    const float* beta1  = (const float*)d_in[10];
    const float* gamma2 = (const float*)d_in[11];
    const float* beta2  = (const float*)d_in[12];
    float* out = (float*)d_out;

    char* ws = (char*)d_ws;
    ushort* buf_xn   = (ushort*)ws;                              // 8192*768
    ushort* buf_attn = buf_xn;
    ushort* buf_qkv  = (ushort*)(ws + 12582912);                 // 8192*2304
    ushort* buf_h    = buf_qkv;                                  // 8192*3072
    ushort* w_qkv    = (ushort*)(ws + 12582912 + 50331648);      // 2304*768
    ushort* w_ot     = w_qkv + (size_t)QKVN * DMODEL;
    ushort* w_1t     = w_ot + (size_t)DMODEL * DMODEL;
    ushort* w_2t     = w_1t + (size_t)HID * DMODEL;
    // V^T lives in d_out (free until step 4; stream-serial)
    ushort* buf_vt   = (ushort*)d_out;

    // 0) all weight converts in one launch (w_qkv = [wq|wk|wv|wo] transposed)
    convert_all<<<6912, 256, 0, stream>>>(wq, wk, wv, wo, w1, w2, w_qkv, w_1t, w_2t);

    // 1) xn1 = LN(x)  (wave-per-row, 4 rows/block)
    ln_kernel<<<NROWS/4, 256, 0, stream>>>(x, gamma1, beta1, buf_xn);
    // 2) qkv = xn1 @ [wq|wk|wv], Q cols pre-scaled by 0.125 (gemm_big 128x128, 512t)
    gemm_big<<<dim3(QKVN/HN, NROWS/HM), 512, 0, stream>>>(buf_xn, w_qkv, nullptr, nullptr,
                                                          nullptr, buf_qkv, NROWS, QKVN, DMODEL, 0, 1);
    // 2b) V -> V^T per head (into d_out scratch)
    transpose_v<<<dim3(SEQ/64, BATCH*NHEAD), 256, 0, stream>>>(buf_qkv + 2*DMODEL, buf_vt);
    // 3) flash attention (K tri-buffer + counted vmcnt, XCD swizzle)
    fattn_kernel<<<dim3(NQT/2, BATCH*NHEAD), 256, 0, stream>>>(buf_qkv, buf_qkv + DMODEL,
                                                               buf_vt, buf_attn, QKVN);
    // 4) x1 = x + attn @ wo (N=768 -> gemm_mfma 512t)
    gemm_mfma<<<dim3(DMODEL/GN, NROWS/GM), 512, 0, stream>>>(buf_attn, w_ot, nullptr, x,
                                                             out, nullptr, NROWS, DMODEL, DMODEL, 0, 0);
    // 5) xn2 = LN(x1)
    ln_kernel<<<NROWS/4, 256, 0, stream>>>(out, gamma2, beta2, buf_xn);
    // 6) h = relu(xn2 @ w1 + b1) (gemm_big 128x128, 512t)
    gemm_big<<<dim3(HID/HN, NROWS/HM), 512, 0, stream>>>(buf_xn, w_1t, b1, nullptr,
                                                         nullptr, buf_h, NROWS, HID, DMODEL, 1, 0);
    // 7) out = x1 + h @ w2 + b2 (N=768 -> gemm_mfma 512t)
    gemm_mfma<<<dim3(DMODEL/GN, NROWS/GM), 512, 0, stream>>>(buf_h, w_2t, b2, out,
                                                             out, nullptr, NROWS, DMODEL, HID, 0, 0);
}